// Round 1
// baseline (4231.657 us; speedup 1.0000x reference)
//
#include <hip/hip_runtime.h>
#include <hip/hip_bf16.h>

// AutoFormer forward, fp32. B=32 S=512 IN=256 D=512 H=8 L=2 DFF=2048 NT=424 K=25
#define S_LEN 512
#define D_DIM 512
#define B_DIM 32
#define IN_DIM 256
#define DFF_DIM 2048
#define NT_DIM 424

static constexpr size_t SZ = (size_t)B_DIM * S_LEN * D_DIM; // 8388608 floats

__device__ __forceinline__ float gelu_tanh(float x) {
  // jax.nn.gelu default: approximate=True (tanh form)
  float x3 = x * x * x;
  return 0.5f * x * (1.f + tanhf(0.7978845608028654f * (x + 0.044715f * x3)));
}

// ---------------------------------------------------------------------------
// Tiled fp32 GEMM: C[M,N] = act(A[M,Kd] @ W[Kd,N] + bias + res)
// 128x128 tile, BK=8, 256 threads, 8x8 per thread in 2x2 quadrants of 4x4.
// Requires M%128==0, N%128==0, Kd%8==0.
// ---------------------------------------------------------------------------
template<int ACT> // 0 none, 1 gelu
__global__ __launch_bounds__(256) void gemm_f32(
    const float* __restrict__ A, const float* __restrict__ W,
    const float* __restrict__ bias, const float* __restrict__ res,
    float* __restrict__ C, int M, int Kd, int N)
{
  __shared__ float As[8][128];
  __shared__ float Bs[8][128];
  const int tid = threadIdx.x;
  const int tx = tid & 15;   // column group
  const int ty = tid >> 4;   // row group
  const int bx = blockIdx.x; // N tile
  const int by = blockIdx.y; // M tile

  // global->LDS load mapping
  const int ar = tid >> 1;          // 0..127 A-tile row
  const int ak = (tid & 1) << 2;    // 0 or 4
  const int br = tid >> 5;          // 0..7 B-tile row (k)
  const int bc = (tid & 31) << 2;   // 0..124

  const float* Ap = A + (size_t)(by * 128 + ar) * Kd + ak;
  const float* Wp = W + (size_t)br * N + (size_t)bx * 128 + bc;

  float acc[2][2][4][4] = {};

  for (int k0 = 0; k0 < Kd; k0 += 8) {
    float4 av = *(const float4*)(Ap + k0);
    float4 bv = *(const float4*)(Wp + (size_t)k0 * N);
    __syncthreads();
    As[ak + 0][ar] = av.x;   // transposed store, 2-way bank alias (free)
    As[ak + 1][ar] = av.y;
    As[ak + 2][ar] = av.z;
    As[ak + 3][ar] = av.w;
    *(float4*)&Bs[br][bc] = bv;
    __syncthreads();
#pragma unroll
    for (int kk = 0; kk < 8; ++kk) {
      float a0[4], a1[4], b0[4], b1[4];
      *(float4*)a0 = *(const float4*)&As[kk][ty * 4];
      *(float4*)a1 = *(const float4*)&As[kk][ty * 4 + 64];
      *(float4*)b0 = *(const float4*)&Bs[kk][tx * 4];
      *(float4*)b1 = *(const float4*)&Bs[kk][tx * 4 + 64];
#pragma unroll
      for (int i = 0; i < 4; ++i)
#pragma unroll
        for (int j = 0; j < 4; ++j) {
          acc[0][0][i][j] += a0[i] * b0[j];
          acc[0][1][i][j] += a0[i] * b1[j];
          acc[1][0][i][j] += a1[i] * b0[j];
          acc[1][1][i][j] += a1[i] * b1[j];
        }
    }
  }

#pragma unroll
  for (int ih = 0; ih < 2; ++ih)
#pragma unroll
    for (int i = 0; i < 4; ++i) {
      const int r = by * 128 + ih * 64 + ty * 4 + i;
#pragma unroll
      for (int jh = 0; jh < 2; ++jh) {
        const int cc = bx * 128 + jh * 64 + tx * 4;
        float4 bia = *(const float4*)(bias + cc);
        float4 ov;
        ov.x = acc[ih][jh][i][0] + bia.x;
        ov.y = acc[ih][jh][i][1] + bia.y;
        ov.z = acc[ih][jh][i][2] + bia.z;
        ov.w = acc[ih][jh][i][3] + bia.w;
        if (res) {
          float4 rv = *(const float4*)(res + (size_t)r * N + cc);
          ov.x += rv.x; ov.y += rv.y; ov.z += rv.z; ov.w += rv.w;
        }
        if (ACT == 1) {
          ov.x = gelu_tanh(ov.x); ov.y = gelu_tanh(ov.y);
          ov.z = gelu_tanh(ov.z); ov.w = gelu_tanh(ov.w);
        }
        *(float4*)(C + (size_t)r * N + cc) = ov;
      }
    }
}

// ---------------------------------------------------------------------------
// Fused auto-correlation: per block = one (b, channel c).
// corr[tau] = sum_s Q[b,(s+tau)%S,c] * K[b,s,c]   (== irfft(Qf*conj(Kf)))
// out[b,s,c] = softmax_tau(corr)[s] * V[b,s,c]
// ---------------------------------------------------------------------------
__global__ __launch_bounds__(256) void autocorr_kernel(
    const float* __restrict__ Q, const float* __restrict__ K,
    const float* __restrict__ V, float* __restrict__ out)
{
  __shared__ float qs[1024]; // Q column duplicated (kills the % S)
  __shared__ float ks[512];
  __shared__ float red[8];
  const int tid = threadIdx.x;
  const int b = blockIdx.x >> 9;
  const int c = blockIdx.x & 511;
  const size_t base = (size_t)b * S_LEN * D_DIM + c;

  for (int s = tid; s < S_LEN; s += 256) {
    float qv = Q[base + (size_t)s * D_DIM];
    qs[s] = qv; qs[s + S_LEN] = qv;
    ks[s] = K[base + (size_t)s * D_DIM];
  }
  __syncthreads();

  const int t0 = tid * 2; // two adjacent taus per thread
  float c0 = 0.f, c1 = 0.f;
#pragma unroll 8
  for (int s = 0; s < S_LEN; ++s) {
    float kv = ks[s];
    c0 += qs[s + t0] * kv;
    c1 += qs[s + t0 + 1] * kv;
  }

  // block softmax over 512 taus
  float m = fmaxf(c0, c1);
#pragma unroll
  for (int off = 32; off; off >>= 1) m = fmaxf(m, __shfl_xor(m, off));
  if ((tid & 63) == 0) red[tid >> 6] = m;
  __syncthreads();
  const float bm = fmaxf(fmaxf(red[0], red[1]), fmaxf(red[2], red[3]));
  const float e0 = expf(c0 - bm), e1 = expf(c1 - bm);
  float sum = e0 + e1;
#pragma unroll
  for (int off = 32; off; off >>= 1) sum += __shfl_xor(sum, off);
  if ((tid & 63) == 0) red[4 + (tid >> 6)] = sum;
  __syncthreads();
  const float inv = 1.f / (red[4] + red[5] + red[6] + red[7]);

  out[base + (size_t)t0 * D_DIM]       = e0 * inv * V[base + (size_t)t0 * D_DIM];
  out[base + (size_t)(t0 + 1) * D_DIM] = e1 * inv * V[base + (size_t)(t0 + 1) * D_DIM];
}

// ---------------------------------------------------------------------------
// x_out = y - moving_avg(y, K=25)  (count_include_pad=False), elementwise
// ---------------------------------------------------------------------------
__global__ __launch_bounds__(256) void movavg_sub_kernel(
    const float* __restrict__ y, float* __restrict__ out)
{
  const int idx = blockIdx.x * 256 + threadIdx.x; // 0 .. B*S*D-1
  const int d = idx & 511;
  const int s = (idx >> 9) & 511;
  const int b = idx >> 18;
  const int lo = max(s - 12, 0);
  const int hi = min(s + 13, S_LEN);
  const float* yp = y + (size_t)b * S_LEN * D_DIM + d;
  float sum = 0.f;
  for (int t = lo; t < hi; ++t) sum += yp[(size_t)t * D_DIM];
  out[idx] = y[idx] - sum / (float)(hi - lo);
}

// mean over seq axis: hm[b,d] = mean_s x[b,s,d]
__global__ __launch_bounds__(256) void mean_kernel(
    const float* __restrict__ x, float* __restrict__ out)
{
  const int idx = blockIdx.x * 256 + threadIdx.x; // 0 .. B*D-1
  const int b = idx >> 9, d = idx & 511;
  const float* xp = x + (size_t)b * S_LEN * D_DIM + d;
  float s = 0.f;
  for (int t = 0; t < S_LEN; ++t) s += xp[(size_t)t * D_DIM];
  out[idx] = s * (1.f / (float)S_LEN);
}

// tiny bounds-checked GEMM for the head projections
template<int ACT> // 0 none, 2 relu
__global__ __launch_bounds__(256) void small_gemm(
    const float* __restrict__ A, const float* __restrict__ W,
    const float* __restrict__ bias, float* __restrict__ C,
    int M, int Kd, int N)
{
  const int idx = blockIdx.x * 256 + threadIdx.x;
  const int m = idx / N, n = idx % N;
  if (m >= M) return;
  float acc = bias[n];
  for (int k = 0; k < Kd; ++k) acc += A[(size_t)m * Kd + k] * W[(size_t)k * N + n];
  if (ACT == 2) acc = fmaxf(acc, 0.f);
  C[(size_t)m * N + n] = acc;
}

// ---------------------------------------------------------------------------
extern "C" void kernel_launch(void* const* d_in, const int* in_sizes, int n_in,
                              void* d_out, int out_size, void* d_ws, size_t ws_size,
                              hipStream_t stream)
{
  const float* x       = (const float*)d_in[0];
  const float* embed_w = (const float*)d_in[1];
  const float* embed_b = (const float*)d_in[2];
  const float* qkvo_w  = (const float*)d_in[3];
  const float* qkvo_b  = (const float*)d_in[4];
  const float* ffn_w1  = (const float*)d_in[5];
  const float* ffn_b1  = (const float*)d_in[6];
  const float* ffn_w2  = (const float*)d_in[7];
  const float* ffn_b2  = (const float*)d_in[8];
  const float* proj_w1 = (const float*)d_in[9];
  const float* proj_b1 = (const float*)d_in[10];
  const float* proj_w2 = (const float*)d_in[11];
  const float* proj_b2 = (const float*)d_in[12];
  float* out = (float*)d_out;

  float* ws = (float*)d_ws;
  float* Bh = ws;            // h / layer input
  float* Bq = ws + SZ;       // Q, then y, then y2
  float* Bk = ws + 2 * SZ;   // K, then x1 (seasonal)
  float* Bv = ws + 3 * SZ;   // V, then FFN hidden chunk (spans Bv..Ba, 2*SZ)
  float* Ba = ws + 4 * SZ;   // attn out

  const int M = B_DIM * S_LEN; // 16384
  dim3 blk(256);

  // embed: h = x @ embed_w + embed_b
  gemm_f32<0><<<dim3(D_DIM / 128, M / 128), blk, 0, stream>>>(
      x, embed_w, embed_b, nullptr, Bh, M, IN_DIM, D_DIM);

  for (int l = 0; l < 2; ++l) {
    const float* qw = qkvo_w + (size_t)l * 4 * D_DIM * D_DIM;
    const float* qb = qkvo_b + (size_t)l * 4 * D_DIM;
    // Q, K, V projections
    gemm_f32<0><<<dim3(4, 128), blk, 0, stream>>>(Bh, qw,                     qb,             nullptr, Bq, M, D_DIM, D_DIM);
    gemm_f32<0><<<dim3(4, 128), blk, 0, stream>>>(Bh, qw + (size_t)D_DIM*D_DIM,   qb + D_DIM,     nullptr, Bk, M, D_DIM, D_DIM);
    gemm_f32<0><<<dim3(4, 128), blk, 0, stream>>>(Bh, qw + (size_t)2*D_DIM*D_DIM, qb + 2*D_DIM,   nullptr, Bv, M, D_DIM, D_DIM);
    // fused correlation + softmax + *V
    autocorr_kernel<<<dim3(B_DIM * D_DIM), blk, 0, stream>>>(Bq, Bk, Bv, Ba);
    // y = attn @ Wo + bo + h (residual)
    gemm_f32<0><<<dim3(4, 128), blk, 0, stream>>>(Ba, qw + (size_t)3*D_DIM*D_DIM, qb + 3*D_DIM, Bh, Bq, M, D_DIM, D_DIM);
    // x1 = y - movavg(y)
    movavg_sub_kernel<<<dim3((unsigned)(SZ / 256)), blk, 0, stream>>>(Bq, Bk);
    // FFN in two 8192-row chunks (hidden buffer = Bv..Ba, 2*SZ floats)
    const float* w1  = ffn_w1 + (size_t)l * D_DIM * DFF_DIM;
    const float* b1p = ffn_b1 + (size_t)l * DFF_DIM;
    const float* w2  = ffn_w2 + (size_t)l * DFF_DIM * D_DIM;
    const float* b2p = ffn_b2 + (size_t)l * D_DIM;
    for (int ch = 0; ch < 2; ++ch) {
      const size_t ro = (size_t)ch * 8192;
      gemm_f32<1><<<dim3(DFF_DIM / 128, 8192 / 128), blk, 0, stream>>>(
          Bk + ro * D_DIM, w1, b1p, nullptr, Bv, 8192, D_DIM, DFF_DIM);
      gemm_f32<0><<<dim3(D_DIM / 128, 8192 / 128), blk, 0, stream>>>(
          Bv, w2, b2p, Bk + ro * D_DIM, Bq + ro * D_DIM, 8192, DFF_DIM, D_DIM);
    }
    // x_next = y2 - movavg(y2)
    movavg_sub_kernel<<<dim3((unsigned)(SZ / 256)), blk, 0, stream>>>(Bq, Bh);
  }

  // head: mean over s, then two small projections
  float* hm = Bq;
  float* p1 = Bq + B_DIM * D_DIM;
  mean_kernel<<<dim3(B_DIM * D_DIM / 256), blk, 0, stream>>>(Bh, hm);
  small_gemm<2><<<dim3((B_DIM * 256 + 255) / 256), blk, 0, stream>>>(
      hm, proj_w1, proj_b1, p1, B_DIM, D_DIM, 256);
  small_gemm<0><<<dim3((B_DIM * NT_DIM + 255) / 256), blk, 0, stream>>>(
      p1, proj_w2, proj_b2, out, B_DIM, 256, NT_DIM);
}

// Round 2
// 1900.460 us; speedup vs baseline: 2.2266x; 2.2266x over previous
//
#include <hip/hip_runtime.h>
#include <hip/hip_bf16.h>

// AutoFormer forward. B=32 S=512 IN=256 D=512 H=8 L=2 DFF=2048 NT=424 K=25
#define S_LEN 512
#define D_DIM 512
#define B_DIM 32
#define IN_DIM 256
#define DFF_DIM 2048
#define NT_DIM 424

static constexpr size_t SZ = (size_t)B_DIM * S_LEN * D_DIM; // 8388608 floats

using s8v = __attribute__((ext_vector_type(8))) short;
using f4v = __attribute__((ext_vector_type(4))) float;

__device__ __forceinline__ unsigned short f2bf(float f) {
  unsigned u = __float_as_uint(f);
  u += 0x7FFFu + ((u >> 16) & 1u);   // RNE
  return (unsigned short)(u >> 16);
}
__device__ __forceinline__ float bf2f(unsigned short h) {
  return __uint_as_float(((unsigned)h) << 16);
}

__device__ __forceinline__ float gelu_tanh(float x) {
  float x3 = x * x * x;
  return 0.5f * x * (1.f + tanhf(0.7978845608028654f * (x + 0.044715f * x3)));
}

// ---------------------------------------------------------------------------
// Weight convert+transpose: W[Kp][N] fp32 -> Wt[N][2*Kp] bf16 = [hi | lo]
// grid (Kp/32, N/32), 256 threads
// ---------------------------------------------------------------------------
__global__ __launch_bounds__(256) void conv_w(
    const float* __restrict__ W, unsigned short* __restrict__ Wt, int Kp, int N)
{
  __shared__ float T[32][33];
  const int k0 = blockIdx.x * 32, n0 = blockIdx.y * 32;
  const int tid = threadIdx.x;
  const int col = tid & 31, r8 = tid >> 5;
#pragma unroll
  for (int it = 0; it < 4; ++it) {
    int row = r8 + it * 8;
    T[row][col] = W[(size_t)(k0 + row) * N + n0 + col];
  }
  __syncthreads();
  const int nl = tid >> 3, kq = tid & 7;
  const size_t K2 = 2 * (size_t)Kp;
#pragma unroll
  for (int j = 0; j < 4; ++j) {
    int kl = kq * 4 + j;
    float v = T[kl][nl];
    unsigned short h = f2bf(v);
    Wt[(size_t)(n0 + nl) * K2 + k0 + kl] = h;
    Wt[(size_t)(n0 + nl) * K2 + Kp + k0 + kl] = f2bf(v - bf2f(h));
  }
}

// ---------------------------------------------------------------------------
// Split-bf16 MFMA GEMM: C[M,N] = act(A[M,Kp](fp32) @ W[Kp,N] + bias (+res))
// W pre-split/transposed as Wt[N][2Kp] bf16. A split to hi/lo in staging.
// acc += Ah*Wh + Ah*Wl + Al*Wh  (AlWl ~2^-18, dropped)
// 128x128 tile, BK=32, 256 thr = 4 waves, wave = 64x64 = 4x4 frags 16x16x32.
// M%128==0, N%128==0, Kp%32==0.
// ---------------------------------------------------------------------------
template<int ACT, int RES> // ACT: 0 none, 1 gelu
__global__ __launch_bounds__(256) void gemm_split(
    const float* __restrict__ A, const unsigned short* __restrict__ Wt,
    const float* __restrict__ bias, const float* __restrict__ res,
    float* __restrict__ C, int M, int Kp, int N)
{
  __shared__ unsigned short Ash[128 * 32];
  __shared__ unsigned short Asl[128 * 32];
  __shared__ unsigned short Wsh[128 * 32];
  __shared__ unsigned short Wsl[128 * 32];
  const int tid = threadIdx.x;
  const int lane = tid & 63, wid = tid >> 6;
  const int fr = lane & 15, kq = lane >> 4;      // frag row/col, k-quarter
  const int wr = wid >> 1, wc = wid & 1;         // wave quadrant
  const int m0 = blockIdx.y * 128, n0 = blockIdx.x * 128;
  const size_t K2 = 2 * (size_t)Kp;

  const int arow = tid >> 1;                     // A staging: row 0..127
  const int akh = (tid & 1) << 4;                // k-half 0/16
  const float* aptr = A + (size_t)(m0 + arow) * Kp + akh;

  f4v acc[4][4] = {};

  for (int k0 = 0; k0 < Kp; k0 += 32) {
    // ---- A: fp32 -> split bf16 (registers) ----
    float4 f[4];
#pragma unroll
    for (int i = 0; i < 4; ++i)
      f[i] = *(const float4*)(aptr + k0 + 4 * i);
    unsigned short hi[16], lo[16];
#pragma unroll
    for (int i = 0; i < 4; ++i) {
      float vv[4] = {f[i].x, f[i].y, f[i].z, f[i].w};
#pragma unroll
      for (int j = 0; j < 4; ++j) {
        unsigned short h = f2bf(vv[j]);
        hi[4 * i + j] = h;
        lo[4 * i + j] = f2bf(vv[j] - bf2f(h));
      }
    }
    __syncthreads();   // previous compute done before LDS overwrite
    *(s8v*)&Ash[arow * 32 + akh]     = *(s8v*)&hi[0];
    *(s8v*)&Ash[arow * 32 + akh + 8] = *(s8v*)&hi[8];
    *(s8v*)&Asl[arow * 32 + akh]     = *(s8v*)&lo[0];
    *(s8v*)&Asl[arow * 32 + akh + 8] = *(s8v*)&lo[8];
    // ---- W: async global->LDS, hi and lo tiles (each 8KB, 2 instr/wave) ----
#pragma unroll
    for (int t = 0; t < 2; ++t) {
      int o = (wid * 2 + t) * 1024 + lane * 16;  // byte offset in 8KB tile
      int nrow = o >> 6;                         // 64B per row (32 bf16)
      int kel = (o & 63) >> 1;                   // element within row
      const unsigned short* sh = Wt + (size_t)(n0 + nrow) * K2 + k0 + kel;
      __builtin_amdgcn_global_load_lds(
          (const __attribute__((address_space(1))) unsigned int*)sh,
          (__attribute__((address_space(3))) unsigned int*)&Wsh[(wid * 2 + t) * 512],
          16, 0, 0);
      __builtin_amdgcn_global_load_lds(
          (const __attribute__((address_space(1))) unsigned int*)(sh + Kp),
          (__attribute__((address_space(3))) unsigned int*)&Wsl[(wid * 2 + t) * 512],
          16, 0, 0);
    }
    __syncthreads();
    // ---- fragments + 48 MFMA ----
    s8v af[4], bh[4], bl[4];
#pragma unroll
    for (int i = 0; i < 4; ++i) {
      af[i] = *(const s8v*)&Ash[(wr * 64 + i * 16 + fr) * 32 + kq * 8];
      bh[i] = *(const s8v*)&Wsh[(wc * 64 + i * 16 + fr) * 32 + kq * 8];
      bl[i] = *(const s8v*)&Wsl[(wc * 64 + i * 16 + fr) * 32 + kq * 8];
    }
#pragma unroll
    for (int i = 0; i < 4; ++i)
#pragma unroll
      for (int j = 0; j < 4; ++j) {
        acc[i][j] = __builtin_amdgcn_mfma_f32_16x16x32_bf16(af[i], bh[j], acc[i][j], 0, 0, 0);
        acc[i][j] = __builtin_amdgcn_mfma_f32_16x16x32_bf16(af[i], bl[j], acc[i][j], 0, 0, 0);
      }
#pragma unroll
    for (int i = 0; i < 4; ++i)
      af[i] = *(const s8v*)&Asl[(wr * 64 + i * 16 + fr) * 32 + kq * 8];
#pragma unroll
    for (int i = 0; i < 4; ++i)
#pragma unroll
      for (int j = 0; j < 4; ++j)
        acc[i][j] = __builtin_amdgcn_mfma_f32_16x16x32_bf16(af[i], bh[j], acc[i][j], 0, 0, 0);
  }

  // ---- epilogue: C/D layout col=lane&15, row=(lane>>4)*4+reg ----
#pragma unroll
  for (int j = 0; j < 4; ++j) {
    const int gc = n0 + wc * 64 + j * 16 + fr;
    const float bv = bias[gc];
#pragma unroll
    for (int i = 0; i < 4; ++i)
#pragma unroll
      for (int r = 0; r < 4; ++r) {
        const int gr = m0 + wr * 64 + i * 16 + kq * 4 + r;
        float v = acc[i][j][r] + bv;
        if (RES) v += res[(size_t)gr * N + gc];
        if (ACT == 1) v = gelu_tanh(v);
        C[(size_t)gr * N + gc] = v;
      }
  }
}

// ---------------------------------------------------------------------------
// Fused auto-correlation, 8 channels per block, in-place on V.
// corr[tau] = sum_s Q[(s+tau)%S]*K[s]; out = softmax_tau(corr) * V
// ---------------------------------------------------------------------------
__global__ __launch_bounds__(256) void autocorr8(
    const float* __restrict__ Q, const float* __restrict__ Km,
    float* __restrict__ V)
{
  __shared__ float qs[8 * 1024];  // XOR-swizzled, Q duplicated (kills %S)
  __shared__ float ks[8 * 520];   // K, later reused for softmax weights
  const int tid = threadIdx.x;
  const int b = blockIdx.x >> 6;
  const int c0 = (blockIdx.x & 63) << 3;
  const size_t base = (size_t)b * S_LEN * D_DIM + c0;

  for (int i = tid; i < 4096; i += 256) {
    int s = i >> 3, cc = i & 7;
    float qv = Q[base + (size_t)s * D_DIM + cc];
    int L0 = cc * 1024 + s;
    int L1 = L0 + 512;
    qs[L0 ^ (((L0 >> 7) & 3) << 2)] = qv;
    qs[L1 ^ (((L1 >> 7) & 3) << 2)] = qv;
    ks[cc * 520 + s] = Km[base + (size_t)s * D_DIM + cc];
  }
  __syncthreads();

  const int c = tid >> 5, tg = tid & 31, t0 = tg << 4; // 16 taus per thread
  const int cbase = c * 1024;
  float acc[16] = {};
  for (int s0 = 0; s0 < 512; s0 += 16) {
    float kr[16];
#pragma unroll
    for (int i = 0; i < 4; ++i)
      *(float4*)&kr[4 * i] = *(const float4*)&ks[c * 520 + s0 + 4 * i];
    float qw[32];
#pragma unroll
    for (int i = 0; i < 8; ++i) {
      int L = cbase + s0 + t0 + 4 * i;
      *(float4*)&qw[4 * i] = *(const float4*)&qs[L ^ (((L >> 7) & 3) << 2)];
    }
#pragma unroll
    for (int u = 0; u < 16; ++u)
#pragma unroll
      for (int t = 0; t < 16; ++t)
        acc[t] = fmaf(qw[t + u], kr[u], acc[t]);
  }

  // softmax over 512 taus per channel: 32 threads (half-wave) per channel
  float mx = acc[0];
#pragma unroll
  for (int t = 1; t < 16; ++t) mx = fmaxf(mx, acc[t]);
#pragma unroll
  for (int off = 16; off; off >>= 1) mx = fmaxf(mx, __shfl_xor(mx, off));
  float e[16], sum = 0.f;
#pragma unroll
  for (int t = 0; t < 16; ++t) { e[t] = __expf(acc[t] - mx); sum += e[t]; }
#pragma unroll
  for (int off = 16; off; off >>= 1) sum += __shfl_xor(sum, off);
  const float inv = 1.f / sum;

  __syncthreads();                 // everyone done reading ks
#pragma unroll
  for (int t = 0; t < 16; ++t) ks[c * 520 + t0 + t] = e[t] * inv;
  __syncthreads();

  for (int i = tid; i < 4096; i += 256) {
    int s = i >> 3, cc = i & 7;
    size_t a = base + (size_t)s * D_DIM + cc;
    V[a] = ks[cc * 520 + s] * V[a];
  }
}

// ---------------------------------------------------------------------------
__global__ __launch_bounds__(256) void movavg_sub_kernel(
    const float* __restrict__ y, float* __restrict__ out)
{
  const int idx = blockIdx.x * 256 + threadIdx.x;
  const int d = idx & 511;
  const int s = (idx >> 9) & 511;
  const int b = idx >> 18;
  const int lo = max(s - 12, 0);
  const int hi = min(s + 13, S_LEN);
  const float* yp = y + (size_t)b * S_LEN * D_DIM + d;
  float sum = 0.f;
  for (int t = lo; t < hi; ++t) sum += yp[(size_t)t * D_DIM];
  out[idx] = y[idx] - sum / (float)(hi - lo);
}

__global__ __launch_bounds__(256) void mean_kernel(
    const float* __restrict__ x, float* __restrict__ out)
{
  const int idx = blockIdx.x * 256 + threadIdx.x;
  const int b = idx >> 9, d = idx & 511;
  const float* xp = x + (size_t)b * S_LEN * D_DIM + d;
  float s = 0.f;
  for (int t = 0; t < S_LEN; ++t) s += xp[(size_t)t * D_DIM];
  out[idx] = s * (1.f / (float)S_LEN);
}

template<int ACT> // 0 none, 2 relu
__global__ __launch_bounds__(256) void small_gemm(
    const float* __restrict__ A, const float* __restrict__ W,
    const float* __restrict__ bias, float* __restrict__ C,
    int M, int Kd, int N)
{
  const int idx = blockIdx.x * 256 + threadIdx.x;
  const int m = idx / N, n = idx % N;
  if (m >= M) return;
  float acc = bias[n];
  for (int k = 0; k < Kd; ++k) acc += A[(size_t)m * Kd + k] * W[(size_t)k * N + n];
  if (ACT == 2) acc = fmaxf(acc, 0.f);
  C[(size_t)m * N + n] = acc;
}

// ---------------------------------------------------------------------------
extern "C" void kernel_launch(void* const* d_in, const int* in_sizes, int n_in,
                              void* d_out, int out_size, void* d_ws, size_t ws_size,
                              hipStream_t stream)
{
  const float* x       = (const float*)d_in[0];
  const float* embed_w = (const float*)d_in[1];
  const float* embed_b = (const float*)d_in[2];
  const float* qkvo_w  = (const float*)d_in[3];
  const float* qkvo_b  = (const float*)d_in[4];
  const float* ffn_w1  = (const float*)d_in[5];
  const float* ffn_b1  = (const float*)d_in[6];
  const float* ffn_w2  = (const float*)d_in[7];
  const float* ffn_b2  = (const float*)d_in[8];
  const float* proj_w1 = (const float*)d_in[9];
  const float* proj_b1 = (const float*)d_in[10];
  const float* proj_w2 = (const float*)d_in[11];
  const float* proj_b2 = (const float*)d_in[12];
  float* out = (float*)d_out;

  float* ws = (float*)d_ws;
  // slot0=Bv (V/attn/hidden-lo), slot1=Bh (h/hidden-hi), slot2=Bq (Q/y/y2), slot3=Bk (K/x1)
  float* Bv = ws;
  float* Bh = ws + SZ;
  float* Bq = ws + 2 * SZ;
  float* Bk = ws + 3 * SZ;
  unsigned short* Wb = (unsigned short*)(ws + 4 * SZ);   // 25.7MB of bf16 weights
  unsigned short* embed_wt = Wb;                          // [512][512]
  unsigned short* qkvo_wt  = Wb + (size_t)512 * 512;      // 8 x [512][1024]
  unsigned short* ffn1_wt  = qkvo_wt + (size_t)8 * 512 * 1024;  // 2 x [2048][1024]
  unsigned short* ffn2_wt  = ffn1_wt + (size_t)2 * 2048 * 1024; // 2 x [512][4096]

  dim3 blk(256);

  // ---- one-time (per call) weight conversion ----
  conv_w<<<dim3(IN_DIM / 32, D_DIM / 32), blk, 0, stream>>>(embed_w, embed_wt, IN_DIM, D_DIM);
  for (int i = 0; i < 8; ++i)
    conv_w<<<dim3(16, 16), blk, 0, stream>>>(
        qkvo_w + (size_t)i * 512 * 512, qkvo_wt + (size_t)i * 512 * 1024, 512, 512);
  for (int l = 0; l < 2; ++l) {
    conv_w<<<dim3(16, 64), blk, 0, stream>>>(
        ffn_w1 + (size_t)l * 512 * 2048, ffn1_wt + (size_t)l * 2048 * 1024, 512, 2048);
    conv_w<<<dim3(64, 16), blk, 0, stream>>>(
        ffn_w2 + (size_t)l * 2048 * 512, ffn2_wt + (size_t)l * 512 * 4096, 2048, 512);
  }

  // ---- embed: Bh = x @ We + be ----
  gemm_split<0, 0><<<dim3(4, 128), blk, 0, stream>>>(
      x, embed_wt, embed_b, nullptr, Bh, 16384, IN_DIM, D_DIM);

  for (int l = 0; l < 2; ++l) {
    const unsigned short* qw = qkvo_wt + (size_t)l * 4 * 512 * 1024;
    const float* qb = qkvo_b + (size_t)l * 4 * 512;
    gemm_split<0, 0><<<dim3(4, 128), blk, 0, stream>>>(
        Bh, qw,                          qb,        nullptr, Bq, 16384, 512, 512);
    gemm_split<0, 0><<<dim3(4, 128), blk, 0, stream>>>(
        Bh, qw + (size_t)512 * 1024,     qb + 512,  nullptr, Bk, 16384, 512, 512);
    gemm_split<0, 0><<<dim3(4, 128), blk, 0, stream>>>(
        Bh, qw + (size_t)2 * 512 * 1024, qb + 1024, nullptr, Bv, 16384, 512, 512);
    autocorr8<<<dim3(B_DIM * 64), blk, 0, stream>>>(Bq, Bk, Bv);
    gemm_split<0, 1><<<dim3(4, 128), blk, 0, stream>>>(
        Bv, qw + (size_t)3 * 512 * 1024, qb + 1536, Bh, Bq, 16384, 512, 512);
    movavg_sub_kernel<<<dim3((unsigned)(SZ / 256)), blk, 0, stream>>>(Bq, Bk);
    // FFN: 2 chunks of 8192 rows; hidden fp32 [8192][2048] spans Bv+Bh (both dead)
    const unsigned short* w1 = ffn1_wt + (size_t)l * 2048 * 1024;
    const unsigned short* w2 = ffn2_wt + (size_t)l * 512 * 4096;
    const float* b1p = ffn_b1 + (size_t)l * DFF_DIM;
    const float* b2p = ffn_b2 + (size_t)l * D_DIM;
    for (int ch = 0; ch < 2; ++ch) {
      const size_t ro = (size_t)ch * 8192;
      gemm_split<1, 0><<<dim3(16, 64), blk, 0, stream>>>(
          Bk + ro * 512, w1, b1p, nullptr, Bv, 8192, 512, 2048);
      gemm_split<0, 1><<<dim3(4, 64), blk, 0, stream>>>(
          Bv, w2, b2p, Bk + ro * 512, Bq + ro * 512, 8192, 2048, 512);
    }
    movavg_sub_kernel<<<dim3((unsigned)(SZ / 256)), blk, 0, stream>>>(Bq, Bh);
  }

  // ---- head ----
  float* hm = Bv;
  float* p1 = Bv + B_DIM * D_DIM;
  mean_kernel<<<dim3(B_DIM * D_DIM / 256), blk, 0, stream>>>(Bh, hm);
  small_gemm<2><<<dim3(32), blk, 0, stream>>>(hm, proj_w1, proj_b1, p1, B_DIM, D_DIM, 256);
  small_gemm<0><<<dim3((B_DIM * NT_DIM + 255) / 256), blk, 0, stream>>>(
      p1, proj_w2, proj_b2, out, B_DIM, 256, NT_DIM);
}

// Round 3
// 1101.541 us; speedup vs baseline: 3.8416x; 1.7253x over previous
//
#include <hip/hip_runtime.h>
#include <hip/hip_bf16.h>

// AutoFormer forward. B=32 S=512 IN=256 D=512 H=8 L=2 DFF=2048 NT=424 K=25
#define S_LEN 512
#define D_DIM 512
#define B_DIM 32
#define IN_DIM 256
#define DFF_DIM 2048
#define NT_DIM 424

static constexpr size_t SZ = (size_t)B_DIM * S_LEN * D_DIM; // 8388608 floats

using s8v = __attribute__((ext_vector_type(8))) short;
using f4v = __attribute__((ext_vector_type(4))) float;
typedef unsigned short ushortT;

__device__ __forceinline__ ushortT f2bf(float f) {
  unsigned u = __float_as_uint(f);
  u += 0x7FFFu + ((u >> 16) & 1u);   // RNE
  return (ushortT)(u >> 16);
}

__device__ __forceinline__ float gelu_tanh(float x) {
  float x3 = x * x * x;
  return 0.5f * x * (1.f + tanhf(0.7978845608028654f * (x + 0.044715f * x3)));
}

// ---------------------------------------------------------------------------
// Weight convert+transpose: W[Kp][N] fp32 -> Wt[N][Kp] bf16. z = matrix batch.
// grid (Kp/32, N/32, nmat), 256 threads
// ---------------------------------------------------------------------------
__global__ __launch_bounds__(256) void conv_w(
    const float* __restrict__ W, ushortT* __restrict__ Wt, int Kp, int N)
{
  __shared__ float T[32][33];
  const int z = blockIdx.z;
  W  += (size_t)z * Kp * N;
  Wt += (size_t)z * N * Kp;
  const int k0 = blockIdx.x * 32, n0 = blockIdx.y * 32;
  const int tid = threadIdx.x;
  const int col = tid & 31, r8 = tid >> 5;
#pragma unroll
  for (int it = 0; it < 4; ++it) {
    int row = r8 + it * 8;
    T[row][col] = W[(size_t)(k0 + row) * N + n0 + col];
  }
  __syncthreads();
  const int nl = tid >> 3, kq = tid & 7;
#pragma unroll
  for (int j = 0; j < 4; ++j) {
    int kl = kq * 4 + j;
    Wt[(size_t)(n0 + nl) * Kp + k0 + kl] = f2bf(T[kl][nl]);
  }
}

// fp32 -> bf16 elementwise (float4 granular)
__global__ __launch_bounds__(256) void cvt_bf16(
    const float* __restrict__ in, ushortT* __restrict__ out, int n4)
{
  int i = blockIdx.x * 256 + threadIdx.x;
  if (i >= n4) return;
  float4 v = ((const float4*)in)[i];
  ushortT o[4] = {f2bf(v.x), f2bf(v.y), f2bf(v.z), f2bf(v.w)};
  *(uint2*)&out[(size_t)i * 4] = *(const uint2*)o;
}

// ---------------------------------------------------------------------------
// bf16 MFMA GEMM: C[M,N] = act(A[M,Kp] @ Wt[N,Kp]^T + bias (+res))
// A, Wt bf16. 128x128 tile, BK=32, 4 waves, wave = 64x64 (4x4 frags 16x16x32).
// Both tiles staged via global_load_lds(16B) with XOR-swizzled sources:
//   kq' = kq ^ ((row>>1)&3)  -> ds_read_b128 conflict-free (8 lanes/quad).
// OUT: 0 fp32 only, 1 fp32+bf16, 2 bf16 only. M%128==0, N%128==0, Kp%32==0.
// ---------------------------------------------------------------------------
template<int ACT, int RES, int OUT>
__global__ __launch_bounds__(256) void gemm_bf16(
    const ushortT* __restrict__ A, const ushortT* __restrict__ Wt,
    const float* __restrict__ bias, const float* __restrict__ res,
    float* __restrict__ C, ushortT* __restrict__ Cb, int M, int Kp, int N)
{
  __shared__ ushortT Ash[128 * 32];
  __shared__ ushortT Wsh[128 * 32];
  const int tid = threadIdx.x;
  const int lane = tid & 63, wid = tid >> 6;
  const int fr = lane & 15, kq = lane >> 4;
  const int wr = wid >> 1, wc = wid & 1;
  const int m0 = blockIdx.y * 128, n0 = blockIdx.x * 128;

  // staging: 8 chunks of 1KB (16 rows each); wave wid owns chunks 2wid,2wid+1
  int srow[2], skq[2];
#pragma unroll
  for (int t = 0; t < 2; ++t) {
    int ch = wid * 2 + t;
    int row = ch * 16 + (lane >> 2);
    int kql = lane & 3;
    srow[t] = row;
    skq[t] = kql ^ ((row >> 1) & 3);
  }

  // swizzled LDS read offsets (ushort index), constant across k-steps
  int aoff[4], boff[4];
#pragma unroll
  for (int i = 0; i < 4; ++i) {
    int ra = wr * 64 + i * 16 + fr;
    aoff[i] = ra * 32 + ((kq ^ ((ra >> 1) & 3)) << 3);
    int rb = wc * 64 + i * 16 + fr;
    boff[i] = rb * 32 + ((kq ^ ((rb >> 1) & 3)) << 3);
  }

  f4v acc[4][4] = {};

  for (int k0 = 0; k0 < Kp; k0 += 32) {
    __syncthreads();                    // prior tile reads done
#pragma unroll
    for (int t = 0; t < 2; ++t) {
      const ushortT* as = A + (size_t)(m0 + srow[t]) * Kp + k0 + skq[t] * 8;
      __builtin_amdgcn_global_load_lds(
          (const __attribute__((address_space(1))) unsigned int*)as,
          (__attribute__((address_space(3))) unsigned int*)&Ash[(wid * 2 + t) * 512],
          16, 0, 0);
      const ushortT* wsrc = Wt + (size_t)(n0 + srow[t]) * Kp + k0 + skq[t] * 8;
      __builtin_amdgcn_global_load_lds(
          (const __attribute__((address_space(1))) unsigned int*)wsrc,
          (__attribute__((address_space(3))) unsigned int*)&Wsh[(wid * 2 + t) * 512],
          16, 0, 0);
    }
    __syncthreads();                    // staging drained (vmcnt0 at barrier)
    s8v af[4], bfv[4];
#pragma unroll
    for (int i = 0; i < 4; ++i) {
      af[i]  = *(const s8v*)&Ash[aoff[i]];
      bfv[i] = *(const s8v*)&Wsh[boff[i]];
    }
#pragma unroll
    for (int i = 0; i < 4; ++i)
#pragma unroll
      for (int j = 0; j < 4; ++j)
        acc[i][j] = __builtin_amdgcn_mfma_f32_16x16x32_bf16(af[i], bfv[j], acc[i][j], 0, 0, 0);
  }

  // epilogue: C/D layout col=lane&15, row=(lane>>4)*4+reg
#pragma unroll
  for (int j = 0; j < 4; ++j) {
    const int gc = n0 + wc * 64 + j * 16 + fr;
    const float bv = bias[gc];
#pragma unroll
    for (int i = 0; i < 4; ++i)
#pragma unroll
      for (int r = 0; r < 4; ++r) {
        const int gr = m0 + wr * 64 + i * 16 + kq * 4 + r;
        float v = acc[i][j][r] + bv;
        if (RES) v += res[(size_t)gr * N + gc];
        if (ACT == 1) v = gelu_tanh(v);
        if (OUT != 2) C[(size_t)gr * N + gc] = v;
        if (OUT != 0) Cb[(size_t)gr * N + gc] = f2bf(v);
      }
  }
}

// ---------------------------------------------------------------------------
// Fused auto-correlation, 8 channels per block; writes bf16 result.
// corr[tau] = sum_s Q[(s+tau)%S]*K[s]; out = softmax_tau(corr) * V
// ---------------------------------------------------------------------------
__global__ __launch_bounds__(256) void autocorr8(
    const float* __restrict__ Q, const float* __restrict__ Km,
    const float* __restrict__ V, ushortT* __restrict__ Ob)
{
  __shared__ float qs[8 * 1024];  // XOR-swizzled, Q duplicated (kills %S)
  __shared__ float ks[8 * 520];   // K, later reused for softmax weights
  const int tid = threadIdx.x;
  const int b = blockIdx.x >> 6;
  const int c0 = (blockIdx.x & 63) << 3;
  const size_t base = (size_t)b * S_LEN * D_DIM + c0;

  for (int i = tid; i < 4096; i += 256) {
    int s = i >> 3, cc = i & 7;
    float qv = Q[base + (size_t)s * D_DIM + cc];
    int L0 = cc * 1024 + s;
    int L1 = L0 + 512;
    qs[L0 ^ (((L0 >> 7) & 3) << 2)] = qv;
    qs[L1 ^ (((L1 >> 7) & 3) << 2)] = qv;
    ks[cc * 520 + s] = Km[base + (size_t)s * D_DIM + cc];
  }
  __syncthreads();

  const int c = tid >> 5, tg = tid & 31, t0 = tg << 4; // 16 taus per thread
  const int cbase = c * 1024;
  float acc[16] = {};
  for (int s0 = 0; s0 < 512; s0 += 16) {
    float kr[16];
#pragma unroll
    for (int i = 0; i < 4; ++i)
      *(float4*)&kr[4 * i] = *(const float4*)&ks[c * 520 + s0 + 4 * i];
    float qw[32];
#pragma unroll
    for (int i = 0; i < 8; ++i) {
      int L = cbase + s0 + t0 + 4 * i;
      *(float4*)&qw[4 * i] = *(const float4*)&qs[L ^ (((L >> 7) & 3) << 2)];
    }
#pragma unroll
    for (int u = 0; u < 16; ++u)
#pragma unroll
      for (int t = 0; t < 16; ++t)
        acc[t] = fmaf(qw[t + u], kr[u], acc[t]);
  }

  // softmax over 512 taus per channel (32 threads per channel)
  float mx = acc[0];
#pragma unroll
  for (int t = 1; t < 16; ++t) mx = fmaxf(mx, acc[t]);
#pragma unroll
  for (int off = 16; off; off >>= 1) mx = fmaxf(mx, __shfl_xor(mx, off));
  float e[16], sum = 0.f;
#pragma unroll
  for (int t = 0; t < 16; ++t) { e[t] = __expf(acc[t] - mx); sum += e[t]; }
#pragma unroll
  for (int off = 16; off; off >>= 1) sum += __shfl_xor(sum, off);
  const float inv = 1.f / sum;

  __syncthreads();                 // everyone done reading ks
#pragma unroll
  for (int t = 0; t < 16; ++t) ks[c * 520 + t0 + t] = e[t] * inv;
  __syncthreads();

  for (int i = tid; i < 4096; i += 256) {
    int s = i >> 3, cc = i & 7;
    size_t a = base + (size_t)s * D_DIM + cc;
    Ob[a] = f2bf(ks[cc * 520 + s] * V[a]);
  }
}

// ---------------------------------------------------------------------------
// out = y - movavg(y, 25); writes fp32 + bf16; optional fused mean (atomics).
// block = (dtile 32 cols, batch b); LDS stripe [512 s][32 d] = 64KB.
// ---------------------------------------------------------------------------
template<int MEAN>
__global__ __launch_bounds__(256) void movavg_sub2(
    const float* __restrict__ y, float* __restrict__ outf,
    ushortT* __restrict__ outb, float* __restrict__ hm)
{
  __shared__ float ys[512 * 32];
  const int tid = threadIdx.x;
  const int b = blockIdx.y, d0 = blockIdx.x * 32;
  const float* yb = y + (size_t)b * S_LEN * D_DIM + d0;

#pragma unroll 4
  for (int p = 0; p < 16; ++p) {
    int i = p * 256 + tid;           // float4 index over [512][8]
    int s = i >> 3, dq = i & 7;
    float4 v = *(const float4*)(yb + (size_t)s * D_DIM + dq * 4);
    *(float4*)&ys[s * 32 + dq * 4] = v;
  }
  __syncthreads();

  const int d = tid & 31, sg = tid >> 5;
  float msum = 0.f;
  for (int it = 0; it < 64; ++it) {
    int s = sg + it * 8;
    int lo = max(s - 12, 0), hi = min(s + 13, S_LEN);
    float sum = 0.f;
    for (int t = lo; t < hi; ++t) sum += ys[t * 32 + d];
    float val = ys[s * 32 + d] - sum / (float)(hi - lo);
    size_t g = (size_t)b * S_LEN * D_DIM + (size_t)s * D_DIM + d0 + d;
    outf[g] = val;
    outb[g] = f2bf(val);
    if (MEAN) msum += val;
  }
  if (MEAN) atomicAdd(&hm[b * D_DIM + d0 + d], msum * (1.f / (float)S_LEN));
}

// ---------------------------------------------------------------------------
// Head: p1[32][256] = relu(hm[32][512] @ W1 + b1); out[32][424] = p1 @ W2 + b2
// ---------------------------------------------------------------------------
__global__ __launch_bounds__(256) void proj_head1(
    const float* __restrict__ hm, const float* __restrict__ W1,
    const float* __restrict__ b1, float* __restrict__ p1)
{
  __shared__ float hs[32 * 512];
  const int tid = threadIdx.x, n0 = blockIdx.x * 32;
  for (int i = tid; i < 16384; i += 256) hs[i] = hm[i];
  __syncthreads();
  const int n = tid & 31, mg = tid >> 5;
  float acc[4] = {};
  for (int k = 0; k < 512; ++k) {
    float w = W1[(size_t)k * 256 + n0 + n];
#pragma unroll
    for (int mi = 0; mi < 4; ++mi)
      acc[mi] = fmaf(hs[(mg * 4 + mi) * 512 + k], w, acc[mi]);
  }
  const float bb = b1[n0 + n];
#pragma unroll
  for (int mi = 0; mi < 4; ++mi)
    p1[(size_t)(mg * 4 + mi) * 256 + n0 + n] = fmaxf(acc[mi] + bb, 0.f);
}

__global__ __launch_bounds__(256) void proj_head2(
    const float* __restrict__ p1, const float* __restrict__ W2,
    const float* __restrict__ b2, float* __restrict__ out)
{
  __shared__ float ps[32 * 256];
  const int tid = threadIdx.x;
  for (int i = tid; i < 8192; i += 256) ps[i] = p1[i];
  __syncthreads();
  const int n = tid & 31, mg = tid >> 5;
  const int ng = blockIdx.x * 32 + n;
  const bool ok = ng < NT_DIM;
  float acc[4] = {};
  for (int k = 0; k < 256; ++k) {
    float w = ok ? W2[(size_t)k * NT_DIM + ng] : 0.f;
#pragma unroll
    for (int mi = 0; mi < 4; ++mi)
      acc[mi] = fmaf(ps[(mg * 4 + mi) * 256 + k], w, acc[mi]);
  }
  if (ok) {
    const float bb = b2[ng];
#pragma unroll
    for (int mi = 0; mi < 4; ++mi)
      out[(size_t)(mg * 4 + mi) * NT_DIM + ng] = acc[mi] + bb;
  }
}

// ---------------------------------------------------------------------------
extern "C" void kernel_launch(void* const* d_in, const int* in_sizes, int n_in,
                              void* d_out, int out_size, void* d_ws, size_t ws_size,
                              hipStream_t stream)
{
  const float* x       = (const float*)d_in[0];
  const float* embed_w = (const float*)d_in[1];
  const float* embed_b = (const float*)d_in[2];
  const float* qkvo_w  = (const float*)d_in[3];
  const float* qkvo_b  = (const float*)d_in[4];
  const float* ffn_w1  = (const float*)d_in[5];
  const float* ffn_b1  = (const float*)d_in[6];
  const float* ffn_w2  = (const float*)d_in[7];
  const float* ffn_b2  = (const float*)d_in[8];
  const float* proj_w1 = (const float*)d_in[9];
  const float* proj_b1 = (const float*)d_in[10];
  const float* proj_w2 = (const float*)d_in[11];
  const float* proj_b2 = (const float*)d_in[12];
  float* out = (float*)d_out;

  float* ws = (float*)d_ws;
  float* Bv = ws;              // V (fp32); overlaid by Hb (with Bh) during FFN
  float* Bh = ws + SZ;         // h (residual)
  float* Bq = ws + 2 * SZ;     // Q / y / y2; xb (bf16) during embed
  float* Bk = ws + 3 * SZ;     // K / x1 (seasonal, fp32)
  ushortT* Sb = (ushortT*)(ws + 4 * SZ);            // bf16 activation mirror, SZ ushorts
  ushortT* Wb = (ushortT*)(ws + 4 * SZ + SZ / 2);   // bf16 weights
  ushortT* embed_wt = Wb;                            // [512][256]
  ushortT* qkvo_wt  = embed_wt + (size_t)512 * 256;  // 8 x [512][512]
  ushortT* ffn1_wt  = qkvo_wt + (size_t)8 * 512 * 512;   // 2 x [2048][512]
  ushortT* ffn2_wt  = ffn1_wt + (size_t)2 * 2048 * 512;  // 2 x [512][2048]
  float* hm = (float*)(ffn2_wt + (size_t)2 * 512 * 2048); // [32][512]
  float* p1 = hm + 16384;                                  // [32][256]
  ushortT* Hb = (ushortT*)Bv;   // FFN hidden bf16 [16384][2048] = 64MB (Bv+Bh)
  ushortT* xb = (ushortT*)Bq;   // x bf16 during embed

  dim3 blk(256);

  hipMemsetAsync(hm, 0, 16384 * sizeof(float), stream);

  // weight conversions (batched over z)
  conv_w<<<dim3(8, 16, 1), blk, 0, stream>>>(embed_w, embed_wt, IN_DIM, D_DIM);
  conv_w<<<dim3(16, 16, 8), blk, 0, stream>>>(qkvo_w, qkvo_wt, 512, 512);
  conv_w<<<dim3(16, 64, 2), blk, 0, stream>>>(ffn_w1, ffn1_wt, 512, 2048);
  conv_w<<<dim3(64, 16, 2), blk, 0, stream>>>(ffn_w2, ffn2_wt, 2048, 512);

  // x -> bf16
  cvt_bf16<<<dim3(4096), blk, 0, stream>>>(x, xb, B_DIM * S_LEN * IN_DIM / 4);

  // embed: Bh(fp32) + Sb(bf16) = x @ We + be
  gemm_bf16<0, 0, 1><<<dim3(4, 128), blk, 0, stream>>>(
      xb, embed_wt, embed_b, nullptr, Bh, Sb, 16384, IN_DIM, D_DIM);

  for (int l = 0; l < 2; ++l) {
    const ushortT* qw = qkvo_wt + (size_t)l * 4 * 512 * 512;
    const float* qb = qkvo_b + (size_t)l * 4 * 512;
    gemm_bf16<0, 0, 0><<<dim3(4, 128), blk, 0, stream>>>(
        Sb, qw,                        qb,        nullptr, Bq, nullptr, 16384, 512, 512);
    gemm_bf16<0, 0, 0><<<dim3(4, 128), blk, 0, stream>>>(
        Sb, qw + (size_t)512 * 512,    qb + 512,  nullptr, Bk, nullptr, 16384, 512, 512);
    gemm_bf16<0, 0, 0><<<dim3(4, 128), blk, 0, stream>>>(
        Sb, qw + (size_t)2 * 512 * 512, qb + 1024, nullptr, Bv, nullptr, 16384, 512, 512);
    autocorr8<<<dim3(B_DIM * 64), blk, 0, stream>>>(Bq, Bk, Bv, Sb);
    gemm_bf16<0, 1, 0><<<dim3(4, 128), blk, 0, stream>>>(
        Sb, qw + (size_t)3 * 512 * 512, qb + 1536, Bh, Bq, nullptr, 16384, 512, 512);
    movavg_sub2<0><<<dim3(16, 32), blk, 0, stream>>>(Bq, Bk, Sb, nullptr);
    // FFN (hidden bf16 overlays Bv+Bh, both dead here)
    gemm_bf16<1, 0, 2><<<dim3(16, 128), blk, 0, stream>>>(
        Sb, ffn1_wt + (size_t)l * 2048 * 512, ffn_b1 + (size_t)l * DFF_DIM,
        nullptr, nullptr, Hb, 16384, 512, 2048);
    gemm_bf16<0, 1, 0><<<dim3(4, 128), blk, 0, stream>>>(
        Hb, ffn2_wt + (size_t)l * 512 * 2048, ffn_b2 + (size_t)l * D_DIM,
        Bk, Bq, nullptr, 16384, 2048, 512);
    if (l == 1)
      movavg_sub2<1><<<dim3(16, 32), blk, 0, stream>>>(Bq, Bh, Sb, hm);
    else
      movavg_sub2<0><<<dim3(16, 32), blk, 0, stream>>>(Bq, Bh, Sb, nullptr);
  }

  proj_head1<<<dim3(8), blk, 0, stream>>>(hm, proj_w1, proj_b1, p1);
  proj_head2<<<dim3(14), blk, 0, stream>>>(p1, proj_w2, proj_b2, out);
}

// Round 6
// 1044.766 us; speedup vs baseline: 4.0503x; 1.0543x over previous
//
#include <hip/hip_runtime.h>
#include <hip/hip_bf16.h>

// AutoFormer forward. B=32 S=512 IN=256 D=512 H=8 L=2 DFF=2048 NT=424 K=25
#define S_LEN 512
#define D_DIM 512
#define B_DIM 32
#define IN_DIM 256
#define DFF_DIM 2048
#define NT_DIM 424

static constexpr size_t SZ = (size_t)B_DIM * S_LEN * D_DIM; // 8388608

using s8v = __attribute__((ext_vector_type(8))) short;
using f4v = __attribute__((ext_vector_type(4))) float;
typedef unsigned short ushortT;

__device__ __forceinline__ ushortT f2bf(float f) {
  unsigned u = __float_as_uint(f);
  u += 0x7FFFu + ((u >> 16) & 1u);   // RNE
  return (ushortT)(u >> 16);
}

__device__ __forceinline__ float gelu_tanh(float x) {
  float x3 = x * x * x;
  return 0.5f * x * (1.f + tanhf(0.7978845608028654f * (x + 0.044715f * x3)));
}

// ---------------------------------------------------------------------------
// Weight convert+transpose: W[Kp][N] fp32 -> Wt[N][Kp] bf16. z = matrix batch.
// ---------------------------------------------------------------------------
__global__ __launch_bounds__(256) void conv_w(
    const float* __restrict__ W, ushortT* __restrict__ Wt, int Kp, int N)
{
  __shared__ float T[32][33];
  const int z = blockIdx.z;
  W  += (size_t)z * Kp * N;
  Wt += (size_t)z * N * Kp;
  const int k0 = blockIdx.x * 32, n0 = blockIdx.y * 32;
  const int tid = threadIdx.x;
  const int col = tid & 31, r8 = tid >> 5;
#pragma unroll
  for (int it = 0; it < 4; ++it) {
    int row = r8 + it * 8;
    T[row][col] = W[(size_t)(k0 + row) * N + n0 + col];
  }
  __syncthreads();
  const int nl = tid >> 3, kq = tid & 7;
#pragma unroll
  for (int j = 0; j < 4; ++j) {
    int kl = kq * 4 + j;
    Wt[(size_t)(n0 + nl) * Kp + k0 + kl] = f2bf(T[kl][nl]);
  }
}

__global__ __launch_bounds__(256) void cvt_bf16(
    const float* __restrict__ in, ushortT* __restrict__ out, int n4)
{
  int i = blockIdx.x * 256 + threadIdx.x;
  if (i >= n4) return;
  float4 v = ((const float4*)in)[i];
  ushortT o[4] = {f2bf(v.x), f2bf(v.y), f2bf(v.z), f2bf(v.w)};
  *(uint2*)&out[(size_t)i * 4] = *(const uint2*)o;
}

// ---------------------------------------------------------------------------
// bf16 MFMA GEMM. OUT: 0 fp32 only, 1 fp32+bf16, 2 bf16 only,
// 3 = fused QKV (N=1536): cols [0,512) -> Qt fp32 transposed [b][c][s],
//     cols [512,1024) -> Kt fp32 transposed, cols [1024,1536) -> C fp32
//     plain [row][c] (V).
// ---------------------------------------------------------------------------
template<int ACT, int RES, int OUT>
__global__ __launch_bounds__(256) void gemm_bf16(
    const ushortT* __restrict__ A, const ushortT* __restrict__ Wt,
    const float* __restrict__ bias, const float* __restrict__ res,
    float* __restrict__ C, ushortT* __restrict__ Cb,
    float* __restrict__ Qt, float* __restrict__ Kt, int M, int Kp, int N)
{
  __shared__ ushortT Ash[128 * 32];
  __shared__ ushortT Wsh[128 * 32];
  const int tid = threadIdx.x;
  const int lane = tid & 63, wid = tid >> 6;
  const int fr = lane & 15, kq = lane >> 4;
  const int wr = wid >> 1, wc = wid & 1;
  const int m0 = blockIdx.y * 128, n0 = blockIdx.x * 128;

  int srow[2], skq[2];
#pragma unroll
  for (int t = 0; t < 2; ++t) {
    int ch = wid * 2 + t;
    int row = ch * 16 + (lane >> 2);
    int kql = lane & 3;
    srow[t] = row;
    skq[t] = kql ^ ((row >> 1) & 3);
  }

  int aoff[4], boff[4];
#pragma unroll
  for (int i = 0; i < 4; ++i) {
    int ra = wr * 64 + i * 16 + fr;
    aoff[i] = ra * 32 + ((kq ^ ((ra >> 1) & 3)) << 3);
    int rb = wc * 64 + i * 16 + fr;
    boff[i] = rb * 32 + ((kq ^ ((rb >> 1) & 3)) << 3);
  }

  f4v acc[4][4] = {};

  for (int k0 = 0; k0 < Kp; k0 += 32) {
    __syncthreads();
#pragma unroll
    for (int t = 0; t < 2; ++t) {
      const ushortT* as = A + (size_t)(m0 + srow[t]) * Kp + k0 + skq[t] * 8;
      __builtin_amdgcn_global_load_lds(
          (const __attribute__((address_space(1))) unsigned int*)as,
          (__attribute__((address_space(3))) unsigned int*)&Ash[(wid * 2 + t) * 512],
          16, 0, 0);
      const ushortT* wsrc = Wt + (size_t)(n0 + srow[t]) * Kp + k0 + skq[t] * 8;
      __builtin_amdgcn_global_load_lds(
          (const __attribute__((address_space(1))) unsigned int*)wsrc,
          (__attribute__((address_space(3))) unsigned int*)&Wsh[(wid * 2 + t) * 512],
          16, 0, 0);
    }
    __syncthreads();
    s8v af[4], bfv[4];
#pragma unroll
    for (int i = 0; i < 4; ++i) {
      af[i]  = *(const s8v*)&Ash[aoff[i]];
      bfv[i] = *(const s8v*)&Wsh[boff[i]];
    }
#pragma unroll
    for (int i = 0; i < 4; ++i)
#pragma unroll
      for (int j = 0; j < 4; ++j)
        acc[i][j] = __builtin_amdgcn_mfma_f32_16x16x32_bf16(af[i], bfv[j], acc[i][j], 0, 0, 0);
  }

  // epilogue: C/D layout col=lane&15, row=(lane>>4)*4+reg
#pragma unroll
  for (int j = 0; j < 4; ++j) {
    const int gc = n0 + wc * 64 + j * 16 + fr;
    const float bv = bias[gc];
#pragma unroll
    for (int i = 0; i < 4; ++i) {
      const int gr0 = m0 + wr * 64 + i * 16 + kq * 4;
      if (OUT == 3) {
        if (gc < 1024) {           // Q or K -> fp32 transposed [b][c][s]
          float* dst = (gc < 512 ? Qt : Kt)
                     + ((size_t)(gr0 >> 9) * 512 + (gc & 511)) * 512 + (gr0 & 511);
          float4 ov;
          ov.x = acc[i][j][0] + bv;
          ov.y = acc[i][j][1] + bv;
          ov.z = acc[i][j][2] + bv;
          ov.w = acc[i][j][3] + bv;
          *(float4*)dst = ov;
        } else {                   // V -> fp32 plain [row][c]
#pragma unroll
          for (int r = 0; r < 4; ++r)
            C[(size_t)(gr0 + r) * D_DIM + (gc & 511)] = acc[i][j][r] + bv;
        }
      } else {
#pragma unroll
        for (int r = 0; r < 4; ++r) {
          const int gr = gr0 + r;
          float v = acc[i][j][r] + bv;
          if (RES) v += res[(size_t)gr * N + gc];
          if (ACT == 1) v = gelu_tanh(v);
          if (OUT != 2) C[(size_t)gr * N + gc] = v;
          if (OUT != 0) Cb[(size_t)gr * N + gc] = f2bf(v);   // FIXED (was OUT==1)
        }
      }
    }
  }
}

// ---------------------------------------------------------------------------
// Fused auto-correlation, 8 channels/block. Q,K fp32 transposed [b][c][s]
// (coalesced float4 loads); V fp32 [b][s][c]; out bf16 [b][s][c].
// corr[tau] = sum_s Q[(s+tau)%S]*K[s]; out = softmax_tau(corr) * V
// No Q duplication (wrap via &511); 3-bit XOR swizzle -> ~2-way banks.
// ---------------------------------------------------------------------------
__global__ __launch_bounds__(256) void autocorr8(
    const float* __restrict__ QT, const float* __restrict__ KT,
    const float* __restrict__ V, ushortT* __restrict__ Ob)
{
  __shared__ float qs[8 * 512];   // XOR-swizzled
  __shared__ float ks[8 * 520];   // K; later reused for softmax weights
  const int tid = threadIdx.x;
  const int b = blockIdx.x >> 6;
  const int c0 = (blockIdx.x & 63) << 3;

  const float* Qg = QT + ((size_t)b * 512 + c0) * 512;
  const float* Kg = KT + ((size_t)b * 512 + c0) * 512;
  for (int chk = tid; chk < 1024; chk += 256) {  // float4 chunks: 8ch x 128
    int cc = chk >> 7, s4 = (chk & 127) << 2;
    float4 qv = *(const float4*)&Qg[cc * 512 + s4];
    int i0 = cc * 512 + s4;
    *(float4*)&qs[i0 ^ (((i0 >> 6) & 7) << 2)] = qv;
    *(float4*)&ks[cc * 520 + s4] = *(const float4*)&Kg[cc * 512 + s4];
  }
  __syncthreads();

  const int c = tid >> 5, tg = tid & 31, t0 = tg << 4; // 16 taus/thread
  const int cbase = c * 512;
  float acc[16] = {};
  for (int s0 = 0; s0 < 512; s0 += 16) {
    float kr[16];
#pragma unroll
    for (int i = 0; i < 4; ++i)
      *(float4*)&kr[4 * i] = *(const float4*)&ks[c * 520 + s0 + 4 * i];
    float qw[32];
#pragma unroll
    for (int i = 0; i < 8; ++i) {
      int L = cbase + ((s0 + t0 + 4 * i) & 511);
      *(float4*)&qw[4 * i] = *(const float4*)&qs[L ^ (((L >> 6) & 7) << 2)];
    }
#pragma unroll
    for (int u = 0; u < 16; ++u)
#pragma unroll
      for (int t = 0; t < 16; ++t)
        acc[t] = fmaf(qw[t + u], kr[u], acc[t]);
  }

  // softmax over 512 taus per channel (32 threads/channel)
  float mx = acc[0];
#pragma unroll
  for (int t = 1; t < 16; ++t) mx = fmaxf(mx, acc[t]);
#pragma unroll
  for (int off = 16; off; off >>= 1) mx = fmaxf(mx, __shfl_xor(mx, off));
  float ex[16], sum = 0.f;
#pragma unroll
  for (int t = 0; t < 16; ++t) { ex[t] = __expf(acc[t] - mx); sum += ex[t]; }
#pragma unroll
  for (int off = 16; off; off >>= 1) sum += __shfl_xor(sum, off);
  const float inv = 1.f / sum;

  __syncthreads();                // all ks reads done before overwrite
#pragma unroll
  for (int t = 0; t < 16; ++t) ks[c * 520 + t0 + t] = ex[t] * inv;
  __syncthreads();

  const size_t base = (size_t)b * S_LEN * D_DIM + c0;
  for (int i = tid; i < 4096; i += 256) {
    int s = i >> 3, cc = i & 7;
    size_t a = base + (size_t)s * D_DIM + cc;
    Ob[a] = f2bf(ks[cc * 520 + s] * V[a]);
  }
}

// ---------------------------------------------------------------------------
template<int MEAN>
__global__ __launch_bounds__(256) void movavg_sub2(
    const float* __restrict__ y, float* __restrict__ outf,
    ushortT* __restrict__ outb, float* __restrict__ hm)
{
  __shared__ float ys[512 * 32];
  const int tid = threadIdx.x;
  const int b = blockIdx.y, d0 = blockIdx.x * 32;
  const float* yb = y + (size_t)b * S_LEN * D_DIM + d0;

#pragma unroll 4
  for (int p = 0; p < 16; ++p) {
    int i = p * 256 + tid;
    int s = i >> 3, dq = i & 7;
    float4 v = *(const float4*)(yb + (size_t)s * D_DIM + dq * 4);
    *(float4*)&ys[s * 32 + dq * 4] = v;
  }
  __syncthreads();

  const int d = tid & 31, sg = tid >> 5;
  float msum = 0.f;
  for (int it = 0; it < 64; ++it) {
    int s = sg + it * 8;
    int lo = max(s - 12, 0), hi = min(s + 13, S_LEN);
    float sum = 0.f;
    for (int t = lo; t < hi; ++t) sum += ys[t * 32 + d];
    float val = ys[s * 32 + d] - sum / (float)(hi - lo);
    size_t g = (size_t)b * S_LEN * D_DIM + (size_t)s * D_DIM + d0 + d;
    outf[g] = val;
    outb[g] = f2bf(val);
    if (MEAN) msum += val;
  }
  if (MEAN) atomicAdd(&hm[b * D_DIM + d0 + d], msum * (1.f / (float)S_LEN));
}

// ---------------------------------------------------------------------------
__global__ __launch_bounds__(256) void proj_head1(
    const float* __restrict__ hm, const float* __restrict__ W1,
    const float* __restrict__ b1, float* __restrict__ p1)
{
  __shared__ float hs[32 * 512];
  const int tid = threadIdx.x, n0 = blockIdx.x * 32;
  for (int i = tid; i < 16384; i += 256) hs[i] = hm[i];
  __syncthreads();
  const int n = tid & 31, mg = tid >> 5;
  float acc[4] = {};
  for (int k = 0; k < 512; ++k) {
    float w = W1[(size_t)k * 256 + n0 + n];
#pragma unroll
    for (int mi = 0; mi < 4; ++mi)
      acc[mi] = fmaf(hs[(mg * 4 + mi) * 512 + k], w, acc[mi]);
  }
  const float bb = b1[n0 + n];
#pragma unroll
  for (int mi = 0; mi < 4; ++mi)
    p1[(size_t)(mg * 4 + mi) * 256 + n0 + n] = fmaxf(acc[mi] + bb, 0.f);
}

__global__ __launch_bounds__(256) void proj_head2(
    const float* __restrict__ p1, const float* __restrict__ W2,
    const float* __restrict__ b2, float* __restrict__ out)
{
  __shared__ float ps[32 * 256];
  const int tid = threadIdx.x;
  for (int i = tid; i < 8192; i += 256) ps[i] = p1[i];
  __syncthreads();
  const int n = tid & 31, mg = tid >> 5;
  const int ng = blockIdx.x * 32 + n;
  const bool ok = ng < NT_DIM;
  float acc[4] = {};
  for (int k = 0; k < 256; ++k) {
    float w = ok ? W2[(size_t)k * NT_DIM + ng] : 0.f;
#pragma unroll
    for (int mi = 0; mi < 4; ++mi)
      acc[mi] = fmaf(ps[(mg * 4 + mi) * 256 + k], w, acc[mi]);
  }
  if (ok) {
    const float bb = b2[ng];
#pragma unroll
    for (int mi = 0; mi < 4; ++mi)
      out[(size_t)(mg * 4 + mi) * NT_DIM + ng] = acc[mi] + bb;
  }
}

// ---------------------------------------------------------------------------
extern "C" void kernel_launch(void* const* d_in, const int* in_sizes, int n_in,
                              void* d_out, int out_size, void* d_ws, size_t ws_size,
                              hipStream_t stream)
{
  const float* x       = (const float*)d_in[0];
  const float* embed_w = (const float*)d_in[1];
  const float* embed_b = (const float*)d_in[2];
  const float* qkvo_w  = (const float*)d_in[3];
  const float* qkvo_b  = (const float*)d_in[4];
  const float* ffn_w1  = (const float*)d_in[5];
  const float* ffn_b1  = (const float*)d_in[6];
  const float* ffn_w2  = (const float*)d_in[7];
  const float* ffn_b2  = (const float*)d_in[8];
  const float* proj_w1 = (const float*)d_in[9];
  const float* proj_b1 = (const float*)d_in[10];
  const float* proj_w2 = (const float*)d_in[11];
  const float* proj_b2 = (const float*)d_in[12];
  float* out = (float*)d_out;

  float* ws = (float*)d_ws;
  float* Bv = ws;              // V fp32; overlaid by Hb during FFN
  float* Bh = ws + SZ;         // h (residual); overlaid by Hb during FFN
  float* Bq = ws + 2 * SZ;     // Q fp32T -> y (fp32); xb during embed
  float* Bk = ws + 3 * SZ;     // K fp32T -> x1 (seasonal, fp32)
  ushortT* Sb = (ushortT*)(ws + 4 * SZ);            // bf16 activation mirror
  ushortT* Wb = (ushortT*)(ws + 4 * SZ + SZ / 2);   // bf16 weights
  ushortT* embed_wt = Wb;                            // [512][256]
  ushortT* qkvo_wt  = embed_wt + (size_t)512 * 256;  // 8 x [512][512]
  ushortT* ffn1_wt  = qkvo_wt + (size_t)8 * 512 * 512;   // 2 x [2048][512]
  ushortT* ffn2_wt  = ffn1_wt + (size_t)2 * 2048 * 512;  // 2 x [512][2048]
  float* hm = (float*)(ffn2_wt + (size_t)2 * 512 * 2048); // [32][512]
  float* p1 = hm + 16384;                                  // [32][256]
  ushortT* Hb  = (ushortT*)Bv;   // FFN hidden bf16 [16384][2048] (Bv+Bh)
  ushortT* xb  = (ushortT*)Bq;   // x bf16 during embed

  dim3 blk(256);

  hipMemsetAsync(hm, 0, 16384 * sizeof(float), stream);

  conv_w<<<dim3(8, 16, 1), blk, 0, stream>>>(embed_w, embed_wt, IN_DIM, D_DIM);
  conv_w<<<dim3(16, 16, 8), blk, 0, stream>>>(qkvo_w, qkvo_wt, 512, 512);
  conv_w<<<dim3(16, 64, 2), blk, 0, stream>>>(ffn_w1, ffn1_wt, 512, 2048);
  conv_w<<<dim3(64, 16, 2), blk, 0, stream>>>(ffn_w2, ffn2_wt, 2048, 512);

  cvt_bf16<<<dim3(4096), blk, 0, stream>>>(x, xb, B_DIM * S_LEN * IN_DIM / 4);

  // embed: Bh(fp32) + Sb(bf16) = x @ We + be
  gemm_bf16<0, 0, 1><<<dim3(4, 128), blk, 0, stream>>>(
      xb, embed_wt, embed_b, nullptr, Bh, Sb, nullptr, nullptr, 16384, IN_DIM, D_DIM);

  for (int l = 0; l < 2; ++l) {
    const ushortT* qw = qkvo_wt + (size_t)l * 4 * 512 * 512;
    const float* qb = qkvo_b + (size_t)l * 4 * 512;
    // fused QKV: Q -> Bq (fp32T), K -> Bk (fp32T), V -> Bv (fp32 plain)
    gemm_bf16<0, 0, 3><<<dim3(12, 128), blk, 0, stream>>>(
        Sb, qw, qb, nullptr, Bv, nullptr, Bq, Bk, 16384, 512, 1536);
    autocorr8<<<dim3(B_DIM * 64), blk, 0, stream>>>(Bq, Bk, Bv, Sb);
    // y = attn @ Wo + bo + h  (overwrites Bq; Q dead)
    gemm_bf16<0, 1, 0><<<dim3(4, 128), blk, 0, stream>>>(
        Sb, qw + (size_t)3 * 512 * 512, qb + 1536, Bh, Bq, nullptr, nullptr, nullptr,
        16384, 512, 512);
    movavg_sub2<0><<<dim3(16, 32), blk, 0, stream>>>(Bq, Bk, Sb, nullptr);
    // FFN (hidden bf16 overlays Bv+Bh, both dead)
    gemm_bf16<1, 0, 2><<<dim3(16, 128), blk, 0, stream>>>(
        Sb, ffn1_wt + (size_t)l * 2048 * 512, ffn_b1 + (size_t)l * DFF_DIM,
        nullptr, nullptr, Hb, nullptr, nullptr, 16384, 512, 2048);
    gemm_bf16<0, 1, 0><<<dim3(4, 128), blk, 0, stream>>>(
        Hb, ffn2_wt + (size_t)l * 512 * 2048, ffn_b2 + (size_t)l * D_DIM,
        Bk, Bq, nullptr, nullptr, nullptr, 16384, 2048, 512);
    if (l == 1)
      movavg_sub2<1><<<dim3(16, 32), blk, 0, stream>>>(Bq, Bh, Sb, hm);
    else
      movavg_sub2<0><<<dim3(16, 32), blk, 0, stream>>>(Bq, Bh, Sb, nullptr);
  }

  proj_head1<<<dim3(8), blk, 0, stream>>>(hm, proj_w1, proj_b1, p1);
  proj_head2<<<dim3(14), blk, 0, stream>>>(p1, proj_w2, proj_b2, out);
}

// Round 7
// 930.843 us; speedup vs baseline: 4.5460x; 1.1224x over previous
//
#include <hip/hip_runtime.h>
#include <hip/hip_bf16.h>

// AutoFormer forward. B=32 S=512 IN=256 D=512 H=8 L=2 DFF=2048 NT=424 K=25
#define S_LEN 512
#define D_DIM 512
#define B_DIM 32
#define IN_DIM 256
#define DFF_DIM 2048
#define NT_DIM 424

static constexpr size_t SZ = (size_t)B_DIM * S_LEN * D_DIM; // 8388608

using s8v = __attribute__((ext_vector_type(8))) short;
using f4v = __attribute__((ext_vector_type(4))) float;
typedef unsigned short ushortT;
typedef __attribute__((ext_vector_type(2))) _Float16 h2f;

__device__ __forceinline__ ushortT f2bf(float f) {
  unsigned u = __float_as_uint(f);
  u += 0x7FFFu + ((u >> 16) & 1u);   // RNE
  return (ushortT)(u >> 16);
}

__device__ __forceinline__ h2f u2h2(unsigned u) {
  union { unsigned u; h2f h; } x; x.u = u; return x.h;
}

__device__ __forceinline__ float gelu_tanh(float x) {
  float x3 = x * x * x;
  return 0.5f * x * (1.f + tanhf(0.7978845608028654f * (x + 0.044715f * x3)));
}

// ---------------------------------------------------------------------------
// Weight convert+transpose: W[Kp][N] fp32 -> Wt[N][Kp] bf16. z = matrix batch.
// ---------------------------------------------------------------------------
__global__ __launch_bounds__(256) void conv_w(
    const float* __restrict__ W, ushortT* __restrict__ Wt, int Kp, int N)
{
  __shared__ float T[32][33];
  const int z = blockIdx.z;
  W  += (size_t)z * Kp * N;
  Wt += (size_t)z * N * Kp;
  const int k0 = blockIdx.x * 32, n0 = blockIdx.y * 32;
  const int tid = threadIdx.x;
  const int col = tid & 31, r8 = tid >> 5;
#pragma unroll
  for (int it = 0; it < 4; ++it) {
    int row = r8 + it * 8;
    T[row][col] = W[(size_t)(k0 + row) * N + n0 + col];
  }
  __syncthreads();
  const int nl = tid >> 3, kq = tid & 7;
#pragma unroll
  for (int j = 0; j < 4; ++j) {
    int kl = kq * 4 + j;
    Wt[(size_t)(n0 + nl) * Kp + k0 + kl] = f2bf(T[kl][nl]);
  }
}

__global__ __launch_bounds__(256) void cvt_bf16(
    const float* __restrict__ in, ushortT* __restrict__ out, int n4)
{
  int i = blockIdx.x * 256 + threadIdx.x;
  if (i >= n4) return;
  float4 v = ((const float4*)in)[i];
  ushortT o[4] = {f2bf(v.x), f2bf(v.y), f2bf(v.z), f2bf(v.w)};
  *(uint2*)&out[(size_t)i * 4] = *(const uint2*)o;
}

// ---------------------------------------------------------------------------
// bf16 MFMA GEMM, 2-phase double-buffered pipeline (one barrier per K-step;
// next tile's global_load_lds issued before computing current tile).
// OUT: 0 fp32 only, 1 fp32+bf16, 2 bf16 only,
// 3 = fused QKV (N=1536): cols [0,512) -> Qh fp16 transposed [b][c][s],
//     cols [512,1024) -> Kh fp16 transposed, cols [1024,1536) -> C fp32
//     plain [row][c] (V).
// ---------------------------------------------------------------------------
template<int ACT, int RES, int OUT>
__global__ __launch_bounds__(256) void gemm_bf16(
    const ushortT* __restrict__ A, const ushortT* __restrict__ Wt,
    const float* __restrict__ bias, const float* __restrict__ res,
    float* __restrict__ C, ushortT* __restrict__ Cb,
    ushortT* __restrict__ Qh, ushortT* __restrict__ Kh, int M, int Kp, int N)
{
  __shared__ ushortT Ash[2][128 * 32];
  __shared__ ushortT Wsh[2][128 * 32];
  const int tid = threadIdx.x;
  const int lane = tid & 63, wid = tid >> 6;
  const int fr = lane & 15, kq = lane >> 4;
  const int wr = wid >> 1, wc = wid & 1;
  const int m0 = blockIdx.y * 128, n0 = blockIdx.x * 128;

  int srow[2], skq[2];
#pragma unroll
  for (int t = 0; t < 2; ++t) {
    int ch = wid * 2 + t;
    int row = ch * 16 + (lane >> 2);
    int kql = lane & 3;
    srow[t] = row;
    skq[t] = kql ^ ((row >> 1) & 3);
  }

  int aoff[4], boff[4];
#pragma unroll
  for (int i = 0; i < 4; ++i) {
    int ra = wr * 64 + i * 16 + fr;
    aoff[i] = ra * 32 + ((kq ^ ((ra >> 1) & 3)) << 3);
    int rb = wc * 64 + i * 16 + fr;
    boff[i] = rb * 32 + ((kq ^ ((rb >> 1) & 3)) << 3);
  }

  auto STAGE = [&](int buf, int k0) {
#pragma unroll
    for (int t = 0; t < 2; ++t) {
      const ushortT* as = A + (size_t)(m0 + srow[t]) * Kp + k0 + skq[t] * 8;
      __builtin_amdgcn_global_load_lds(
          (const __attribute__((address_space(1))) unsigned int*)as,
          (__attribute__((address_space(3))) unsigned int*)&Ash[buf][(wid * 2 + t) * 512],
          16, 0, 0);
      const ushortT* wsrc = Wt + (size_t)(n0 + srow[t]) * Kp + k0 + skq[t] * 8;
      __builtin_amdgcn_global_load_lds(
          (const __attribute__((address_space(1))) unsigned int*)wsrc,
          (__attribute__((address_space(3))) unsigned int*)&Wsh[buf][(wid * 2 + t) * 512],
          16, 0, 0);
    }
  };

  f4v acc[4][4] = {};
  STAGE(0, 0);
  int cur = 0;

  for (int k0 = 0; k0 < Kp; k0 += 32) {
    __syncthreads();              // drains pending STAGE (vmcnt0) + sync reads
    if (k0 + 32 < Kp) STAGE(cur ^ 1, k0 + 32);
    s8v af[4], bfv[4];
#pragma unroll
    for (int i = 0; i < 4; ++i) {
      af[i]  = *(const s8v*)&Ash[cur][aoff[i]];
      bfv[i] = *(const s8v*)&Wsh[cur][boff[i]];
    }
#pragma unroll
    for (int i = 0; i < 4; ++i)
#pragma unroll
      for (int j = 0; j < 4; ++j)
        acc[i][j] = __builtin_amdgcn_mfma_f32_16x16x32_bf16(af[i], bfv[j], acc[i][j], 0, 0, 0);
    cur ^= 1;
  }

  // epilogue: C/D layout col=lane&15, row=(lane>>4)*4+reg
#pragma unroll
  for (int j = 0; j < 4; ++j) {
    const int gc = n0 + wc * 64 + j * 16 + fr;
    const float bv = bias[gc];
#pragma unroll
    for (int i = 0; i < 4; ++i) {
      const int gr0 = m0 + wr * 64 + i * 16 + kq * 4;
      if (OUT == 3) {
        if (gc < 1024) {           // Q or K -> fp16 transposed [b][c][s]
          ushortT h4[4];
#pragma unroll
          for (int r = 0; r < 4; ++r) {
            _Float16 hh = (_Float16)(acc[i][j][r] + bv);
            h4[r] = __builtin_bit_cast(ushortT, hh);
          }
          ushortT* dst = (gc < 512 ? Qh : Kh)
                       + ((size_t)(gr0 >> 9) * 512 + (gc & 511)) * 512 + (gr0 & 511);
          *(uint2*)dst = *(const uint2*)h4;
        } else {                   // V -> fp32 plain [row][c]
#pragma unroll
          for (int r = 0; r < 4; ++r)
            C[(size_t)(gr0 + r) * D_DIM + (gc & 511)] = acc[i][j][r] + bv;
        }
      } else {
#pragma unroll
        for (int r = 0; r < 4; ++r) {
          const int gr = gr0 + r;
          float v = acc[i][j][r] + bv;
          if (RES) v += res[(size_t)gr * N + gc];
          if (ACT == 1) v = gelu_tanh(v);
          if (OUT != 2) C[(size_t)gr * N + gc] = v;
          if (OUT != 0) Cb[(size_t)gr * N + gc] = f2bf(v);
        }
      }
    }
  }
}

// ---------------------------------------------------------------------------
// Auto-correlation, fp16 dot2. 8 channels/block.
// Qh,Kh fp16 transposed [b][c][s]; V fp32 [b][s][c]; out bf16 [b][s][c].
// corr[tau] = sum_s Q[(s+tau)%S]*K[s]; out = softmax_tau(corr) * V
// ---------------------------------------------------------------------------
__global__ __launch_bounds__(256) void autocorr_f16(
    const ushortT* __restrict__ Qh, const ushortT* __restrict__ Kh,
    const float* __restrict__ V, ushortT* __restrict__ Ob)
{
  __shared__ ushortT qh[8 * 1056];  // Q duplicated (kills %S), XOR-swizzled
  __shared__ ushortT kh[8 * 520];   // K; later reused for softmax weights
  const int tid = threadIdx.x;
  const int b = blockIdx.x >> 6;
  const int c0 = (blockIdx.x & 63) << 3;

  const ushortT* Qg = Qh + ((size_t)b * 512 + c0) * 512;
  const ushortT* Kg = Kh + ((size_t)b * 512 + c0) * 512;
  for (int chk = tid; chk < 512; chk += 256) {   // 16B chunks: 8ch x 64
    int cc = chk >> 6, s8 = (chk & 63) << 3;
    uint4 qv = *(const uint4*)&Qg[cc * 512 + s8];
    int i0 = cc * 1056 + s8, i1 = i0 + 512;
    *(uint4*)&qh[i0 ^ (((i0 >> 6) & 7) << 3)] = qv;
    *(uint4*)&qh[i1 ^ (((i1 >> 6) & 7) << 3)] = qv;
    *(uint4*)&kh[cc * 520 + s8] = *(const uint4*)&Kg[cc * 512 + s8];
  }
  __syncthreads();

  const int c = tid >> 5, tg = tid & 31, t0 = tg << 4; // 16 taus/thread
  float acc[16] = {};
  for (int s0 = 0; s0 < 512; s0 += 16) {
    unsigned ku[8];                       // K[s0..s0+15] as 8 half2 (broadcast)
    *(uint4*)&ku[0] = *(const uint4*)&kh[c * 520 + s0];
    *(uint4*)&ku[4] = *(const uint4*)&kh[c * 520 + s0 + 8];
    unsigned qu[16];                      // Q[s0+t0 .. +31] as 16 half2
#pragma unroll
    for (int j = 0; j < 4; ++j) {
      int idx = c * 1056 + s0 + t0 + 8 * j;
      int sw = idx ^ (((idx >> 6) & 7) << 3);
      *(uint4*)&qu[4 * j] = *(const uint4*)&qh[sw];
    }
    unsigned qs[15];                      // 1-half-shifted pairs
#pragma unroll
    for (int i = 0; i < 15; ++i)
      qs[i] = __builtin_amdgcn_alignbit(qu[i + 1], qu[i], 16);
#pragma unroll
    for (int e = 0; e < 8; ++e)
#pragma unroll
      for (int u = 0; u < 8; ++u) {
        acc[2 * e]     = __builtin_amdgcn_fdot2(u2h2(qu[e + u]), u2h2(ku[u]), acc[2 * e], false);
        acc[2 * e + 1] = __builtin_amdgcn_fdot2(u2h2(qs[e + u]), u2h2(ku[u]), acc[2 * e + 1], false);
      }
  }

  // softmax over 512 taus per channel (32 threads/channel, half-wave)
  float mx = acc[0];
#pragma unroll
  for (int t = 1; t < 16; ++t) mx = fmaxf(mx, acc[t]);
#pragma unroll
  for (int off = 16; off; off >>= 1) mx = fmaxf(mx, __shfl_xor(mx, off));
  float ex[16], sum = 0.f;
#pragma unroll
  for (int t = 0; t < 16; ++t) { ex[t] = __expf(acc[t] - mx); sum += ex[t]; }
#pragma unroll
  for (int off = 16; off; off >>= 1) sum += __shfl_xor(sum, off);
  const float inv = 1.f / sum;

  __syncthreads();                // all kh reads done before overwrite
  ushortT h16[16];
#pragma unroll
  for (int t = 0; t < 16; ++t)
    h16[t] = __builtin_bit_cast(ushortT, (_Float16)(ex[t] * inv));
  *(uint4*)&kh[c * 520 + t0]     = *(const uint4*)&h16[0];
  *(uint4*)&kh[c * 520 + t0 + 8] = *(const uint4*)&h16[8];
  __syncthreads();

  const size_t base = (size_t)b * S_LEN * D_DIM + c0;
  for (int i = tid; i < 4096; i += 256) {
    int s = i >> 3, cc = i & 7;
    float wv = (float)__builtin_bit_cast(_Float16, kh[cc * 520 + s]);
    size_t a = base + (size_t)s * D_DIM + cc;
    Ob[a] = f2bf(wv * V[a]);
  }
}

// ---------------------------------------------------------------------------
template<int MEAN>
__global__ __launch_bounds__(256) void movavg_sub2(
    const float* __restrict__ y, float* __restrict__ outf,
    ushortT* __restrict__ outb, float* __restrict__ hm)
{
  __shared__ float ys[512 * 32];
  const int tid = threadIdx.x;
  const int b = blockIdx.y, d0 = blockIdx.x * 32;
  const float* yb = y + (size_t)b * S_LEN * D_DIM + d0;

#pragma unroll 4
  for (int p = 0; p < 16; ++p) {
    int i = p * 256 + tid;
    int s = i >> 3, dq = i & 7;
    float4 v = *(const float4*)(yb + (size_t)s * D_DIM + dq * 4);
    *(float4*)&ys[s * 32 + dq * 4] = v;
  }
  __syncthreads();

  const int d = tid & 31, sg = tid >> 5;
  float msum = 0.f;
  for (int it = 0; it < 64; ++it) {
    int s = sg + it * 8;
    int lo = max(s - 12, 0), hi = min(s + 13, S_LEN);
    float sum = 0.f;
    for (int t = lo; t < hi; ++t) sum += ys[t * 32 + d];
    float val = ys[s * 32 + d] - sum / (float)(hi - lo);
    size_t g = (size_t)b * S_LEN * D_DIM + (size_t)s * D_DIM + d0 + d;
    outf[g] = val;
    outb[g] = f2bf(val);
    if (MEAN) msum += val;
  }
  if (MEAN) atomicAdd(&hm[b * D_DIM + d0 + d], msum * (1.f / (float)S_LEN));
}

// ---------------------------------------------------------------------------
__global__ __launch_bounds__(256) void proj_head1(
    const float* __restrict__ hm, const float* __restrict__ W1,
    const float* __restrict__ b1, float* __restrict__ p1)
{
  __shared__ float hs[32 * 512];
  const int tid = threadIdx.x, n0 = blockIdx.x * 32;
  for (int i = tid; i < 16384; i += 256) hs[i] = hm[i];
  __syncthreads();
  const int n = tid & 31, mg = tid >> 5;
  float acc[4] = {};
  for (int k = 0; k < 512; ++k) {
    float w = W1[(size_t)k * 256 + n0 + n];
#pragma unroll
    for (int mi = 0; mi < 4; ++mi)
      acc[mi] = fmaf(hs[(mg * 4 + mi) * 512 + k], w, acc[mi]);
  }
  const float bb = b1[n0 + n];
#pragma unroll
  for (int mi = 0; mi < 4; ++mi)
    p1[(size_t)(mg * 4 + mi) * 256 + n0 + n] = fmaxf(acc[mi] + bb, 0.f);
}

__global__ __launch_bounds__(256) void proj_head2(
    const float* __restrict__ p1, const float* __restrict__ W2,
    const float* __restrict__ b2, float* __restrict__ out)
{
  __shared__ float ps[32 * 256];
  const int tid = threadIdx.x;
  for (int i = tid; i < 8192; i += 256) ps[i] = p1[i];
  __syncthreads();
  const int n = tid & 31, mg = tid >> 5;
  const int ng = blockIdx.x * 32 + n;
  const bool ok = ng < NT_DIM;
  float acc[4] = {};
  for (int k = 0; k < 256; ++k) {
    float w = ok ? W2[(size_t)k * NT_DIM + ng] : 0.f;
#pragma unroll
    for (int mi = 0; mi < 4; ++mi)
      acc[mi] = fmaf(ps[(mg * 4 + mi) * 256 + k], w, acc[mi]);
  }
  if (ok) {
    const float bb = b2[ng];
#pragma unroll
    for (int mi = 0; mi < 4; ++mi)
      out[(size_t)(mg * 4 + mi) * NT_DIM + ng] = acc[mi] + bb;
  }
}

// ---------------------------------------------------------------------------
extern "C" void kernel_launch(void* const* d_in, const int* in_sizes, int n_in,
                              void* d_out, int out_size, void* d_ws, size_t ws_size,
                              hipStream_t stream)
{
  const float* x       = (const float*)d_in[0];
  const float* embed_w = (const float*)d_in[1];
  const float* embed_b = (const float*)d_in[2];
  const float* qkvo_w  = (const float*)d_in[3];
  const float* qkvo_b  = (const float*)d_in[4];
  const float* ffn_w1  = (const float*)d_in[5];
  const float* ffn_b1  = (const float*)d_in[6];
  const float* ffn_w2  = (const float*)d_in[7];
  const float* ffn_b2  = (const float*)d_in[8];
  const float* proj_w1 = (const float*)d_in[9];
  const float* proj_b1 = (const float*)d_in[10];
  const float* proj_w2 = (const float*)d_in[11];
  const float* proj_b2 = (const float*)d_in[12];
  float* out = (float*)d_out;

  float* ws = (float*)d_ws;
  float* Bv = ws;              // V fp32; overlaid by Hb during FFN
  float* Bh = ws + SZ;         // h (residual); overlaid by Hb during FFN
  float* Bq = ws + 2 * SZ;     // Qh+Kh (fp16T) -> y (fp32); xb during embed
  float* Bk = ws + 3 * SZ;     // x1 (seasonal, fp32)
  ushortT* Sb = (ushortT*)(ws + 4 * SZ);            // bf16 activation mirror
  ushortT* Wb = (ushortT*)(ws + 4 * SZ + SZ / 2);   // bf16 weights
  ushortT* embed_wt = Wb;                            // [512][256]
  ushortT* qkvo_wt  = embed_wt + (size_t)512 * 256;  // 8 x [512][512]
  ushortT* ffn1_wt  = qkvo_wt + (size_t)8 * 512 * 512;   // 2 x [2048][512]
  ushortT* ffn2_wt  = ffn1_wt + (size_t)2 * 2048 * 512;  // 2 x [512][2048]
  float* hm = (float*)(ffn2_wt + (size_t)2 * 512 * 2048); // [32][512]
  float* p1 = hm + 16384;                                  // [32][256]
  ushortT* Hb  = (ushortT*)Bv;   // FFN hidden bf16 [16384][2048] (Bv+Bh)
  ushortT* xb  = (ushortT*)Bq;   // x bf16 during embed
  ushortT* QKh = (ushortT*)Bq;   // Qh [0,SZ) + Kh [SZ,2SZ) fp16T

  dim3 blk(256);

  hipMemsetAsync(hm, 0, 16384 * sizeof(float), stream);

  conv_w<<<dim3(8, 16, 1), blk, 0, stream>>>(embed_w, embed_wt, IN_DIM, D_DIM);
  conv_w<<<dim3(16, 16, 8), blk, 0, stream>>>(qkvo_w, qkvo_wt, 512, 512);
  conv_w<<<dim3(16, 64, 2), blk, 0, stream>>>(ffn_w1, ffn1_wt, 512, 2048);
  conv_w<<<dim3(64, 16, 2), blk, 0, stream>>>(ffn_w2, ffn2_wt, 2048, 512);

  cvt_bf16<<<dim3(4096), blk, 0, stream>>>(x, xb, B_DIM * S_LEN * IN_DIM / 4);

  // embed: Bh(fp32) + Sb(bf16) = x @ We + be
  gemm_bf16<0, 0, 1><<<dim3(4, 128), blk, 0, stream>>>(
      xb, embed_wt, embed_b, nullptr, Bh, Sb, nullptr, nullptr, 16384, IN_DIM, D_DIM);

  for (int l = 0; l < 2; ++l) {
    const ushortT* qw = qkvo_wt + (size_t)l * 4 * 512 * 512;
    const float* qb = qkvo_b + (size_t)l * 4 * 512;
    // fused QKV: Q -> QKh (fp16T), K -> QKh+SZ (fp16T), V -> Bv (fp32 plain)
    gemm_bf16<0, 0, 3><<<dim3(12, 128), blk, 0, stream>>>(
        Sb, qw, qb, nullptr, Bv, nullptr, QKh, QKh + SZ, 16384, 512, 1536);
    autocorr_f16<<<dim3(B_DIM * 64), blk, 0, stream>>>(QKh, QKh + SZ, Bv, Sb);
    // y = attn @ Wo + bo + h  (overwrites QKh space; Q/K dead)
    gemm_bf16<0, 1, 0><<<dim3(4, 128), blk, 0, stream>>>(
        Sb, qw + (size_t)3 * 512 * 512, qb + 1536, Bh, Bq, nullptr, nullptr, nullptr,
        16384, 512, 512);
    movavg_sub2<0><<<dim3(16, 32), blk, 0, stream>>>(Bq, Bk, Sb, nullptr);
    // FFN (hidden bf16 overlays Bv+Bh, both dead)
    gemm_bf16<1, 0, 2><<<dim3(16, 128), blk, 0, stream>>>(
        Sb, ffn1_wt + (size_t)l * 2048 * 512, ffn_b1 + (size_t)l * DFF_DIM,
        nullptr, nullptr, Hb, nullptr, nullptr, 16384, 512, 2048);
    gemm_bf16<0, 1, 0><<<dim3(4, 128), blk, 0, stream>>>(
        Hb, ffn2_wt + (size_t)l * 512 * 2048, ffn_b2 + (size_t)l * D_DIM,
        Bk, Bq, nullptr, nullptr, nullptr, 16384, 2048, 512);
    if (l == 1)
      movavg_sub2<1><<<dim3(16, 32), blk, 0, stream>>>(Bq, Bh, Sb, hm);
    else
      movavg_sub2<0><<<dim3(16, 32), blk, 0, stream>>>(Bq, Bh, Sb, nullptr);
  }

  proj_head1<<<dim3(8), blk, 0, stream>>>(hm, proj_w1, proj_b1, p1);
  proj_head2<<<dim3(14), blk, 0, stream>>>(p1, proj_w2, proj_b2, out);
}

// Round 8
// 901.060 us; speedup vs baseline: 4.6963x; 1.0331x over previous
//
#include <hip/hip_runtime.h>
#include <hip/hip_bf16.h>

// AutoFormer forward. B=32 S=512 IN=256 D=512 H=8 L=2 DFF=2048 NT=424 K=25
#define S_LEN 512
#define D_DIM 512
#define B_DIM 32
#define IN_DIM 256
#define DFF_DIM 2048
#define NT_DIM 424

static constexpr size_t SZ = (size_t)B_DIM * S_LEN * D_DIM; // 8388608

using s8v = __attribute__((ext_vector_type(8))) short;
using f4v = __attribute__((ext_vector_type(4))) float;
typedef unsigned short ushortT;
typedef __attribute__((ext_vector_type(2))) _Float16 h2f;

__device__ __forceinline__ ushortT f2bf(float f) {
  unsigned u = __float_as_uint(f);
  u += 0x7FFFu + ((u >> 16) & 1u);   // RNE
  return (ushortT)(u >> 16);
}

__device__ __forceinline__ h2f u2h2(unsigned u) {
  union { unsigned u; h2f h; } x; x.u = u; return x.h;
}

__device__ __forceinline__ float gelu_tanh(float x) {
  float x3 = x * x * x;
  return 0.5f * x * (1.f + tanhf(0.7978845608028654f * (x + 0.044715f * x3)));
}

// ---------------------------------------------------------------------------
// Weight convert+transpose: W[Kp][N] fp32 -> Wt[N][Kp] bf16. z = matrix batch.
// ---------------------------------------------------------------------------
__global__ __launch_bounds__(256) void conv_w(
    const float* __restrict__ W, ushortT* __restrict__ Wt, int Kp, int N)
{
  __shared__ float T[32][33];
  const int z = blockIdx.z;
  W  += (size_t)z * Kp * N;
  Wt += (size_t)z * N * Kp;
  const int k0 = blockIdx.x * 32, n0 = blockIdx.y * 32;
  const int tid = threadIdx.x;
  const int col = tid & 31, r8 = tid >> 5;
#pragma unroll
  for (int it = 0; it < 4; ++it) {
    int row = r8 + it * 8;
    T[row][col] = W[(size_t)(k0 + row) * N + n0 + col];
  }
  __syncthreads();
  const int nl = tid >> 3, kq = tid & 7;
#pragma unroll
  for (int j = 0; j < 4; ++j) {
    int kl = kq * 4 + j;
    Wt[(size_t)(n0 + nl) * Kp + k0 + kl] = f2bf(T[kl][nl]);
  }
}

__global__ __launch_bounds__(256) void cvt_bf16(
    const float* __restrict__ in, ushortT* __restrict__ out, int n4)
{
  int i = blockIdx.x * 256 + threadIdx.x;
  if (i >= n4) return;
  float4 v = ((const float4*)in)[i];
  ushortT o[4] = {f2bf(v.x), f2bf(v.y), f2bf(v.z), f2bf(v.w)};
  *(uint2*)&out[(size_t)i * 4] = *(const uint2*)o;
}

// ---------------------------------------------------------------------------
// bf16 MFMA GEMM, 2-phase double-buffered, XCD-aware block swizzle.
// OUT: 0 fp32 only, 1 fp32+bf16, 2 bf16 only,
// 3 = fused QKV (N=1536): cols [0,512) -> Qh fp16 transposed [b][c][s],
//     cols [512,1024) -> Kh fp16 transposed, cols [1024,1536) -> C fp32
//     plain [row][c] (V).
// ---------------------------------------------------------------------------
template<int ACT, int RES, int OUT>
__global__ __launch_bounds__(256) void gemm_bf16(
    const ushortT* __restrict__ A, const ushortT* __restrict__ Wt,
    const float* __restrict__ bias, const float* __restrict__ res,
    float* __restrict__ C, ushortT* __restrict__ Cb,
    ushortT* __restrict__ Qh, ushortT* __restrict__ Kh, int M, int Kp, int N)
{
  __shared__ ushortT Ash[2][128 * 32];
  __shared__ ushortT Wsh[2][128 * 32];
  const int tid = threadIdx.x;
  const int lane = tid & 63, wid = tid >> 6;
  const int fr = lane & 15, kq = lane >> 4;
  const int wr = wid >> 1, wc = wid & 1;

  // XCD-aware swizzle: hw-consecutive-per-XCD blocks -> consecutive logical
  // tiles (share A row-panel; panel+B fit 4MB per-XCD L2). nwg % 8 == 0.
  const int nwg = gridDim.x * gridDim.y;
  const int bid = blockIdx.y * gridDim.x + blockIdx.x;
  const int swz = (bid & 7) * (nwg >> 3) + (bid >> 3);
  const int bx = swz % gridDim.x, by = swz / gridDim.x;
  const int m0 = by * 128, n0 = bx * 128;

  int srow[2], skq[2];
#pragma unroll
  for (int t = 0; t < 2; ++t) {
    int ch = wid * 2 + t;
    int row = ch * 16 + (lane >> 2);
    int kql = lane & 3;
    srow[t] = row;
    skq[t] = kql ^ ((row >> 1) & 3);
  }

  int aoff[4], boff[4];
#pragma unroll
  for (int i = 0; i < 4; ++i) {
    int ra = wr * 64 + i * 16 + fr;
    aoff[i] = ra * 32 + ((kq ^ ((ra >> 1) & 3)) << 3);
    int rb = wc * 64 + i * 16 + fr;
    boff[i] = rb * 32 + ((kq ^ ((rb >> 1) & 3)) << 3);
  }

  auto STAGE = [&](int buf, int k0) {
#pragma unroll
    for (int t = 0; t < 2; ++t) {
      const ushortT* as = A + (size_t)(m0 + srow[t]) * Kp + k0 + skq[t] * 8;
      __builtin_amdgcn_global_load_lds(
          (const __attribute__((address_space(1))) unsigned int*)as,
          (__attribute__((address_space(3))) unsigned int*)&Ash[buf][(wid * 2 + t) * 512],
          16, 0, 0);
      const ushortT* wsrc = Wt + (size_t)(n0 + srow[t]) * Kp + k0 + skq[t] * 8;
      __builtin_amdgcn_global_load_lds(
          (const __attribute__((address_space(1))) unsigned int*)wsrc,
          (__attribute__((address_space(3))) unsigned int*)&Wsh[buf][(wid * 2 + t) * 512],
          16, 0, 0);
    }
  };

  f4v acc[4][4] = {};
  STAGE(0, 0);
  int cur = 0;

  for (int k0 = 0; k0 < Kp; k0 += 32) {
    __syncthreads();              // drains pending STAGE (vmcnt0) + sync reads
    if (k0 + 32 < Kp) STAGE(cur ^ 1, k0 + 32);
    s8v af[4], bfv[4];
#pragma unroll
    for (int i = 0; i < 4; ++i) {
      af[i]  = *(const s8v*)&Ash[cur][aoff[i]];
      bfv[i] = *(const s8v*)&Wsh[cur][boff[i]];
    }
#pragma unroll
    for (int i = 0; i < 4; ++i)
#pragma unroll
      for (int j = 0; j < 4; ++j)
        acc[i][j] = __builtin_amdgcn_mfma_f32_16x16x32_bf16(af[i], bfv[j], acc[i][j], 0, 0, 0);
    cur ^= 1;
  }

  // epilogue: C/D layout col=lane&15, row=(lane>>4)*4+reg
#pragma unroll
  for (int j = 0; j < 4; ++j) {
    const int gc = n0 + wc * 64 + j * 16 + fr;
    const float bv = bias[gc];
#pragma unroll
    for (int i = 0; i < 4; ++i) {
      const int gr0 = m0 + wr * 64 + i * 16 + kq * 4;
      if (OUT == 3) {
        if (gc < 1024) {           // Q or K -> fp16 transposed [b][c][s]
          ushortT h4[4];
#pragma unroll
          for (int r = 0; r < 4; ++r) {
            _Float16 hh = (_Float16)(acc[i][j][r] + bv);
            h4[r] = __builtin_bit_cast(ushortT, hh);
          }
          ushortT* dst = (gc < 512 ? Qh : Kh)
                       + ((size_t)(gr0 >> 9) * 512 + (gc & 511)) * 512 + (gr0 & 511);
          *(uint2*)dst = *(const uint2*)h4;
        } else {                   // V -> fp32 plain [row][c]
#pragma unroll
          for (int r = 0; r < 4; ++r)
            C[(size_t)(gr0 + r) * D_DIM + (gc & 511)] = acc[i][j][r] + bv;
        }
      } else {
#pragma unroll
        for (int r = 0; r < 4; ++r) {
          const int gr = gr0 + r;
          float v = acc[i][j][r] + bv;
          if (RES) v += res[(size_t)gr * N + gc];
          if (ACT == 1) v = gelu_tanh(v);
          if (OUT != 2) C[(size_t)gr * N + gc] = v;
          if (OUT != 0) Cb[(size_t)gr * N + gc] = f2bf(v);
        }
      }
    }
  }
}

// ---------------------------------------------------------------------------
// Auto-correlation, fp16 dot2. 16 channels/block, 512 threads.
// Qh,Kh fp16 transposed [b][c][s]; V fp32 [b][s][c]; out bf16 [b][s][c].
// corr[tau] = sum_s Q[(s+tau)%S]*K[s]; out = softmax_tau(corr) * V
// No Q duplication: circular wrap via &511 at 8-half granularity.
// ---------------------------------------------------------------------------
__global__ __launch_bounds__(512) void autocorr_f16(
    const ushortT* __restrict__ Qh, const ushortT* __restrict__ Kh,
    const float* __restrict__ V, ushortT* __restrict__ Ob)
{
  __shared__ ushortT qh[16 * 528];  // XOR-swizzled
  __shared__ ushortT kh[16 * 520];  // K; later reused for softmax weights
  const int tid = threadIdx.x;
  const int b = blockIdx.x >> 5;
  const int c0 = (blockIdx.x & 31) << 4;

  const ushortT* Qg = Qh + ((size_t)b * 512 + c0) * 512;
  const ushortT* Kg = Kh + ((size_t)b * 512 + c0) * 512;
  for (int chk = tid; chk < 1024; chk += 512) {  // 16B chunks: 16ch x 64
    int cc = chk >> 6, s8 = (chk & 63) << 3;
    uint4 qv = *(const uint4*)&Qg[cc * 512 + s8];
    int i0 = cc * 528 + s8;
    *(uint4*)&qh[i0 ^ (((i0 >> 6) & 7) << 3)] = qv;
    *(uint4*)&kh[cc * 520 + s8] = *(const uint4*)&Kg[cc * 512 + s8];
  }
  __syncthreads();

  const int c = tid >> 5, tg = tid & 31, t0 = tg << 4; // 16 taus/thread
  const int cbase = c * 528;
  float acc[16] = {};
  for (int s0 = 0; s0 < 512; s0 += 16) {
    unsigned ku[8];                       // K[s0..s0+15] as 8 half2 (broadcast)
    *(uint4*)&ku[0] = *(const uint4*)&kh[c * 520 + s0];
    *(uint4*)&ku[4] = *(const uint4*)&kh[c * 520 + s0 + 8];
    unsigned qu[16];                      // Q[(s0+t0 .. +31)&511] as 16 half2
#pragma unroll
    for (int j = 0; j < 4; ++j) {
      int idx = cbase + ((s0 + t0 + 8 * j) & 511);
      int sw = idx ^ (((idx >> 6) & 7) << 3);
      *(uint4*)&qu[4 * j] = *(const uint4*)&qh[sw];
    }
    unsigned qs[15];                      // 1-half-shifted pairs
#pragma unroll
    for (int i = 0; i < 15; ++i)
      qs[i] = __builtin_amdgcn_alignbit(qu[i + 1], qu[i], 16);
#pragma unroll
    for (int e = 0; e < 8; ++e)
#pragma unroll
      for (int u = 0; u < 8; ++u) {
        acc[2 * e]     = __builtin_amdgcn_fdot2(u2h2(qu[e + u]), u2h2(ku[u]), acc[2 * e], false);
        acc[2 * e + 1] = __builtin_amdgcn_fdot2(u2h2(qs[e + u]), u2h2(ku[u]), acc[2 * e + 1], false);
      }
  }

  // softmax over 512 taus per channel (32 threads/channel, half-wave)
  float mx = acc[0];
#pragma unroll
  for (int t = 1; t < 16; ++t) mx = fmaxf(mx, acc[t]);
#pragma unroll
  for (int off = 16; off; off >>= 1) mx = fmaxf(mx, __shfl_xor(mx, off));
  float ex[16], sum = 0.f;
#pragma unroll
  for (int t = 0; t < 16; ++t) { ex[t] = __expf(acc[t] - mx); sum += ex[t]; }
#pragma unroll
  for (int off = 16; off; off >>= 1) sum += __shfl_xor(sum, off);
  const float inv = 1.f / sum;

  __syncthreads();                // all kh reads done before overwrite
  ushortT h16[16];
#pragma unroll
  for (int t = 0; t < 16; ++t)
    h16[t] = __builtin_bit_cast(ushortT, (_Float16)(ex[t] * inv));
  *(uint4*)&kh[c * 520 + t0]     = *(const uint4*)&h16[0];
  *(uint4*)&kh[c * 520 + t0 + 8] = *(const uint4*)&h16[8];
  __syncthreads();

  const size_t base = (size_t)b * S_LEN * D_DIM + c0;
  for (int i = tid; i < 8192; i += 512) {
    int s = i >> 4, cc = i & 15;
    float wv = (float)__builtin_bit_cast(_Float16, kh[cc * 520 + s]);
    size_t a = base + (size_t)s * D_DIM + cc;
    Ob[a] = f2bf(wv * V[a]);
  }
}

// ---------------------------------------------------------------------------
template<int MEAN>
__global__ __launch_bounds__(256) void movavg_sub2(
    const float* __restrict__ y, float* __restrict__ outf,
    ushortT* __restrict__ outb, float* __restrict__ hm)
{
  __shared__ float ys[512 * 32];
  const int tid = threadIdx.x;
  const int b = blockIdx.y, d0 = blockIdx.x * 32;
  const float* yb = y + (size_t)b * S_LEN * D_DIM + d0;

#pragma unroll 4
  for (int p = 0; p < 16; ++p) {
    int i = p * 256 + tid;
    int s = i >> 3, dq = i & 7;
    float4 v = *(const float4*)(yb + (size_t)s * D_DIM + dq * 4);
    *(float4*)&ys[s * 32 + dq * 4] = v;
  }
  __syncthreads();

  const int d = tid & 31, sg = tid >> 5;
  float msum = 0.f;
  for (int it = 0; it < 64; ++it) {
    int s = sg + it * 8;
    int lo = max(s - 12, 0), hi = min(s + 13, S_LEN);
    float sum = 0.f;
    for (int t = lo; t < hi; ++t) sum += ys[t * 32 + d];
    float val = ys[s * 32 + d] - sum / (float)(hi - lo);
    size_t g = (size_t)b * S_LEN * D_DIM + (size_t)s * D_DIM + d0 + d;
    outf[g] = val;
    outb[g] = f2bf(val);
    if (MEAN) msum += val;
  }
  if (MEAN) atomicAdd(&hm[b * D_DIM + d0 + d], msum * (1.f / (float)S_LEN));
}

// ---------------------------------------------------------------------------
__global__ __launch_bounds__(256) void proj_head1(
    const float* __restrict__ hm, const float* __restrict__ W1,
    const float* __restrict__ b1, float* __restrict__ p1)
{
  __shared__ float hs[32 * 512];
  const int tid = threadIdx.x, n0 = blockIdx.x * 32;
  for (int i = tid; i < 16384; i += 256) hs[i] = hm[i];
  __syncthreads();
  const int n = tid & 31, mg = tid >> 5;
  float acc[4] = {};
  for (int k = 0; k < 512; ++k) {
    float w = W1[(size_t)k * 256 + n0 + n];
#pragma unroll
    for (int mi = 0; mi < 4; ++mi)
      acc[mi] = fmaf(hs[(mg * 4 + mi) * 512 + k], w, acc[mi]);
  }
  const float bb = b1[n0 + n];
#pragma unroll
  for (int mi = 0; mi < 4; ++mi)
    p1[(size_t)(mg * 4 + mi) * 256 + n0 + n] = fmaxf(acc[mi] + bb, 0.f);
}

__global__ __launch_bounds__(256) void proj_head2(
    const float* __restrict__ p1, const float* __restrict__ W2,
    const float* __restrict__ b2, float* __restrict__ out)
{
  __shared__ float ps[32 * 256];
  const int tid = threadIdx.x;
  for (int i = tid; i < 8192; i += 256) ps[i] = p1[i];
  __syncthreads();
  const int n = tid & 31, mg = tid >> 5;
  const int ng = blockIdx.x * 32 + n;
  const bool ok = ng < NT_DIM;
  float acc[4] = {};
  for (int k = 0; k < 256; ++k) {
    float w = ok ? W2[(size_t)k * NT_DIM + ng] : 0.f;
#pragma unroll
    for (int mi = 0; mi < 4; ++mi)
      acc[mi] = fmaf(ps[(mg * 4 + mi) * 256 + k], w, acc[mi]);
  }
  if (ok) {
    const float bb = b2[ng];
#pragma unroll
    for (int mi = 0; mi < 4; ++mi)
      out[(size_t)(mg * 4 + mi) * NT_DIM + ng] = acc[mi] + bb;
  }
}

// ---------------------------------------------------------------------------
extern "C" void kernel_launch(void* const* d_in, const int* in_sizes, int n_in,
                              void* d_out, int out_size, void* d_ws, size_t ws_size,
                              hipStream_t stream)
{
  const float* x       = (const float*)d_in[0];
  const float* embed_w = (const float*)d_in[1];
  const float* embed_b = (const float*)d_in[2];
  const float* qkvo_w  = (const float*)d_in[3];
  const float* qkvo_b  = (const float*)d_in[4];
  const float* ffn_w1  = (const float*)d_in[5];
  const float* ffn_b1  = (const float*)d_in[6];
  const float* ffn_w2  = (const float*)d_in[7];
  const float* ffn_b2  = (const float*)d_in[8];
  const float* proj_w1 = (const float*)d_in[9];
  const float* proj_b1 = (const float*)d_in[10];
  const float* proj_w2 = (const float*)d_in[11];
  const float* proj_b2 = (const float*)d_in[12];
  float* out = (float*)d_out;

  float* ws = (float*)d_ws;
  float* Bv = ws;              // V fp32; overlaid by Hb during FFN
  float* Bh = ws + SZ;         // h (residual); overlaid by Hb during FFN
  float* Bq = ws + 2 * SZ;     // Qh+Kh (fp16T) -> y (fp32); xb during embed
  float* Bk = ws + 3 * SZ;     // x1 (seasonal, fp32)
  ushortT* Sb = (ushortT*)(ws + 4 * SZ);            // bf16 activation mirror
  ushortT* Wb = (ushortT*)(ws + 4 * SZ + SZ / 2);   // bf16 weights
  ushortT* embed_wt = Wb;                            // [512][256]
  ushortT* qkvo_wt  = embed_wt + (size_t)512 * 256;  // 8 x [512][512]
  ushortT* ffn1_wt  = qkvo_wt + (size_t)8 * 512 * 512;   // 2 x [2048][512]
  ushortT* ffn2_wt  = ffn1_wt + (size_t)2 * 2048 * 512;  // 2 x [512][2048]
  float* hm = (float*)(ffn2_wt + (size_t)2 * 512 * 2048); // [32][512]
  float* p1 = hm + 16384;                                  // [32][256]
  ushortT* Hb  = (ushortT*)Bv;   // FFN hidden bf16 [16384][2048] (Bv+Bh)
  ushortT* xb  = (ushortT*)Bq;   // x bf16 during embed
  ushortT* QKh = (ushortT*)Bq;   // Qh [0,SZ) + Kh [SZ,2SZ) fp16T

  dim3 blk(256);

  hipMemsetAsync(hm, 0, 16384 * sizeof(float), stream);

  conv_w<<<dim3(8, 16, 1), blk, 0, stream>>>(embed_w, embed_wt, IN_DIM, D_DIM);
  conv_w<<<dim3(16, 16, 8), blk, 0, stream>>>(qkvo_w, qkvo_wt, 512, 512);
  conv_w<<<dim3(16, 64, 2), blk, 0, stream>>>(ffn_w1, ffn1_wt, 512, 2048);
  conv_w<<<dim3(64, 16, 2), blk, 0, stream>>>(ffn_w2, ffn2_wt, 2048, 512);

  cvt_bf16<<<dim3(4096), blk, 0, stream>>>(x, xb, B_DIM * S_LEN * IN_DIM / 4);

  // embed: Bh(fp32) + Sb(bf16) = x @ We + be
  gemm_bf16<0, 0, 1><<<dim3(4, 128), blk, 0, stream>>>(
      xb, embed_wt, embed_b, nullptr, Bh, Sb, nullptr, nullptr, 16384, IN_DIM, D_DIM);

  for (int l = 0; l < 2; ++l) {
    const ushortT* qw = qkvo_wt + (size_t)l * 4 * 512 * 512;
    const float* qb = qkvo_b + (size_t)l * 4 * 512;
    // fused QKV: Q -> QKh (fp16T), K -> QKh+SZ (fp16T), V -> Bv (fp32 plain)
    gemm_bf16<0, 0, 3><<<dim3(12, 128), blk, 0, stream>>>(
        Sb, qw, qb, nullptr, Bv, nullptr, QKh, QKh + SZ, 16384, 512, 1536);
    autocorr_f16<<<dim3(B_DIM * 32), dim3(512), 0, stream>>>(QKh, QKh + SZ, Bv, Sb);
    // y = attn @ Wo + bo + h  (overwrites QKh space; Q/K dead)
    gemm_bf16<0, 1, 0><<<dim3(4, 128), blk, 0, stream>>>(
        Sb, qw + (size_t)3 * 512 * 512, qb + 1536, Bh, Bq, nullptr, nullptr, nullptr,
        16384, 512, 512);
    movavg_sub2<0><<<dim3(16, 32), blk, 0, stream>>>(Bq, Bk, Sb, nullptr);
    // FFN (hidden bf16 overlays Bv+Bh, both dead)
    gemm_bf16<1, 0, 2><<<dim3(16, 128), blk, 0, stream>>>(
        Sb, ffn1_wt + (size_t)l * 2048 * 512, ffn_b1 + (size_t)l * DFF_DIM,
        nullptr, nullptr, Hb, nullptr, nullptr, 16384, 512, 2048);
    gemm_bf16<0, 1, 0><<<dim3(4, 128), blk, 0, stream>>>(
        Hb, ffn2_wt + (size_t)l * 512 * 2048, ffn_b2 + (size_t)l * D_DIM,
        Bk, Bq, nullptr, nullptr, nullptr, 16384, 2048, 512);
    if (l == 1)
      movavg_sub2<1><<<dim3(16, 32), blk, 0, stream>>>(Bq, Bh, Sb, hm);
    else
      movavg_sub2<0><<<dim3(16, 32), blk, 0, stream>>>(Bq, Bh, Sb, nullptr);
  }

  proj_head1<<<dim3(8), blk, 0, stream>>>(hm, proj_w1, proj_b1, p1);
  proj_head2<<<dim3(14), blk, 0, stream>>>(p1, proj_w2, proj_b2, out);
}

// Round 9
// 683.557 us; speedup vs baseline: 6.1906x; 1.3182x over previous
//
#include <hip/hip_runtime.h>
#include <hip/hip_bf16.h>

// AutoFormer forward. B=32 S=512 IN=256 D=512 H=8 L=2 DFF=2048 NT=424 K=25
#define S_LEN 512
#define D_DIM 512
#define B_DIM 32
#define IN_DIM 256
#define DFF_DIM 2048
#define NT_DIM 424

static constexpr size_t SZ = (size_t)B_DIM * S_LEN * D_DIM; // 8388608

using s8v = __attribute__((ext_vector_type(8))) short;
using f4v = __attribute__((ext_vector_type(4))) float;
typedef unsigned short ushortT;
typedef __attribute__((ext_vector_type(2))) _Float16 h2f;

__device__ __forceinline__ ushortT f2bf(float f) {
  unsigned u = __float_as_uint(f);
  u += 0x7FFFu + ((u >> 16) & 1u);   // RNE
  return (ushortT)(u >> 16);
}

__device__ __forceinline__ h2f u2h2(unsigned u) {
  union { unsigned u; h2f h; } x; x.u = u; return x.h;
}

__device__ __forceinline__ float gelu_tanh(float x) {
  float x3 = x * x * x;
  return 0.5f * x * (1.f + tanhf(0.7978845608028654f * (x + 0.044715f * x3)));
}

// ---------------------------------------------------------------------------
// All weight conversions in ONE dispatch. z picks the matrix:
// z=0 embed [256][512]; z=1..8 qkvo [512][512]; z=9,10 ffn1 [512][2048];
// z=11,12 ffn2 [2048][512]. W[Kp][N] fp32 -> Wt[N][Kp] bf16 (transposed).
// grid (16, 64, 13); ffn2 swaps tile axes so kx fits.
// ---------------------------------------------------------------------------
__global__ __launch_bounds__(256) void conv_all(
    const float* __restrict__ embed_w, const float* __restrict__ qkvo_w,
    const float* __restrict__ ffn_w1, const float* __restrict__ ffn_w2,
    ushortT* __restrict__ embed_wt, ushortT* __restrict__ qkvo_wt,
    ushortT* __restrict__ ffn1_wt, ushortT* __restrict__ ffn2_wt)
{
  __shared__ float T[32][33];
  const int z = blockIdx.z;
  const float* W; ushortT* Wt; int Kp, N;
  if (z == 0)       { W = embed_w; Wt = embed_wt; Kp = 256; N = 512; }
  else if (z <= 8)  { int i = z - 1; W = qkvo_w + (size_t)i * 512 * 512;
                      Wt = qkvo_wt + (size_t)i * 512 * 512; Kp = 512; N = 512; }
  else if (z <= 10) { int l = z - 9; W = ffn_w1 + (size_t)l * 512 * 2048;
                      Wt = ffn1_wt + (size_t)l * 2048 * 512; Kp = 512; N = 2048; }
  else              { int l = z - 11; W = ffn_w2 + (size_t)l * 2048 * 512;
                      Wt = ffn2_wt + (size_t)l * 512 * 2048; Kp = 2048; N = 512; }
  int k0, n0;
  if (z >= 11) { k0 = blockIdx.y * 32; n0 = blockIdx.x * 32; }
  else         { k0 = blockIdx.x * 32; n0 = blockIdx.y * 32; }
  if (k0 >= Kp || n0 >= N) return;

  const int tid = threadIdx.x;
  const int col = tid & 31, r8 = tid >> 5;
#pragma unroll
  for (int it = 0; it < 4; ++it) {
    int row = r8 + it * 8;
    T[row][col] = W[(size_t)(k0 + row) * N + n0 + col];
  }
  __syncthreads();
  const int nl = tid >> 3, kq = tid & 7;
#pragma unroll
  for (int j = 0; j < 4; ++j) {
    int kl = kq * 4 + j;
    Wt[(size_t)(n0 + nl) * Kp + k0 + kl] = f2bf(T[kl][nl]);
  }
}

__global__ __launch_bounds__(256) void cvt_bf16(
    const float* __restrict__ in, ushortT* __restrict__ out, int n4)
{
  int i = blockIdx.x * 256 + threadIdx.x;
  if (i >= n4) return;
  float4 v = ((const float4*)in)[i];
  ushortT o[4] = {f2bf(v.x), f2bf(v.y), f2bf(v.z), f2bf(v.w)};
  *(uint2*)&out[(size_t)i * 4] = *(const uint2*)o;
}

// ---------------------------------------------------------------------------
// bf16 MFMA GEMM, 2-phase double-buffered, XCD-aware block swizzle.
// OUT: 0 fp32 only, 1 fp32+bf16, 2 bf16 only,
// 3 = fused QKV (N=1536): cols [0,512) -> Qh fp16 transposed [b][c][s],
//     cols [512,1024) -> Kh fp16 transposed, cols [1024,1536) -> C fp32
//     plain [row][c] (V).
// ---------------------------------------------------------------------------
template<int ACT, int RES, int OUT>
__global__ __launch_bounds__(256) void gemm_bf16(
    const ushortT* __restrict__ A, const ushortT* __restrict__ Wt,
    const float* __restrict__ bias, const float* __restrict__ res,
    float* __restrict__ C, ushortT* __restrict__ Cb,
    ushortT* __restrict__ Qh, ushortT* __restrict__ Kh, int M, int Kp, int N)
{
  __shared__ ushortT Ash[2][128 * 32];
  __shared__ ushortT Wsh[2][128 * 32];
  const int tid = threadIdx.x;
  const int lane = tid & 63, wid = tid >> 6;
  const int fr = lane & 15, kq = lane >> 4;
  const int wr = wid >> 1, wc = wid & 1;

  // XCD-aware swizzle: consecutive logical tiles land on one XCD's L2.
  const int nwg = gridDim.x * gridDim.y;
  const int bid = blockIdx.y * gridDim.x + blockIdx.x;
  const int swz = (bid & 7) * (nwg >> 3) + (bid >> 3);
  const int bx = swz % gridDim.x, by = swz / gridDim.x;
  const int m0 = by * 128, n0 = bx * 128;

  int srow[2], skq[2];
#pragma unroll
  for (int t = 0; t < 2; ++t) {
    int ch = wid * 2 + t;
    int row = ch * 16 + (lane >> 2);
    int kql = lane & 3;
    srow[t] = row;
    skq[t] = kql ^ ((row >> 1) & 3);
  }

  int aoff[4], boff[4];
#pragma unroll
  for (int i = 0; i < 4; ++i) {
    int ra = wr * 64 + i * 16 + fr;
    aoff[i] = ra * 32 + ((kq ^ ((ra >> 1) & 3)) << 3);
    int rb = wc * 64 + i * 16 + fr;
    boff[i] = rb * 32 + ((kq ^ ((rb >> 1) & 3)) << 3);
  }

  auto STAGE = [&](int buf, int k0) {
#pragma unroll
    for (int t = 0; t < 2; ++t) {
      const ushortT* as = A + (size_t)(m0 + srow[t]) * Kp + k0 + skq[t] * 8;
      __builtin_amdgcn_global_load_lds(
          (const __attribute__((address_space(1))) unsigned int*)as,
          (__attribute__((address_space(3))) unsigned int*)&Ash[buf][(wid * 2 + t) * 512],
          16, 0, 0);
      const ushortT* wsrc = Wt + (size_t)(n0 + srow[t]) * Kp + k0 + skq[t] * 8;
      __builtin_amdgcn_global_load_lds(
          (const __attribute__((address_space(1))) unsigned int*)wsrc,
          (__attribute__((address_space(3))) unsigned int*)&Wsh[buf][(wid * 2 + t) * 512],
          16, 0, 0);
    }
  };

  f4v acc[4][4] = {};
  STAGE(0, 0);
  int cur = 0;

  for (int k0 = 0; k0 < Kp; k0 += 32) {
    __syncthreads();              // drains pending STAGE + sync prior reads
    if (k0 + 32 < Kp) STAGE(cur ^ 1, k0 + 32);
    s8v af[4], bfv[4];
#pragma unroll
    for (int i = 0; i < 4; ++i) {
      af[i]  = *(const s8v*)&Ash[cur][aoff[i]];
      bfv[i] = *(const s8v*)&Wsh[cur][boff[i]];
    }
#pragma unroll
    for (int i = 0; i < 4; ++i)
#pragma unroll
      for (int j = 0; j < 4; ++j)
        acc[i][j] = __builtin_amdgcn_mfma_f32_16x16x32_bf16(af[i], bfv[j], acc[i][j], 0, 0, 0);
    cur ^= 1;
  }

  // epilogue: C/D layout col=lane&15, row=(lane>>4)*4+reg
#pragma unroll
  for (int j = 0; j < 4; ++j) {
    const int gc = n0 + wc * 64 + j * 16 + fr;
    const float bv = bias[gc];
#pragma unroll
    for (int i = 0; i < 4; ++i) {
      const int gr0 = m0 + wr * 64 + i * 16 + kq * 4;
      if (OUT == 3) {
        if (gc < 1024) {           // Q or K -> fp16 transposed [b][c][s]
          ushortT h4[4];
#pragma unroll
          for (int r = 0; r < 4; ++r) {
            _Float16 hh = (_Float16)(acc[i][j][r] + bv);
            h4[r] = __builtin_bit_cast(ushortT, hh);
          }
          ushortT* dst = (gc < 512 ? Qh : Kh)
                       + ((size_t)(gr0 >> 9) * 512 + (gc & 511)) * 512 + (gr0 & 511);
          *(uint2*)dst = *(const uint2*)h4;
        } else {                   // V -> fp32 plain [row][c]
#pragma unroll
          for (int r = 0; r < 4; ++r)
            C[(size_t)(gr0 + r) * D_DIM + (gc & 511)] = acc[i][j][r] + bv;
        }
      } else {
#pragma unroll
        for (int r = 0; r < 4; ++r) {
          const int gr = gr0 + r;
          float v = acc[i][j][r] + bv;
          if (RES) v += res[(size_t)gr * N + gc];
          if (ACT == 1) v = gelu_tanh(v);
          if (OUT != 2) C[(size_t)gr * N + gc] = v;
          if (OUT != 0) Cb[(size_t)gr * N + gc] = f2bf(v);
        }
      }
    }
  }
}

// ---------------------------------------------------------------------------
// Auto-correlation, fp16 dot2. 16 channels/block, 512 threads.
// Qh,Kh fp16 transposed [b][c][s]; V fp32 [b][s][c]; out bf16 [b][s][c].
// corr[tau] = sum_s Q[(s+tau)%S]*K[s]; out = softmax_tau(corr) * V
// ---------------------------------------------------------------------------
__global__ __launch_bounds__(512) void autocorr_f16(
    const ushortT* __restrict__ Qh, const ushortT* __restrict__ Kh,
    const float* __restrict__ V, ushortT* __restrict__ Ob)
{
  __shared__ ushortT qh[16 * 528];  // XOR-swizzled
  __shared__ ushortT kh[16 * 520];  // K; later reused for softmax weights
  const int tid = threadIdx.x;
  const int b = blockIdx.x >> 5;
  const int c0 = (blockIdx.x & 31) << 4;

  const ushortT* Qg = Qh + ((size_t)b * 512 + c0) * 512;
  const ushortT* Kg = Kh + ((size_t)b * 512 + c0) * 512;
  for (int chk = tid; chk < 1024; chk += 512) {  // 16B chunks: 16ch x 64
    int cc = chk >> 6, s8 = (chk & 63) << 3;
    uint4 qv = *(const uint4*)&Qg[cc * 512 + s8];
    int i0 = cc * 528 + s8;
    *(uint4*)&qh[i0 ^ (((i0 >> 6) & 7) << 3)] = qv;
    *(uint4*)&kh[cc * 520 + s8] = *(const uint4*)&Kg[cc * 512 + s8];
  }
  __syncthreads();

  const int c = tid >> 5, tg = tid & 31, t0 = tg << 4; // 16 taus/thread
  const int cbase = c * 528;
  float acc[16] = {};
  for (int s0 = 0; s0 < 512; s0 += 16) {
    unsigned ku[8];                       // K[s0..s0+15] as 8 half2 (broadcast)
    *(uint4*)&ku[0] = *(const uint4*)&kh[c * 520 + s0];
    *(uint4*)&ku[4] = *(const uint4*)&kh[c * 520 + s0 + 8];
    unsigned qu[16];                      // Q[(s0+t0 .. +31)&511] as 16 half2
#pragma unroll
    for (int j = 0; j < 4; ++j) {
      int idx = cbase + ((s0 + t0 + 8 * j) & 511);
      int sw = idx ^ (((idx >> 6) & 7) << 3);
      *(uint4*)&qu[4 * j] = *(const uint4*)&qh[sw];
    }
    unsigned qs[15];                      // 1-half-shifted pairs
#pragma unroll
    for (int i = 0; i < 15; ++i)
      qs[i] = __builtin_amdgcn_alignbit(qu[i + 1], qu[i], 16);
#pragma unroll
    for (int e = 0; e < 8; ++e)
#pragma unroll
      for (int u = 0; u < 8; ++u) {
        acc[2 * e]     = __builtin_amdgcn_fdot2(u2h2(qu[e + u]), u2h2(ku[u]), acc[2 * e], false);
        acc[2 * e + 1] = __builtin_amdgcn_fdot2(u2h2(qs[e + u]), u2h2(ku[u]), acc[2 * e + 1], false);
      }
  }

  // softmax over 512 taus per channel (32 threads/channel, half-wave)
  float mx = acc[0];
#pragma unroll
  for (int t = 1; t < 16; ++t) mx = fmaxf(mx, acc[t]);
#pragma unroll
  for (int off = 16; off; off >>= 1) mx = fmaxf(mx, __shfl_xor(mx, off));
  float ex[16], sum = 0.f;
#pragma unroll
  for (int t = 0; t < 16; ++t) { ex[t] = __expf(acc[t] - mx); sum += ex[t]; }
#pragma unroll
  for (int off = 16; off; off >>= 1) sum += __shfl_xor(sum, off);
  const float inv = 1.f / sum;

  __syncthreads();                // all kh reads done before overwrite
  ushortT h16[16];
#pragma unroll
  for (int t = 0; t < 16; ++t)
    h16[t] = __builtin_bit_cast(ushortT, (_Float16)(ex[t] * inv));
  *(uint4*)&kh[c * 520 + t0]     = *(const uint4*)&h16[0];
  *(uint4*)&kh[c * 520 + t0 + 8] = *(const uint4*)&h16[8];
  __syncthreads();

  const size_t base = (size_t)b * S_LEN * D_DIM + c0;
  for (int i = tid; i < 8192; i += 512) {
    int s = i >> 4, cc = i & 15;
    float wv = (float)__builtin_bit_cast(_Float16, kh[cc * 520 + s]);
    size_t a = base + (size_t)s * D_DIM + cc;
    Ob[a] = f2bf(wv * V[a]);
  }
}

// ---------------------------------------------------------------------------
// out = y - movavg(y,25), sliding-window: each thread owns 64 consecutive s.
// count_include_pad=False boundaries handled by conditional add/remove.
// ---------------------------------------------------------------------------
template<int MEAN>
__global__ __launch_bounds__(256) void movavg_sub2(
    const float* __restrict__ y, float* __restrict__ outf,
    ushortT* __restrict__ outb, float* __restrict__ hm)
{
  __shared__ float ys[512 * 32];
  const int tid = threadIdx.x;
  const int b = blockIdx.y, d0 = blockIdx.x * 32;
  const float* yb = y + (size_t)b * S_LEN * D_DIM + d0;

#pragma unroll 4
  for (int p = 0; p < 16; ++p) {
    int i = p * 256 + tid;
    int s = i >> 3, dq = i & 7;
    float4 v = *(const float4*)(yb + (size_t)s * D_DIM + dq * 4);
    *(float4*)&ys[s * 32 + dq * 4] = v;
  }
  __syncthreads();

  const int d = tid & 31, sg = tid >> 5;
  const int s0 = sg * 64;
  // init window sum for s = s0
  int lo = max(s0 - 12, 0), hi = min(s0 + 13, S_LEN);
  float sum = 0.f;
  for (int t = lo; t < hi; ++t) sum += ys[t * 32 + d];

  float msum = 0.f;
  const size_t gb = (size_t)b * S_LEN * D_DIM + d0 + d;
  for (int i = 0; i < 64; ++i) {
    const int s = s0 + i;
    float val = ys[s * 32 + d] - sum / (float)(hi - lo);
    size_t g = gb + (size_t)s * D_DIM;
    outf[g] = val;
    outb[g] = f2bf(val);
    if (MEAN) msum += val;
    // advance window to s+1
    int add = s + 13;
    if (add < S_LEN) { sum += ys[add * 32 + d]; hi = add + 1; }
    int rem = s - 12;
    if (rem >= 0) { sum -= ys[rem * 32 + d]; lo = rem + 1; }
  }
  if (MEAN) atomicAdd(&hm[b * D_DIM + d0 + d], msum * (1.f / (float)S_LEN));
}

// ---------------------------------------------------------------------------
__global__ __launch_bounds__(256) void proj_head1(
    const float* __restrict__ hm, const float* __restrict__ W1,
    const float* __restrict__ b1, float* __restrict__ p1)
{
  __shared__ float hs[32 * 512];
  const int tid = threadIdx.x, n0 = blockIdx.x * 32;
  for (int i = tid; i < 16384; i += 256) hs[i] = hm[i];
  __syncthreads();
  const int n = tid & 31, mg = tid >> 5;
  float acc[4] = {};
  for (int k = 0; k < 512; ++k) {
    float w = W1[(size_t)k * 256 + n0 + n];
#pragma unroll
    for (int mi = 0; mi < 4; ++mi)
      acc[mi] = fmaf(hs[(mg * 4 + mi) * 512 + k], w, acc[mi]);
  }
  const float bb = b1[n0 + n];
#pragma unroll
  for (int mi = 0; mi < 4; ++mi)
    p1[(size_t)(mg * 4 + mi) * 256 + n0 + n] = fmaxf(acc[mi] + bb, 0.f);
}

__global__ __launch_bounds__(256) void proj_head2(
    const float* __restrict__ p1, const float* __restrict__ W2,
    const float* __restrict__ b2, float* __restrict__ out)
{
  __shared__ float ps[32 * 256];
  const int tid = threadIdx.x;
  for (int i = tid; i < 8192; i += 256) ps[i] = p1[i];
  __syncthreads();
  const int n = tid & 31, mg = tid >> 5;
  const int ng = blockIdx.x * 32 + n;
  const bool ok = ng < NT_DIM;
  float acc[4] = {};
  for (int k = 0; k < 256; ++k) {
    float w = ok ? W2[(size_t)k * NT_DIM + ng] : 0.f;
#pragma unroll
    for (int mi = 0; mi < 4; ++mi)
      acc[mi] = fmaf(ps[(mg * 4 + mi) * 256 + k], w, acc[mi]);
  }
  if (ok) {
    const float bb = b2[ng];
#pragma unroll
    for (int mi = 0; mi < 4; ++mi)
      out[(size_t)(mg * 4 + mi) * NT_DIM + ng] = acc[mi] + bb;
  }
}

// ---------------------------------------------------------------------------
extern "C" void kernel_launch(void* const* d_in, const int* in_sizes, int n_in,
                              void* d_out, int out_size, void* d_ws, size_t ws_size,
                              hipStream_t stream)
{
  const float* x       = (const float*)d_in[0];
  const float* embed_w = (const float*)d_in[1];
  const float* embed_b = (const float*)d_in[2];
  const float* qkvo_w  = (const float*)d_in[3];
  const float* qkvo_b  = (const float*)d_in[4];
  const float* ffn_w1  = (const float*)d_in[5];
  const float* ffn_b1  = (const float*)d_in[6];
  const float* ffn_w2  = (const float*)d_in[7];
  const float* ffn_b2  = (const float*)d_in[8];
  const float* proj_w1 = (const float*)d_in[9];
  const float* proj_b1 = (const float*)d_in[10];
  const float* proj_w2 = (const float*)d_in[11];
  const float* proj_b2 = (const float*)d_in[12];
  float* out = (float*)d_out;

  float* ws = (float*)d_ws;
  float* Bv = ws;              // V fp32; overlaid by Hb during FFN
  float* Bh = ws + SZ;         // h (residual); overlaid by Hb during FFN
  float* Bq = ws + 2 * SZ;     // Qh+Kh (fp16T) -> y (fp32); xb during embed
  float* Bk = ws + 3 * SZ;     // x1 (seasonal, fp32)
  ushortT* Sb = (ushortT*)(ws + 4 * SZ);            // bf16 activation mirror
  ushortT* Wb = (ushortT*)(ws + 4 * SZ + SZ / 2);   // bf16 weights
  ushortT* embed_wt = Wb;                            // [512][256]
  ushortT* qkvo_wt  = embed_wt + (size_t)512 * 256;  // 8 x [512][512]
  ushortT* ffn1_wt  = qkvo_wt + (size_t)8 * 512 * 512;   // 2 x [2048][512]
  ushortT* ffn2_wt  = ffn1_wt + (size_t)2 * 2048 * 512;  // 2 x [512][2048]
  float* hm = (float*)(ffn2_wt + (size_t)2 * 512 * 2048); // [32][512]
  float* p1 = hm + 16384;                                  // [32][256]
  ushortT* Hb  = (ushortT*)Bv;   // FFN hidden bf16 [16384][2048] (Bv+Bh)
  ushortT* xb  = (ushortT*)Bq;   // x bf16 during embed
  ushortT* QKh = (ushortT*)Bq;   // Qh [0,SZ) + Kh [SZ,2SZ) fp16T

  dim3 blk(256);

  hipMemsetAsync(hm, 0, 16384 * sizeof(float), stream);

  // all weight conversions in one dispatch
  conv_all<<<dim3(16, 64, 13), blk, 0, stream>>>(
      embed_w, qkvo_w, ffn_w1, ffn_w2, embed_wt, qkvo_wt, ffn1_wt, ffn2_wt);

  cvt_bf16<<<dim3(4096), blk, 0, stream>>>(x, xb, B_DIM * S_LEN * IN_DIM / 4);

  // embed: Bh(fp32) + Sb(bf16) = x @ We + be
  gemm_bf16<0, 0, 1><<<dim3(4, 128), blk, 0, stream>>>(
      xb, embed_wt, embed_b, nullptr, Bh, Sb, nullptr, nullptr, 16384, IN_DIM, D_DIM);

  for (int l = 0; l < 2; ++l) {
    const ushortT* qw = qkvo_wt + (size_t)l * 4 * 512 * 512;
    const float* qb = qkvo_b + (size_t)l * 4 * 512;
    // fused QKV: Q -> QKh (fp16T), K -> QKh+SZ (fp16T), V -> Bv (fp32 plain)
    gemm_bf16<0, 0, 3><<<dim3(12, 128), blk, 0, stream>>>(
        Sb, qw, qb, nullptr, Bv, nullptr, QKh, QKh + SZ, 16384, 512, 1536);
    autocorr_f16<<<dim3(B_DIM * 32), dim3(512), 0, stream>>>(QKh, QKh + SZ, Bv, Sb);
    // y = attn @ Wo + bo + h  (overwrites QKh space; Q/K dead)
    gemm_bf16<0, 1, 0><<<dim3(4, 128), blk, 0, stream>>>(
        Sb, qw + (size_t)3 * 512 * 512, qb + 1536, Bh, Bq, nullptr, nullptr, nullptr,
        16384, 512, 512);
    movavg_sub2<0><<<dim3(16, 32), blk, 0, stream>>>(Bq, Bk, Sb, nullptr);
    // FFN (hidden bf16 overlays Bv+Bh, both dead)
    gemm_bf16<1, 0, 2><<<dim3(16, 128), blk, 0, stream>>>(
        Sb, ffn1_wt + (size_t)l * 2048 * 512, ffn_b1 + (size_t)l * DFF_DIM,
        nullptr, nullptr, Hb, nullptr, nullptr, 16384, 512, 2048);
    gemm_bf16<0, 1, 0><<<dim3(4, 128), blk, 0, stream>>>(
        Hb, ffn2_wt + (size_t)l * 512 * 2048, ffn_b2 + (size_t)l * D_DIM,
        Bk, Bq, nullptr, nullptr, nullptr, 16384, 2048, 512);
    if (l == 1)
      movavg_sub2<1><<<dim3(16, 32), blk, 0, stream>>>(Bq, Bh, Sb, hm);
    else
      movavg_sub2<0><<<dim3(16, 32), blk, 0, stream>>>(Bq, Bh, Sb, nullptr);
  }

  proj_head1<<<dim3(8), blk, 0, stream>>>(hm, proj_w1, proj_b1, p1);
  proj_head2<<<dim3(14), blk, 0, stream>>>(p1, proj_w2, proj_b2, out);
}

// Round 10
// 593.494 us; speedup vs baseline: 7.1301x; 1.1518x over previous
//
#include <hip/hip_runtime.h>
#include <hip/hip_bf16.h>

// AutoFormer forward. B=32 S=512 IN=256 D=512 H=8 L=2 DFF=2048 NT=424 K=25
#define S_LEN 512
#define D_DIM 512
#define B_DIM 32
#define IN_DIM 256
#define DFF_DIM 2048
#define NT_DIM 424

static constexpr size_t SZ = (size_t)B_DIM * S_LEN * D_DIM; // 8388608

using s8v = __attribute__((ext_vector_type(8))) short;
using f4v = __attribute__((ext_vector_type(4))) float;
typedef unsigned short ushortT;

__device__ __forceinline__ ushortT f2bf(float f) {
  unsigned u = __float_as_uint(f);
  u += 0x7FFFu + ((u >> 16) & 1u);   // RNE
  return (ushortT)(u >> 16);
}

__device__ __forceinline__ float gelu_tanh(float x) {
  float x3 = x * x * x;
  return 0.5f * x * (1.f + tanhf(0.7978845608028654f * (x + 0.044715f * x3)));
}

__device__ __forceinline__ float2 cadd(float2 a, float2 b) { return float2{a.x + b.x, a.y + b.y}; }
__device__ __forceinline__ float2 csub(float2 a, float2 b) { return float2{a.x - b.x, a.y - b.y}; }
__device__ __forceinline__ float2 cmul(float2 a, float2 b) {
  return float2{a.x * b.x - a.y * b.y, a.x * b.y + a.y * b.x};
}
__device__ __forceinline__ float2 mni(float2 a) { return float2{a.y, -a.x}; } // *(-i)

// 8-point DFT, natural order in/out, e^{-2πi/8} convention.
__device__ __forceinline__ void dft8(float2 a[8]) {
  float2 t0 = cadd(a[0], a[4]), t4 = csub(a[0], a[4]);
  float2 t1 = cadd(a[1], a[5]), t5 = csub(a[1], a[5]);
  float2 t2 = cadd(a[2], a[6]), t6 = csub(a[2], a[6]);
  float2 t3 = cadd(a[3], a[7]), t7 = csub(a[3], a[7]);
  float2 u0 = cadd(t0, t2), u2 = csub(t0, t2);
  float2 u1 = cadd(t1, t3), u3 = csub(t1, t3);
  const float C = 0.70710678118654752f;
  float2 s5 = float2{C * (t5.x + t5.y), C * (t5.y - t5.x)};   // w8 * t5
  float2 s6 = mni(t6);                                        // w8^2 * t6
  float2 s7 = float2{C * (t7.y - t7.x), -C * (t7.x + t7.y)};  // w8^3 * t7
  float2 v0 = cadd(t4, s6), v2 = csub(t4, s6);
  float2 v1 = cadd(s5, s7), v3 = csub(s5, s7);
  a[0] = cadd(u0, u1); a[4] = csub(u0, u1);
  a[2] = cadd(u2, mni(u3)); a[6] = csub(u2, mni(u3));
  a[1] = cadd(v0, v1); a[5] = csub(v0, v1);
  a[3] = cadd(v2, mni(v3)); a[7] = csub(v2, mni(v3));
}

// ---------------------------------------------------------------------------
// All weight conversions in ONE dispatch (z picks the matrix).
// ---------------------------------------------------------------------------
__global__ __launch_bounds__(256) void conv_all(
    const float* __restrict__ embed_w, const float* __restrict__ qkvo_w,
    const float* __restrict__ ffn_w1, const float* __restrict__ ffn_w2,
    ushortT* __restrict__ embed_wt, ushortT* __restrict__ qkvo_wt,
    ushortT* __restrict__ ffn1_wt, ushortT* __restrict__ ffn2_wt)
{
  __shared__ float T[32][33];
  const int z = blockIdx.z;
  const float* W; ushortT* Wt; int Kp, N;
  if (z == 0)       { W = embed_w; Wt = embed_wt; Kp = 256; N = 512; }
  else if (z <= 8)  { int i = z - 1; W = qkvo_w + (size_t)i * 512 * 512;
                      Wt = qkvo_wt + (size_t)i * 512 * 512; Kp = 512; N = 512; }
  else if (z <= 10) { int l = z - 9; W = ffn_w1 + (size_t)l * 512 * 2048;
                      Wt = ffn1_wt + (size_t)l * 2048 * 512; Kp = 512; N = 2048; }
  else              { int l = z - 11; W = ffn_w2 + (size_t)l * 2048 * 512;
                      Wt = ffn2_wt + (size_t)l * 512 * 2048; Kp = 2048; N = 512; }
  int k0, n0;
  if (z >= 11) { k0 = blockIdx.y * 32; n0 = blockIdx.x * 32; }
  else         { k0 = blockIdx.x * 32; n0 = blockIdx.y * 32; }
  if (k0 >= Kp || n0 >= N) return;

  const int tid = threadIdx.x;
  const int col = tid & 31, r8 = tid >> 5;
#pragma unroll
  for (int it = 0; it < 4; ++it) {
    int row = r8 + it * 8;
    T[row][col] = W[(size_t)(k0 + row) * N + n0 + col];
  }
  __syncthreads();
  const int nl = tid >> 3, kq = tid & 7;
#pragma unroll
  for (int j = 0; j < 4; ++j) {
    int kl = kq * 4 + j;
    Wt[(size_t)(n0 + nl) * Kp + k0 + kl] = f2bf(T[kl][nl]);
  }
}

__global__ __launch_bounds__(256) void cvt_bf16(
    const float* __restrict__ in, ushortT* __restrict__ out, int n4)
{
  int i = blockIdx.x * 256 + threadIdx.x;
  if (i >= n4) return;
  float4 v = ((const float4*)in)[i];
  ushortT o[4] = {f2bf(v.x), f2bf(v.y), f2bf(v.z), f2bf(v.w)};
  *(uint2*)&out[(size_t)i * 4] = *(const uint2*)o;
}

// ---------------------------------------------------------------------------
// bf16 MFMA GEMM, 2-phase double-buffered, XCD-aware block swizzle.
// OUT: 0 fp32 only, 1 fp32+bf16, 2 bf16 only,
// 3 = fused QKV (N=1536): Q/K -> fp16 transposed [b][c][s], V -> fp32 plain.
// ---------------------------------------------------------------------------
template<int ACT, int RES, int OUT>
__global__ __launch_bounds__(256) void gemm_bf16(
    const ushortT* __restrict__ A, const ushortT* __restrict__ Wt,
    const float* __restrict__ bias, const float* __restrict__ res,
    float* __restrict__ C, ushortT* __restrict__ Cb,
    ushortT* __restrict__ Qh, ushortT* __restrict__ Kh, int M, int Kp, int N)
{
  __shared__ ushortT Ash[2][128 * 32];
  __shared__ ushortT Wsh[2][128 * 32];
  const int tid = threadIdx.x;
  const int lane = tid & 63, wid = tid >> 6;
  const int fr = lane & 15, kq = lane >> 4;
  const int wr = wid >> 1, wc = wid & 1;

  const int nwg = gridDim.x * gridDim.y;
  const int bid = blockIdx.y * gridDim.x + blockIdx.x;
  const int swz = (bid & 7) * (nwg >> 3) + (bid >> 3);
  const int bx = swz % gridDim.x, by = swz / gridDim.x;
  const int m0 = by * 128, n0 = bx * 128;

  int srow[2], skq[2];
#pragma unroll
  for (int t = 0; t < 2; ++t) {
    int ch = wid * 2 + t;
    int row = ch * 16 + (lane >> 2);
    int kql = lane & 3;
    srow[t] = row;
    skq[t] = kql ^ ((row >> 1) & 3);
  }

  int aoff[4], boff[4];
#pragma unroll
  for (int i = 0; i < 4; ++i) {
    int ra = wr * 64 + i * 16 + fr;
    aoff[i] = ra * 32 + ((kq ^ ((ra >> 1) & 3)) << 3);
    int rb = wc * 64 + i * 16 + fr;
    boff[i] = rb * 32 + ((kq ^ ((rb >> 1) & 3)) << 3);
  }

  auto STAGE = [&](int buf, int k0) {
#pragma unroll
    for (int t = 0; t < 2; ++t) {
      const ushortT* as = A + (size_t)(m0 + srow[t]) * Kp + k0 + skq[t] * 8;
      __builtin_amdgcn_global_load_lds(
          (const __attribute__((address_space(1))) unsigned int*)as,
          (__attribute__((address_space(3))) unsigned int*)&Ash[buf][(wid * 2 + t) * 512],
          16, 0, 0);
      const ushortT* wsrc = Wt + (size_t)(n0 + srow[t]) * Kp + k0 + skq[t] * 8;
      __builtin_amdgcn_global_load_lds(
          (const __attribute__((address_space(1))) unsigned int*)wsrc,
          (__attribute__((address_space(3))) unsigned int*)&Wsh[buf][(wid * 2 + t) * 512],
          16, 0, 0);
    }
  };

  f4v acc[4][4] = {};
  STAGE(0, 0);
  int cur = 0;

  for (int k0 = 0; k0 < Kp; k0 += 32) {
    __syncthreads();
    if (k0 + 32 < Kp) STAGE(cur ^ 1, k0 + 32);
    s8v af[4], bfv[4];
#pragma unroll
    for (int i = 0; i < 4; ++i) {
      af[i]  = *(const s8v*)&Ash[cur][aoff[i]];
      bfv[i] = *(const s8v*)&Wsh[cur][boff[i]];
    }
#pragma unroll
    for (int i = 0; i < 4; ++i)
#pragma unroll
      for (int j = 0; j < 4; ++j)
        acc[i][j] = __builtin_amdgcn_mfma_f32_16x16x32_bf16(af[i], bfv[j], acc[i][j], 0, 0, 0);
    cur ^= 1;
  }

#pragma unroll
  for (int j = 0; j < 4; ++j) {
    const int gc = n0 + wc * 64 + j * 16 + fr;
    const float bv = bias[gc];
#pragma unroll
    for (int i = 0; i < 4; ++i) {
      const int gr0 = m0 + wr * 64 + i * 16 + kq * 4;
      if (OUT == 3) {
        if (gc < 1024) {
          ushortT h4[4];
#pragma unroll
          for (int r = 0; r < 4; ++r) {
            _Float16 hh = (_Float16)(acc[i][j][r] + bv);
            h4[r] = __builtin_bit_cast(ushortT, hh);
          }
          ushortT* dst = (gc < 512 ? Qh : Kh)
                       + ((size_t)(gr0 >> 9) * 512 + (gc & 511)) * 512 + (gr0 & 511);
          *(uint2*)dst = *(const uint2*)h4;
        } else {
#pragma unroll
          for (int r = 0; r < 4; ++r)
            C[(size_t)(gr0 + r) * D_DIM + (gc & 511)] = acc[i][j][r] + bv;
        }
      } else {
#pragma unroll
        for (int r = 0; r < 4; ++r) {
          const int gr = gr0 + r;
          float v = acc[i][j][r] + bv;
          if (RES) v += res[(size_t)gr * N + gc];
          if (ACT == 1) v = gelu_tanh(v);
          if (OUT != 2) C[(size_t)gr * N + gc] = v;
          if (OUT != 0) Cb[(size_t)gr * N + gc] = f2bf(v);
        }
      }
    }
  }
}

// ---------------------------------------------------------------------------
// FFT auto-correlation. 8 channels/block, 512 threads; wave = channel.
// Qh,Kh fp16 transposed [b][c][s]; V fp32 [b][s][c]; out bf16 [b][s][c].
// corr = irfft(rfft(Q)*conj(rfft(K))) via packed z=Q+iK, Stockham radix-8.
// LDS addressing: padded cidx -> cidx + (cidx>>3), channel stride 578 complex.
// ---------------------------------------------------------------------------
__global__ __launch_bounds__(512) void autocorr_fft(
    const ushortT* __restrict__ Qh, const ushortT* __restrict__ Kh,
    const float* __restrict__ V, ushortT* __restrict__ Ob)
{
  __shared__ float2 zs[8 * 578];
  const int tid = threadIdx.x;
  const int b  = blockIdx.x >> 6;
  const int c0 = (blockIdx.x & 63) << 3;
  const int ch = tid >> 6;          // wave index = channel
  const int t  = tid & 63;          // lane
  float2* zc = &zs[ch * 578];

  // ---- load fp16 Q,K -> z = Q + iK (coalesced 16B chunks per lane) ----
  {
    const ushortT* Qg = Qh + ((size_t)b * 512 + c0 + ch) * 512 + t * 8;
    const ushortT* Kg = Kh + ((size_t)b * 512 + c0 + ch) * 512 + t * 8;
    uint4 qv = *(const uint4*)Qg;
    uint4 kv = *(const uint4*)Kg;
    const ushortT* qp = (const ushortT*)&qv;
    const ushortT* kp = (const ushortT*)&kv;
    const int base = 9 * t;         // off(8t) = 8t + t
#pragma unroll
    for (int j = 0; j < 8; ++j) {
      zc[base + j] = float2{(float)__builtin_bit_cast(_Float16, qp[j]),
                            (float)__builtin_bit_cast(_Float16, kp[j])};
    }
  }
  __syncthreads();

  float2 a[8];
  // Stockham radix-8 stage; gather always x[t+64r].
  auto stage_fn = [&](int stage, bool do_scatter) {
#pragma unroll
    for (int r = 0; r < 8; ++r) { int ci = t + 64 * r; a[r] = zc[ci + (ci >> 3)]; }
    dft8(a);
    if (stage < 2) {
      float angle = (stage == 0) ? (-6.283185307179586f / 512.f) * (float)t
                                 : (-6.283185307179586f / 64.f) * (float)(t >> 3);
      float sn, cs;
      __sincosf(angle, &sn, &cs);
      float2 w = float2{cs, sn}, wp = w;
      a[1] = cmul(a[1], wp);
#pragma unroll
      for (int r = 2; r < 8; ++r) { wp = cmul(wp, w); a[r] = cmul(a[r], wp); }
    }
    if (!do_scatter) return;
    __syncthreads();
#pragma unroll
    for (int r = 0; r < 8; ++r) {
      int ci = (stage == 0) ? 8 * t + r
             : (stage == 1) ? (t & 7) + 64 * (t >> 3) + 8 * r
                            : t + 64 * r;
      zc[ci + (ci >> 3)] = a[r];
    }
    __syncthreads();
  };

  // ---- forward FFT: Z[k] in natural order ----
  stage_fn(0, true); stage_fn(1, true); stage_fn(2, true);

  // ---- spectrum: store conj(Qf*conj(Kf)) * (0.25/512) ----
  float2 Zk[8], Zm[8];
#pragma unroll
  for (int r = 0; r < 8; ++r) {
    int k = t + 64 * r, mk = (512 - k) & 511;
    Zk[r] = zc[k + (k >> 3)];
    Zm[r] = zc[mk + (mk >> 3)];
  }
  __syncthreads();
  const float S = 0.00048828125f;   // 0.25/512
#pragma unroll
  for (int r = 0; r < 8; ++r) {
    int k = t + 64 * r;
    float x1 = Zk[r].x, y1 = Zk[r].y, x2 = Zm[r].x, y2 = Zm[r].y;
    float sx = x1 + x2, dx = x1 - x2, sy = y1 + y2, dy = y1 - y2;
    float pre = sx * sy - dy * dx;
    float pim = sx * dx + dy * sy;
    zc[k + (k >> 3)] = float2{pre * S, -pim * S};
  }
  __syncthreads();

  // ---- inverse: corr[t+64r] = Re(FFT(conj P))[t+64r] (scale folded) ----
  stage_fn(0, true); stage_fn(1, true); stage_fn(2, false);

  // ---- softmax over 512 taus (wave-wide shfl) ----
  float corr[8];
#pragma unroll
  for (int r = 0; r < 8; ++r) corr[r] = a[r].x;
  float mx = corr[0];
#pragma unroll
  for (int r = 1; r < 8; ++r) mx = fmaxf(mx, corr[r]);
#pragma unroll
  for (int o = 1; o < 64; o <<= 1) mx = fmaxf(mx, __shfl_xor(mx, o));
  float ex[8], sum = 0.f;
#pragma unroll
  for (int r = 0; r < 8; ++r) { ex[r] = __expf(corr[r] - mx); sum += ex[r]; }
#pragma unroll
  for (int o = 1; o < 64; o <<= 1) sum += __shfl_xor(sum, o);
  const float inv = 1.f / sum;

  __syncthreads();
  float* wl = (float*)zc;           // weights, flat [512] floats per channel
#pragma unroll
  for (int r = 0; r < 8; ++r) wl[t + 64 * r] = ex[r] * inv;
  __syncthreads();

  // ---- out = softmax * V ----
  const float* wall = (const float*)zs;
  const size_t base = (size_t)b * S_LEN * D_DIM + c0;
  for (int i = tid; i < 4096; i += 512) {
    int s = i >> 3, cc = i & 7;
    float wv = wall[cc * 1156 + s];
    size_t ad = base + (size_t)s * D_DIM + cc;
    Ob[ad] = f2bf(wv * V[ad]);
  }
}

// ---------------------------------------------------------------------------
template<int MEAN>
__global__ __launch_bounds__(256) void movavg_sub2(
    const float* __restrict__ y, float* __restrict__ outf,
    ushortT* __restrict__ outb, float* __restrict__ hm)
{
  __shared__ float ys[512 * 32];
  const int tid = threadIdx.x;
  const int b = blockIdx.y, d0 = blockIdx.x * 32;
  const float* yb = y + (size_t)b * S_LEN * D_DIM + d0;

#pragma unroll 4
  for (int p = 0; p < 16; ++p) {
    int i = p * 256 + tid;
    int s = i >> 3, dq = i & 7;
    float4 v = *(const float4*)(yb + (size_t)s * D_DIM + dq * 4);
    *(float4*)&ys[s * 32 + dq * 4] = v;
  }
  __syncthreads();

  const int d = tid & 31, sg = tid >> 5;
  const int s0 = sg * 64;
  int lo = max(s0 - 12, 0), hi = min(s0 + 13, S_LEN);
  float sum = 0.f;
  for (int t = lo; t < hi; ++t) sum += ys[t * 32 + d];

  float msum = 0.f;
  const size_t gb = (size_t)b * S_LEN * D_DIM + d0 + d;
  for (int i = 0; i < 64; ++i) {
    const int s = s0 + i;
    float val = ys[s * 32 + d] - sum / (float)(hi - lo);
    size_t g = gb + (size_t)s * D_DIM;
    outf[g] = val;
    outb[g] = f2bf(val);
    if (MEAN) msum += val;
    int add = s + 13;
    if (add < S_LEN) { sum += ys[add * 32 + d]; hi = add + 1; }
    int rem = s - 12;
    if (rem >= 0) { sum -= ys[rem * 32 + d]; lo = rem + 1; }
  }
  if (MEAN) atomicAdd(&hm[b * D_DIM + d0 + d], msum * (1.f / (float)S_LEN));
}

// ---------------------------------------------------------------------------
__global__ __launch_bounds__(256) void proj_head1(
    const float* __restrict__ hm, const float* __restrict__ W1,
    const float* __restrict__ b1, float* __restrict__ p1)
{
  __shared__ float hs[32 * 512];
  const int tid = threadIdx.x, n0 = blockIdx.x * 32;
  for (int i = tid; i < 16384; i += 256) hs[i] = hm[i];
  __syncthreads();
  const int n = tid & 31, mg = tid >> 5;
  float acc[4] = {};
  for (int k = 0; k < 512; ++k) {
    float w = W1[(size_t)k * 256 + n0 + n];
#pragma unroll
    for (int mi = 0; mi < 4; ++mi)
      acc[mi] = fmaf(hs[(mg * 4 + mi) * 512 + k], w, acc[mi]);
  }
  const float bb = b1[n0 + n];
#pragma unroll
  for (int mi = 0; mi < 4; ++mi)
    p1[(size_t)(mg * 4 + mi) * 256 + n0 + n] = fmaxf(acc[mi] + bb, 0.f);
}

__global__ __launch_bounds__(256) void proj_head2(
    const float* __restrict__ p1, const float* __restrict__ W2,
    const float* __restrict__ b2, float* __restrict__ out)
{
  __shared__ float ps[32 * 256];
  const int tid = threadIdx.x;
  for (int i = tid; i < 8192; i += 256) ps[i] = p1[i];
  __syncthreads();
  const int n = tid & 31, mg = tid >> 5;
  const int ng = blockIdx.x * 32 + n;
  const bool ok = ng < NT_DIM;
  float acc[4] = {};
  for (int k = 0; k < 256; ++k) {
    float w = ok ? W2[(size_t)k * NT_DIM + ng] : 0.f;
#pragma unroll
    for (int mi = 0; mi < 4; ++mi)
      acc[mi] = fmaf(ps[(mg * 4 + mi) * 256 + k], w, acc[mi]);
  }
  if (ok) {
    const float bb = b2[ng];
#pragma unroll
    for (int mi = 0; mi < 4; ++mi)
      out[(size_t)(mg * 4 + mi) * NT_DIM + ng] = acc[mi] + bb;
  }
}

// ---------------------------------------------------------------------------
extern "C" void kernel_launch(void* const* d_in, const int* in_sizes, int n_in,
                              void* d_out, int out_size, void* d_ws, size_t ws_size,
                              hipStream_t stream)
{
  const float* x       = (const float*)d_in[0];
  const float* embed_w = (const float*)d_in[1];
  const float* embed_b = (const float*)d_in[2];
  const float* qkvo_w  = (const float*)d_in[3];
  const float* qkvo_b  = (const float*)d_in[4];
  const float* ffn_w1  = (const float*)d_in[5];
  const float* ffn_b1  = (const float*)d_in[6];
  const float* ffn_w2  = (const float*)d_in[7];
  const float* ffn_b2  = (const float*)d_in[8];
  const float* proj_w1 = (const float*)d_in[9];
  const float* proj_b1 = (const float*)d_in[10];
  const float* proj_w2 = (const float*)d_in[11];
  const float* proj_b2 = (const float*)d_in[12];
  float* out = (float*)d_out;

  float* ws = (float*)d_ws;
  float* Bv = ws;              // V fp32; overlaid by Hb during FFN
  float* Bh = ws + SZ;         // h (residual); overlaid by Hb during FFN
  float* Bq = ws + 2 * SZ;     // Qh+Kh (fp16T) -> y (fp32); xb during embed
  float* Bk = ws + 3 * SZ;     // x1 (seasonal, fp32)
  ushortT* Sb = (ushortT*)(ws + 4 * SZ);            // bf16 activation mirror
  ushortT* Wb = (ushortT*)(ws + 4 * SZ + SZ / 2);   // bf16 weights
  ushortT* embed_wt = Wb;                            // [512][256]
  ushortT* qkvo_wt  = embed_wt + (size_t)512 * 256;  // 8 x [512][512]
  ushortT* ffn1_wt  = qkvo_wt + (size_t)8 * 512 * 512;   // 2 x [2048][512]
  ushortT* ffn2_wt  = ffn1_wt + (size_t)2 * 2048 * 512;  // 2 x [512][2048]
  float* hm = (float*)(ffn2_wt + (size_t)2 * 512 * 2048); // [32][512]
  float* p1 = hm + 16384;                                  // [32][256]
  ushortT* Hb  = (ushortT*)Bv;   // FFN hidden bf16 [16384][2048] (Bv+Bh)
  ushortT* xb  = (ushortT*)Bq;   // x bf16 during embed
  ushortT* QKh = (ushortT*)Bq;   // Qh [0,SZ) + Kh [SZ,2SZ) fp16T

  dim3 blk(256);

  hipMemsetAsync(hm, 0, 16384 * sizeof(float), stream);

  conv_all<<<dim3(16, 64, 13), blk, 0, stream>>>(
      embed_w, qkvo_w, ffn_w1, ffn_w2, embed_wt, qkvo_wt, ffn1_wt, ffn2_wt);

  cvt_bf16<<<dim3(4096), blk, 0, stream>>>(x, xb, B_DIM * S_LEN * IN_DIM / 4);

  // embed: Bh(fp32) + Sb(bf16) = x @ We + be
  gemm_bf16<0, 0, 1><<<dim3(4, 128), blk, 0, stream>>>(
      xb, embed_wt, embed_b, nullptr, Bh, Sb, nullptr, nullptr, 16384, IN_DIM, D_DIM);

  for (int l = 0; l < 2; ++l) {
    const ushortT* qw = qkvo_wt + (size_t)l * 4 * 512 * 512;
    const float* qb = qkvo_b + (size_t)l * 4 * 512;
    // fused QKV: Q -> QKh (fp16T), K -> QKh+SZ (fp16T), V -> Bv (fp32 plain)
    gemm_bf16<0, 0, 3><<<dim3(12, 128), blk, 0, stream>>>(
        Sb, qw, qb, nullptr, Bv, nullptr, QKh, QKh + SZ, 16384, 512, 1536);
    autocorr_fft<<<dim3(B_DIM * 64), dim3(512), 0, stream>>>(QKh, QKh + SZ, Bv, Sb);
    // y = attn @ Wo + bo + h  (overwrites QKh space; Q/K dead)
    gemm_bf16<0, 1, 0><<<dim3(4, 128), blk, 0, stream>>>(
        Sb, qw + (size_t)3 * 512 * 512, qb + 1536, Bh, Bq, nullptr, nullptr, nullptr,
        16384, 512, 512);
    movavg_sub2<0><<<dim3(16, 32), blk, 0, stream>>>(Bq, Bk, Sb, nullptr);
    // FFN (hidden bf16 overlays Bv+Bh, both dead)
    gemm_bf16<1, 0, 2><<<dim3(16, 128), blk, 0, stream>>>(
        Sb, ffn1_wt + (size_t)l * 2048 * 512, ffn_b1 + (size_t)l * DFF_DIM,
        nullptr, nullptr, Hb, nullptr, nullptr, 16384, 512, 2048);
    gemm_bf16<0, 1, 0><<<dim3(4, 128), blk, 0, stream>>>(
        Hb, ffn2_wt + (size_t)l * 512 * 2048, ffn_b2 + (size_t)l * D_DIM,
        Bk, Bq, nullptr, nullptr, nullptr, 16384, 2048, 512);
    if (l == 1)
      movavg_sub2<1><<<dim3(16, 32), blk, 0, stream>>>(Bq, Bh, Sb, hm);
    else
      movavg_sub2<0><<<dim3(16, 32), blk, 0, stream>>>(Bq, Bh, Sb, nullptr);
  }

  proj_head1<<<dim3(8), blk, 0, stream>>>(hm, proj_w1, proj_b1, p1);
  proj_head2<<<dim3(14), blk, 0, stream>>>(p1, proj_w2, proj_b2, out);
}

// Round 11
// 556.704 us; speedup vs baseline: 7.6013x; 1.0661x over previous
//
#include <hip/hip_runtime.h>
#include <hip/hip_bf16.h>

// AutoFormer forward. B=32 S=512 IN=256 D=512 H=8 L=2 DFF=2048 NT=424 K=25
#define S_LEN 512
#define D_DIM 512
#define B_DIM 32
#define IN_DIM 256
#define DFF_DIM 2048
#define NT_DIM 424

static constexpr size_t SZ = (size_t)B_DIM * S_LEN * D_DIM; // 8388608

using s8v = __attribute__((ext_vector_type(8))) short;
using f4v = __attribute__((ext_vector_type(4))) float;
typedef unsigned short ushortT;

__device__ __forceinline__ ushortT f2bf(float f) {
  unsigned u = __float_as_uint(f);
  u += 0x7FFFu + ((u >> 16) & 1u);   // RNE
  return (ushortT)(u >> 16);
}

// gelu(tanh approx) == x * sigmoid(2*0.7978845608*(x+0.044715x^3)) exactly
__device__ __forceinline__ float gelu_fast(float x) {
  float a = 1.5957691216057308f * (x + 0.044715f * x * x * x);
  return x / (1.f + __expf(-a));
}

__device__ __forceinline__ float2 cadd(float2 a, float2 b) { return float2{a.x + b.x, a.y + b.y}; }
__device__ __forceinline__ float2 csub(float2 a, float2 b) { return float2{a.x - b.x, a.y - b.y}; }
__device__ __forceinline__ float2 cmul(float2 a, float2 b) {
  return float2{a.x * b.x - a.y * b.y, a.x * b.y + a.y * b.x};
}
__device__ __forceinline__ float2 mni(float2 a) { return float2{a.y, -a.x}; } // *(-i)

// 8-point DFT, natural order in/out, e^{-2πi/8} convention.
__device__ __forceinline__ void dft8(float2 a[8]) {
  float2 t0 = cadd(a[0], a[4]), t4 = csub(a[0], a[4]);
  float2 t1 = cadd(a[1], a[5]), t5 = csub(a[1], a[5]);
  float2 t2 = cadd(a[2], a[6]), t6 = csub(a[2], a[6]);
  float2 t3 = cadd(a[3], a[7]), t7 = csub(a[3], a[7]);
  float2 u0 = cadd(t0, t2), u2 = csub(t0, t2);
  float2 u1 = cadd(t1, t3), u3 = csub(t1, t3);
  const float C = 0.70710678118654752f;
  float2 s5 = float2{C * (t5.x + t5.y), C * (t5.y - t5.x)};
  float2 s6 = mni(t6);
  float2 s7 = float2{C * (t7.y - t7.x), -C * (t7.x + t7.y)};
  float2 v0 = cadd(t4, s6), v2 = csub(t4, s6);
  float2 v1 = cadd(s5, s7), v3 = csub(s5, s7);
  a[0] = cadd(u0, u1); a[4] = csub(u0, u1);
  a[2] = cadd(u2, mni(u3)); a[6] = csub(u2, mni(u3));
  a[1] = cadd(v0, v1); a[5] = csub(v0, v1);
  a[3] = cadd(v2, mni(v3)); a[7] = csub(v2, mni(v3));
}

// ---------------------------------------------------------------------------
// All weight conversions in ONE dispatch (z picks the matrix).
// ---------------------------------------------------------------------------
__global__ __launch_bounds__(256) void conv_all(
    const float* __restrict__ embed_w, const float* __restrict__ qkvo_w,
    const float* __restrict__ ffn_w1, const float* __restrict__ ffn_w2,
    ushortT* __restrict__ embed_wt, ushortT* __restrict__ qkvo_wt,
    ushortT* __restrict__ ffn1_wt, ushortT* __restrict__ ffn2_wt)
{
  __shared__ float T[32][33];
  const int z = blockIdx.z;
  const float* W; ushortT* Wt; int Kp, N;
  if (z == 0)       { W = embed_w; Wt = embed_wt; Kp = 256; N = 512; }
  else if (z <= 8)  { int i = z - 1; W = qkvo_w + (size_t)i * 512 * 512;
                      Wt = qkvo_wt + (size_t)i * 512 * 512; Kp = 512; N = 512; }
  else if (z <= 10) { int l = z - 9; W = ffn_w1 + (size_t)l * 512 * 2048;
                      Wt = ffn1_wt + (size_t)l * 2048 * 512; Kp = 512; N = 2048; }
  else              { int l = z - 11; W = ffn_w2 + (size_t)l * 2048 * 512;
                      Wt = ffn2_wt + (size_t)l * 512 * 2048; Kp = 2048; N = 512; }
  int k0, n0;
  if (z >= 11) { k0 = blockIdx.y * 32; n0 = blockIdx.x * 32; }
  else         { k0 = blockIdx.x * 32; n0 = blockIdx.y * 32; }
  if (k0 >= Kp || n0 >= N) return;

  const int tid = threadIdx.x;
  const int col = tid & 31, r8 = tid >> 5;
#pragma unroll
  for (int it = 0; it < 4; ++it) {
    int row = r8 + it * 8;
    T[row][col] = W[(size_t)(k0 + row) * N + n0 + col];
  }
  __syncthreads();
  const int nl = tid >> 3, kq = tid & 7;
#pragma unroll
  for (int j = 0; j < 4; ++j) {
    int kl = kq * 4 + j;
    Wt[(size_t)(n0 + nl) * Kp + k0 + kl] = f2bf(T[kl][nl]);
  }
}

__global__ __launch_bounds__(256) void cvt_bf16(
    const float* __restrict__ in, ushortT* __restrict__ out, int n4)
{
  int i = blockIdx.x * 256 + threadIdx.x;
  if (i >= n4) return;
  float4 v = ((const float4*)in)[i];
  ushortT o[4] = {f2bf(v.x), f2bf(v.y), f2bf(v.z), f2bf(v.w)};
  *(uint2*)&out[(size_t)i * 4] = *(const uint2*)o;
}

// ---------------------------------------------------------------------------
// bf16 MFMA GEMM, 2-phase double-buffered, XCD-aware block swizzle.
// OUT: 0 fp32 only, 1 fp32+bf16, 2 bf16 only,
// 3 = fused QKV (N=1536): Q/K -> fp16 transposed [b][c][s], V -> fp32 plain.
// Low-precision outputs go through an LDS transpose tile (union with the
// staging buffers) so global stores are 256B-contiguous per 16 lanes.
// ---------------------------------------------------------------------------
template<int ACT, int RES, int OUT>
__global__ __launch_bounds__(256) void gemm_bf16(
    const ushortT* __restrict__ A, const ushortT* __restrict__ Wt,
    const float* __restrict__ bias, const float* __restrict__ res,
    float* __restrict__ C, ushortT* __restrict__ Cb,
    ushortT* __restrict__ Qh, ushortT* __restrict__ Kh, int M, int Kp, int N)
{
  // union: staging (2 bufs x (A 8KB | W 8KB) = 16384 ushorts)  /
  //        epilogue transpose tile [128][132] = 16896 ushorts
  __shared__ __align__(16) ushortT smem[16896];
  ushortT* Tt = smem;

  const int tid = threadIdx.x;
  const int lane = tid & 63, wid = tid >> 6;
  const int fr = lane & 15, kq = lane >> 4;
  const int wr = wid >> 1, wc = wid & 1;

  const int nwg = gridDim.x * gridDim.y;
  const int bid = blockIdx.y * gridDim.x + blockIdx.x;
  const int swz = (bid & 7) * (nwg >> 3) + (bid >> 3);
  const int bx = swz % gridDim.x, by = swz / gridDim.x;
  const int m0 = by * 128, n0 = bx * 128;

  int srow[2], skq[2];
#pragma unroll
  for (int t = 0; t < 2; ++t) {
    int ch = wid * 2 + t;
    int row = ch * 16 + (lane >> 2);
    int kql = lane & 3;
    srow[t] = row;
    skq[t] = kql ^ ((row >> 1) & 3);
  }

  int aoff[4], boff[4];
#pragma unroll
  for (int i = 0; i < 4; ++i) {
    int ra = wr * 64 + i * 16 + fr;
    aoff[i] = ra * 32 + ((kq ^ ((ra >> 1) & 3)) << 3);
    int rb = wc * 64 + i * 16 + fr;
    boff[i] = rb * 32 + ((kq ^ ((rb >> 1) & 3)) << 3);
  }

  auto STAGE = [&](int buf, int k0) {
#pragma unroll
    for (int t = 0; t < 2; ++t) {
      const ushortT* as = A + (size_t)(m0 + srow[t]) * Kp + k0 + skq[t] * 8;
      __builtin_amdgcn_global_load_lds(
          (const __attribute__((address_space(1))) unsigned int*)as,
          (__attribute__((address_space(3))) unsigned int*)&smem[buf * 4096 + (wid * 2 + t) * 512],
          16, 0, 0);
      const ushortT* wsrc = Wt + (size_t)(n0 + srow[t]) * Kp + k0 + skq[t] * 8;
      __builtin_amdgcn_global_load_lds(
          (const __attribute__((address_space(1))) unsigned int*)wsrc,
          (__attribute__((address_space(3))) unsigned int*)&smem[8192 + buf * 4096 + (wid * 2 + t) * 512],
          16, 0, 0);
    }
  };

  f4v acc[4][4] = {};
  STAGE(0, 0);
  int cur = 0;

  for (int k0 = 0; k0 < Kp; k0 += 32) {
    __syncthreads();
    if (k0 + 32 < Kp) STAGE(cur ^ 1, k0 + 32);
    s8v af[4], bfv[4];
#pragma unroll
    for (int i = 0; i < 4; ++i) {
      af[i]  = *(const s8v*)&smem[cur * 4096 + aoff[i]];
      bfv[i] = *(const s8v*)&smem[8192 + cur * 4096 + boff[i]];
    }
#pragma unroll
    for (int i = 0; i < 4; ++i)
#pragma unroll
      for (int j = 0; j < 4; ++j)
        acc[i][j] = __builtin_amdgcn_mfma_f32_16x16x32_bf16(af[i], bfv[j], acc[i][j], 0, 0, 0);
    cur ^= 1;
  }

  // ---- epilogue (C/D layout: col=lane&15, row=(lane>>4)*4+reg) ----
  if (OUT == 3 && n0 < 1024) {
    // Q or K -> fp16 transposed [b][c][s]; stash Tt[c][s], then coalesced.
    __syncthreads();           // staging LDS reads finished block-wide
#pragma unroll
    for (int j = 0; j < 4; ++j) {
      const int c = wc * 64 + j * 16 + fr;
      const float bv = bias[n0 + c];
#pragma unroll
      for (int i = 0; i < 4; ++i)
#pragma unroll
        for (int r = 0; r < 4; ++r) {
          const int s = wr * 64 + i * 16 + kq * 4 + r;
          _Float16 hh = (_Float16)(acc[i][j][r] + bv);
          Tt[c * 132 + s] = __builtin_bit_cast(ushortT, hh);
        }
    }
    __syncthreads();
    ushortT* dstM = (n0 < 512) ? Qh : Kh;
    const int cg0 = n0 & 511;
    const int bb = m0 >> 9, ss0 = m0 & 511;
    const int g = tid >> 4, ln = tid & 15;
#pragma unroll
    for (int p = 0; p < 8; ++p) {
      const int c = p * 16 + g;
      uint4 v = *(const uint4*)&Tt[c * 132 + ln * 8];
      *(uint4*)&dstM[((size_t)bb * 512 + cg0 + c) * 512 + ss0 + ln * 8] = v;
    }
  } else if (OUT == 3) {
    // V -> fp32 plain [row][c] (64B runs, already coalesced)
#pragma unroll
    for (int j = 0; j < 4; ++j) {
      const int gc = n0 + wc * 64 + j * 16 + fr;
      const float bv = bias[gc];
#pragma unroll
      for (int i = 0; i < 4; ++i) {
        const int gr0 = m0 + wr * 64 + i * 16 + kq * 4;
#pragma unroll
        for (int r = 0; r < 4; ++r)
          C[(size_t)(gr0 + r) * D_DIM + (gc & 511)] = acc[i][j][r] + bv;
      }
    }
  } else {
    if (OUT != 0) __syncthreads();   // will overwrite staging LDS
#pragma unroll
    for (int j = 0; j < 4; ++j) {
      const int lc = wc * 64 + j * 16 + fr;
      const int gc = n0 + lc;
      const float bv = bias[gc];
#pragma unroll
      for (int i = 0; i < 4; ++i)
#pragma unroll
        for (int r = 0; r < 4; ++r) {
          const int lr = wr * 64 + i * 16 + kq * 4 + r;
          const int gr = m0 + lr;
          float v = acc[i][j][r] + bv;
          if (RES) v += res[(size_t)gr * N + gc];
          if (ACT == 1) v = gelu_fast(v);
          if (OUT != 2) C[(size_t)gr * N + gc] = v;
          if (OUT != 0) Tt[lr * 132 + lc] = f2bf(v);
        }
    }
    if (OUT != 0) {
      __syncthreads();
      const int g = tid >> 4, ln = tid & 15;
#pragma unroll
      for (int p = 0; p < 8; ++p) {
        const int row = p * 16 + g;
        uint4 v = *(const uint4*)&Tt[row * 132 + ln * 8];
        *(uint4*)&Cb[(size_t)(m0 + row) * N + n0 + ln * 8] = v;
      }
    }
  }
}

// ---------------------------------------------------------------------------
// FFT auto-correlation. 8 channels/block, 512 threads; wave = channel.
// ---------------------------------------------------------------------------
__global__ __launch_bounds__(512) void autocorr_fft(
    const ushortT* __restrict__ Qh, const ushortT* __restrict__ Kh,
    const float* __restrict__ V, ushortT* __restrict__ Ob)
{
  __shared__ float2 zs[8 * 578];
  const int tid = threadIdx.x;
  const int b  = blockIdx.x >> 6;
  const int c0 = (blockIdx.x & 63) << 3;
  const int ch = tid >> 6;
  const int t  = tid & 63;
  float2* zc = &zs[ch * 578];

  {
    const ushortT* Qg = Qh + ((size_t)b * 512 + c0 + ch) * 512 + t * 8;
    const ushortT* Kg = Kh + ((size_t)b * 512 + c0 + ch) * 512 + t * 8;
    uint4 qv = *(const uint4*)Qg;
    uint4 kv = *(const uint4*)Kg;
    const ushortT* qp = (const ushortT*)&qv;
    const ushortT* kp = (const ushortT*)&kv;
    const int base = 9 * t;
#pragma unroll
    for (int j = 0; j < 8; ++j) {
      zc[base + j] = float2{(float)__builtin_bit_cast(_Float16, qp[j]),
                            (float)__builtin_bit_cast(_Float16, kp[j])};
    }
  }
  __syncthreads();

  float2 a[8];
  auto stage_fn = [&](int stage, bool do_scatter) {
#pragma unroll
    for (int r = 0; r < 8; ++r) { int ci = t + 64 * r; a[r] = zc[ci + (ci >> 3)]; }
    dft8(a);
    if (stage < 2) {
      float angle = (stage == 0) ? (-6.283185307179586f / 512.f) * (float)t
                                 : (-6.283185307179586f / 64.f) * (float)(t >> 3);
      float sn, cs;
      __sincosf(angle, &sn, &cs);
      float2 w = float2{cs, sn}, wp = w;
      a[1] = cmul(a[1], wp);
#pragma unroll
      for (int r = 2; r < 8; ++r) { wp = cmul(wp, w); a[r] = cmul(a[r], wp); }
    }
    if (!do_scatter) return;
    __syncthreads();
#pragma unroll
    for (int r = 0; r < 8; ++r) {
      int ci = (stage == 0) ? 8 * t + r
             : (stage == 1) ? (t & 7) + 64 * (t >> 3) + 8 * r
                            : t + 64 * r;
      zc[ci + (ci >> 3)] = a[r];
    }
    __syncthreads();
  };

  stage_fn(0, true); stage_fn(1, true); stage_fn(2, true);

  float2 Zk[8], Zm[8];
#pragma unroll
  for (int r = 0; r < 8; ++r) {
    int k = t + 64 * r, mk = (512 - k) & 511;
    Zk[r] = zc[k + (k >> 3)];
    Zm[r] = zc[mk + (mk >> 3)];
  }
  __syncthreads();
  const float S = 0.00048828125f;   // 0.25/512
#pragma unroll
  for (int r = 0; r < 8; ++r) {
    int k = t + 64 * r;
    float x1 = Zk[r].x, y1 = Zk[r].y, x2 = Zm[r].x, y2 = Zm[r].y;
    float sx = x1 + x2, dx = x1 - x2, sy = y1 + y2, dy = y1 - y2;
    float pre = sx * sy - dy * dx;
    float pim = sx * dx + dy * sy;
    zc[k + (k >> 3)] = float2{pre * S, -pim * S};
  }
  __syncthreads();

  stage_fn(0, true); stage_fn(1, true); stage_fn(2, false);

  float corr[8];
#pragma unroll
  for (int r = 0; r < 8; ++r) corr[r] = a[r].x;
  float mx = corr[0];
#pragma unroll
  for (int r = 1; r < 8; ++r) mx = fmaxf(mx, corr[r]);
#pragma unroll
  for (int o = 1; o < 64; o <<= 1) mx = fmaxf(mx, __shfl_xor(mx, o));
  float ex[8], sum = 0.f;
#pragma unroll
  for (int r = 0; r < 8; ++r) { ex[r] = __expf(corr[r] - mx); sum += ex[r]; }
#pragma unroll
  for (int o = 1; o < 64; o <<= 1) sum += __shfl_xor(sum, o);
  const float inv = 1.f / sum;

  __syncthreads();
  float* wl = (float*)zc;
#pragma unroll
  for (int r = 0; r < 8; ++r) wl[t + 64 * r] = ex[r] * inv;
  __syncthreads();

  const float* wall = (const float*)zs;
  const size_t base = (size_t)b * S_LEN * D_DIM + c0;
  for (int i = tid; i < 4096; i += 512) {
    int s = i >> 3, cc = i & 7;
    float wv = wall[cc * 1156 + s];
    size_t ad = base + (size_t)s * D_DIM + cc;
    Ob[ad] = f2bf(wv * V[ad]);
  }
}

// ---------------------------------------------------------------------------
template<int MEAN>
__global__ __launch_bounds__(256) void movavg_sub2(
    const float* __restrict__ y, float* __restrict__ outf,
    ushortT* __restrict__ outb, float* __restrict__ hm)
{
  __shared__ float ys[512 * 32];
  const int tid = threadIdx.x;
  const int b = blockIdx.y, d0 = blockIdx.x * 32;
  const float* yb = y + (size_t)b * S_LEN * D_DIM + d0;

#pragma unroll 4
  for (int p = 0; p < 16; ++p) {
    int i = p * 256 + tid;
    int s = i >> 3, dq = i & 7;
    float4 v = *(const float4*)(yb + (size_t)s * D_DIM + dq * 4);
    *(float4*)&ys[s * 32 + dq * 4] = v;
  }
  __syncthreads();

  const int d = tid & 31, sg = tid >> 5;
  const int s0 = sg * 64;
  int lo = max(s0 - 12, 0), hi = min(s0 + 13, S_LEN);
  float sum = 0.f;
  for (int t = lo; t < hi; ++t) sum += ys[t * 32 + d];

  float msum = 0.f;
  const size_t gb = (size_t)b * S_LEN * D_DIM + d0 + d;
  for (int i = 0; i < 64; ++i) {
    const int s = s0 + i;
    float val = ys[s * 32 + d] - sum / (float)(hi - lo);
    size_t g = gb + (size_t)s * D_DIM;
    outf[g] = val;
    outb[g] = f2bf(val);
    if (MEAN) msum += val;
    int add = s + 13;
    if (add < S_LEN) { sum += ys[add * 32 + d]; hi = add + 1; }
    int rem = s - 12;
    if (rem >= 0) { sum -= ys[rem * 32 + d]; lo = rem + 1; }
  }
  if (MEAN) atomicAdd(&hm[b * D_DIM + d0 + d], msum * (1.f / (float)S_LEN));
}

// ---------------------------------------------------------------------------
__global__ __launch_bounds__(256) void proj_head1(
    const float* __restrict__ hm, const float* __restrict__ W1,
    const float* __restrict__ b1, float* __restrict__ p1)
{
  __shared__ float hs[32 * 512];
  const int tid = threadIdx.x, n0 = blockIdx.x * 32;
  for (int i = tid; i < 16384; i += 256) hs[i] = hm[i];
  __syncthreads();
  const int n = tid & 31, mg = tid >> 5;
  float acc[4] = {};
  for (int k = 0; k < 512; ++k) {
    float w = W1[(size_t)k * 256 + n0 + n];
#pragma unroll
    for (int mi = 0; mi < 4; ++mi)
      acc[mi] = fmaf(hs[(mg * 4 + mi) * 512 + k], w, acc[mi]);
  }
  const float bb = b1[n0 + n];
#pragma unroll
  for (int mi = 0; mi < 4; ++mi)
    p1[(size_t)(mg * 4 + mi) * 256 + n0 + n] = fmaxf(acc[mi] + bb, 0.f);
}

__global__ __launch_bounds__(256) void proj_head2(
    const float* __restrict__ p1, const float* __restrict__ W2,
    const float* __restrict__ b2, float* __restrict__ out)
{
  __shared__ float ps[32 * 256];
  const int tid = threadIdx.x;
  for (int i = tid; i < 8192; i += 256) ps[i] = p1[i];
  __syncthreads();
  const int n = tid & 31, mg = tid >> 5;
  const int ng = blockIdx.x * 32 + n;
  const bool ok = ng < NT_DIM;
  float acc[4] = {};
  for (int k = 0; k < 256; ++k) {
    float w = ok ? W2[(size_t)k * NT_DIM + ng] : 0.f;
#pragma unroll
    for (int mi = 0; mi < 4; ++mi)
      acc[mi] = fmaf(ps[(mg * 4 + mi) * 256 + k], w, acc[mi]);
  }
  if (ok) {
    const float bb = b2[ng];
#pragma unroll
    for (int mi = 0; mi < 4; ++mi)
      out[(size_t)(mg * 4 + mi) * NT_DIM + ng] = acc[mi] + bb;
  }
}

// ---------------------------------------------------------------------------
extern "C" void kernel_launch(void* const* d_in, const int* in_sizes, int n_in,
                              void* d_out, int out_size, void* d_ws, size_t ws_size,
                              hipStream_t stream)
{
  const float* x       = (const float*)d_in[0];
  const float* embed_w = (const float*)d_in[1];
  const float* embed_b = (const float*)d_in[2];
  const float* qkvo_w  = (const float*)d_in[3];
  const float* qkvo_b  = (const float*)d_in[4];
  const float* ffn_w1  = (const float*)d_in[5];
  const float* ffn_b1  = (const float*)d_in[6];
  const float* ffn_w2  = (const float*)d_in[7];
  const float* ffn_b2  = (const float*)d_in[8];
  const float* proj_w1 = (const float*)d_in[9];
  const float* proj_b1 = (const float*)d_in[10];
  const float* proj_w2 = (const float*)d_in[11];
  const float* proj_b2 = (const float*)d_in[12];
  float* out = (float*)d_out;

  float* ws = (float*)d_ws;
  float* Bv = ws;              // V fp32; overlaid by Hb during FFN
  float* Bh = ws + SZ;         // h (residual); overlaid by Hb during FFN
  float* Bq = ws + 2 * SZ;     // Qh+Kh (fp16T) -> y (fp32); xb during embed
  float* Bk = ws + 3 * SZ;     // x1 (seasonal, fp32)
  ushortT* Sb = (ushortT*)(ws + 4 * SZ);            // bf16 activation mirror
  ushortT* Wb = (ushortT*)(ws + 4 * SZ + SZ / 2);   // bf16 weights
  ushortT* embed_wt = Wb;                            // [512][256]
  ushortT* qkvo_wt  = embed_wt + (size_t)512 * 256;  // 8 x [512][512]
  ushortT* ffn1_wt  = qkvo_wt + (size_t)8 * 512 * 512;   // 2 x [2048][512]
  ushortT* ffn2_wt  = ffn1_wt + (size_t)2 * 2048 * 512;  // 2 x [512][2048]
  float* hm = (float*)(ffn2_wt + (size_t)2 * 512 * 2048); // [32][512]
  float* p1 = hm + 16384;                                  // [32][256]
  ushortT* Hb  = (ushortT*)Bv;   // FFN hidden bf16 [16384][2048] (Bv+Bh)
  ushortT* xb  = (ushortT*)Bq;   // x bf16 during embed
  ushortT* QKh = (ushortT*)Bq;   // Qh [0,SZ) + Kh [SZ,2SZ) fp16T

  dim3 blk(256);

  hipMemsetAsync(hm, 0, 16384 * sizeof(float), stream);

  conv_all<<<dim3(16, 64, 13), blk, 0, stream>>>(
      embed_w, qkvo_w, ffn_w1, ffn_w2, embed_wt, qkvo_wt, ffn1_wt, ffn2_wt);

  cvt_bf16<<<dim3(4096), blk, 0, stream>>>(x, xb, B_DIM * S_LEN * IN_DIM / 4);

  // embed: Bh(fp32) + Sb(bf16) = x @ We + be
  gemm_bf16<0, 0, 1><<<dim3(4, 128), blk, 0, stream>>>(
      xb, embed_wt, embed_b, nullptr, Bh, Sb, nullptr, nullptr, 16384, IN_DIM, D_DIM);

  for (int l = 0; l < 2; ++l) {
    const ushortT* qw = qkvo_wt + (size_t)l * 4 * 512 * 512;
    const float* qb = qkvo_b + (size_t)l * 4 * 512;
    // fused QKV: Q -> QKh (fp16T), K -> QKh+SZ (fp16T), V -> Bv (fp32 plain)
    gemm_bf16<0, 0, 3><<<dim3(12, 128), blk, 0, stream>>>(
        Sb, qw, qb, nullptr, Bv, nullptr, QKh, QKh + SZ, 16384, 512, 1536);
    autocorr_fft<<<dim3(B_DIM * 64), dim3(512), 0, stream>>>(QKh, QKh + SZ, Bv, Sb);
    // y = attn @ Wo + bo + h  (overwrites QKh space; Q/K dead)
    gemm_bf16<0, 1, 0><<<dim3(4, 128), blk, 0, stream>>>(
        Sb, qw + (size_t)3 * 512 * 512, qb + 1536, Bh, Bq, nullptr, nullptr, nullptr,
        16384, 512, 512);
    movavg_sub2<0><<<dim3(16, 32), blk, 0, stream>>>(Bq, Bk, Sb, nullptr);
    // FFN (hidden bf16 overlays Bv+Bh, both dead)
    gemm_bf16<1, 0, 2><<<dim3(16, 128), blk, 0, stream>>>(
        Sb, ffn1_wt + (size_t)l * 2048 * 512, ffn_b1 + (size_t)l * DFF_DIM,
        nullptr, nullptr, Hb, nullptr, nullptr, 16384, 512, 2048);
    gemm_bf16<0, 1, 0><<<dim3(4, 128), blk, 0, stream>>>(
        Hb, ffn2_wt + (size_t)l * 512 * 2048, ffn_b2 + (size_t)l * D_DIM,
        Bk, Bq, nullptr, nullptr, nullptr, 16384, 2048, 512);
    if (l == 1)
      movavg_sub2<1><<<dim3(16, 32), blk, 0, stream>>>(Bq, Bh, Sb, hm);
    else
      movavg_sub2<0><<<dim3(16, 32), blk, 0, stream>>>(Bq, Bh, Sb, nullptr);
  }

  proj_head1<<<dim3(8), blk, 0, stream>>>(hm, proj_w1, proj_b1, p1);
  proj_head2<<<dim3(14), blk, 0, stream>>>(p1, proj_w2, proj_b2, out);
}

// Round 12
// 553.469 us; speedup vs baseline: 7.6457x; 1.0058x over previous
//
#include <hip/hip_runtime.h>
#include <hip/hip_bf16.h>

// AutoFormer forward. B=32 S=512 IN=256 D=512 H=8 L=2 DFF=2048 NT=424 K=25
#define S_LEN 512
#define D_DIM 512
#define B_DIM 32
#define IN_DIM 256
#define DFF_DIM 2048
#define NT_DIM 424

static constexpr size_t SZ = (size_t)B_DIM * S_LEN * D_DIM; // 8388608

using s8v = __attribute__((ext_vector_type(8))) short;
using f4v = __attribute__((ext_vector_type(4))) float;
typedef unsigned short ushortT;

__device__ __forceinline__ ushortT f2bf(float f) {
  unsigned u = __float_as_uint(f);
  u += 0x7FFFu + ((u >> 16) & 1u);   // RNE
  return (ushortT)(u >> 16);
}
__device__ __forceinline__ float bf2f(ushortT h) {
  return __uint_as_float(((unsigned)h) << 16);
}

// gelu(tanh approx) == x * sigmoid(2*0.7978845608*(x+0.044715x^3)) exactly
__device__ __forceinline__ float gelu_fast(float x) {
  float a = 1.5957691216057308f * (x + 0.044715f * x * x * x);
  return x / (1.f + __expf(-a));
}

__device__ __forceinline__ float2 cadd(float2 a, float2 b) { return float2{a.x + b.x, a.y + b.y}; }
__device__ __forceinline__ float2 csub(float2 a, float2 b) { return float2{a.x - b.x, a.y - b.y}; }
__device__ __forceinline__ float2 cmul(float2 a, float2 b) {
  return float2{a.x * b.x - a.y * b.y, a.x * b.y + a.y * b.x};
}
__device__ __forceinline__ float2 mni(float2 a) { return float2{a.y, -a.x}; } // *(-i)

// 8-point DFT, natural order in/out, e^{-2πi/8} convention.
__device__ __forceinline__ void dft8(float2 a[8]) {
  float2 t0 = cadd(a[0], a[4]), t4 = csub(a[0], a[4]);
  float2 t1 = cadd(a[1], a[5]), t5 = csub(a[1], a[5]);
  float2 t2 = cadd(a[2], a[6]), t6 = csub(a[2], a[6]);
  float2 t3 = cadd(a[3], a[7]), t7 = csub(a[3], a[7]);
  float2 u0 = cadd(t0, t2), u2 = csub(t0, t2);
  float2 u1 = cadd(t1, t3), u3 = csub(t1, t3);
  const float C = 0.70710678118654752f;
  float2 s5 = float2{C * (t5.x + t5.y), C * (t5.y - t5.x)};
  float2 s6 = mni(t6);
  float2 s7 = float2{C * (t7.y - t7.x), -C * (t7.x + t7.y)};
  float2 v0 = cadd(t4, s6), v2 = csub(t4, s6);
  float2 v1 = cadd(s5, s7), v3 = csub(s5, s7);
  a[0] = cadd(u0, u1); a[4] = csub(u0, u1);
  a[2] = cadd(u2, mni(u3)); a[6] = csub(u2, mni(u3));
  a[1] = cadd(v0, v1); a[5] = csub(v0, v1);
  a[3] = cadd(v2, mni(v3)); a[7] = csub(v2, mni(v3));
}

// ---------------------------------------------------------------------------
// All weight conversions in ONE dispatch (z picks the matrix).
// ---------------------------------------------------------------------------
__global__ __launch_bounds__(256) void conv_all(
    const float* __restrict__ embed_w, const float* __restrict__ qkvo_w,
    const float* __restrict__ ffn_w1, const float* __restrict__ ffn_w2,
    ushortT* __restrict__ embed_wt, ushortT* __restrict__ qkvo_wt,
    ushortT* __restrict__ ffn1_wt, ushortT* __restrict__ ffn2_wt)
{
  __shared__ float T[32][33];
  const int z = blockIdx.z;
  const float* W; ushortT* Wt; int Kp, N;
  if (z == 0)       { W = embed_w; Wt = embed_wt; Kp = 256; N = 512; }
  else if (z <= 8)  { int i = z - 1; W = qkvo_w + (size_t)i * 512 * 512;
                      Wt = qkvo_wt + (size_t)i * 512 * 512; Kp = 512; N = 512; }
  else if (z <= 10) { int l = z - 9; W = ffn_w1 + (size_t)l * 512 * 2048;
                      Wt = ffn1_wt + (size_t)l * 2048 * 512; Kp = 512; N = 2048; }
  else              { int l = z - 11; W = ffn_w2 + (size_t)l * 2048 * 512;
                      Wt = ffn2_wt + (size_t)l * 512 * 2048; Kp = 2048; N = 512; }
  int k0, n0;
  if (z >= 11) { k0 = blockIdx.y * 32; n0 = blockIdx.x * 32; }
  else         { k0 = blockIdx.x * 32; n0 = blockIdx.y * 32; }
  if (k0 >= Kp || n0 >= N) return;

  const int tid = threadIdx.x;
  const int col = tid & 31, r8 = tid >> 5;
#pragma unroll
  for (int it = 0; it < 4; ++it) {
    int row = r8 + it * 8;
    T[row][col] = W[(size_t)(k0 + row) * N + n0 + col];
  }
  __syncthreads();
  const int nl = tid >> 3, kq = tid & 7;
#pragma unroll
  for (int j = 0; j < 4; ++j) {
    int kl = kq * 4 + j;
    Wt[(size_t)(n0 + nl) * Kp + k0 + kl] = f2bf(T[kl][nl]);
  }
}

__global__ __launch_bounds__(256) void cvt_bf16(
    const float* __restrict__ in, ushortT* __restrict__ out, int n4)
{
  int i = blockIdx.x * 256 + threadIdx.x;
  if (i >= n4) return;
  float4 v = ((const float4*)in)[i];
  ushortT o[4] = {f2bf(v.x), f2bf(v.y), f2bf(v.z), f2bf(v.w)};
  *(uint2*)&out[(size_t)i * 4] = *(const uint2*)o;
}

// ---------------------------------------------------------------------------
// bf16 MFMA GEMM, 2-phase double-buffered, XCD-aware block swizzle.
// RES: 0 none, 1 fp32 res, 2 bf16 res (resb).
// OUT: 0 fp32 only, 1 fp32+bf16, 2 bf16 only,
// 3 = fused QKV (N=1536): cols [0,1024) -> Q/K fp16 transposed [b][c][s],
//     cols [1024,1536) -> V bf16 plain [row][c] into Cb.
// All low-precision outputs go through an LDS transpose tile (union with
// staging) so global stores are 256B-contiguous per 16 lanes.
// ---------------------------------------------------------------------------
template<int ACT, int RES, int OUT>
__global__ __launch_bounds__(256) void gemm_bf16(
    const ushortT* __restrict__ A, const ushortT* __restrict__ Wt,
    const float* __restrict__ bias, const float* __restrict__ res,
    const ushortT* __restrict__ resb,
    float* __restrict__ C, ushortT* __restrict__ Cb,
    ushortT* __restrict__ Qh, ushortT* __restrict__ Kh, int M, int Kp, int N)
{
  // union: staging (2 bufs x (A 8KB | W 8KB) = 16384 ushorts) /
  //        epilogue transpose tile [128][132] = 16896 ushorts
  __shared__ __align__(16) ushortT smem[16896];
  ushortT* Tt = smem;

  const int tid = threadIdx.x;
  const int lane = tid & 63, wid = tid >> 6;
  const int fr = lane & 15, kq = lane >> 4;
  const int wr = wid >> 1, wc = wid & 1;

  const int nwg = gridDim.x * gridDim.y;
  const int bid = blockIdx.y * gridDim.x + blockIdx.x;
  const int swz = (bid & 7) * (nwg >> 3) + (bid >> 3);
  const int bx = swz % gridDim.x, by = swz / gridDim.x;
  const int m0 = by * 128, n0 = bx * 128;

  int srow[2], skq[2];
#pragma unroll
  for (int t = 0; t < 2; ++t) {
    int ch = wid * 2 + t;
    int row = ch * 16 + (lane >> 2);
    int kql = lane & 3;
    srow[t] = row;
    skq[t] = kql ^ ((row >> 1) & 3);
  }

  int aoff[4], boff[4];
#pragma unroll
  for (int i = 0; i < 4; ++i) {
    int ra = wr * 64 + i * 16 + fr;
    aoff[i] = ra * 32 + ((kq ^ ((ra >> 1) & 3)) << 3);
    int rb = wc * 64 + i * 16 + fr;
    boff[i] = rb * 32 + ((kq ^ ((rb >> 1) & 3)) << 3);
  }

  auto STAGE = [&](int buf, int k0) {
#pragma unroll
    for (int t = 0; t < 2; ++t) {
      const ushortT* as = A + (size_t)(m0 + srow[t]) * Kp + k0 + skq[t] * 8;
      __builtin_amdgcn_global_load_lds(
          (const __attribute__((address_space(1))) unsigned int*)as,
          (__attribute__((address_space(3))) unsigned int*)&smem[buf * 4096 + (wid * 2 + t) * 512],
          16, 0, 0);
      const ushortT* wsrc = Wt + (size_t)(n0 + srow[t]) * Kp + k0 + skq[t] * 8;
      __builtin_amdgcn_global_load_lds(
          (const __attribute__((address_space(1))) unsigned int*)wsrc,
          (__attribute__((address_space(3))) unsigned int*)&smem[8192 + buf * 4096 + (wid * 2 + t) * 512],
          16, 0, 0);
    }
  };

  f4v acc[4][4] = {};
  STAGE(0, 0);
  int cur = 0;

  for (int k0 = 0; k0 < Kp; k0 += 32) {
    __syncthreads();
    if (k0 + 32 < Kp) STAGE(cur ^ 1, k0 + 32);
    s8v af[4], bfv[4];
#pragma unroll
    for (int i = 0; i < 4; ++i) {
      af[i]  = *(const s8v*)&smem[cur * 4096 + aoff[i]];
      bfv[i] = *(const s8v*)&smem[8192 + cur * 4096 + boff[i]];
    }
#pragma unroll
    for (int i = 0; i < 4; ++i)
#pragma unroll
      for (int j = 0; j < 4; ++j)
        acc[i][j] = __builtin_amdgcn_mfma_f32_16x16x32_bf16(af[i], bfv[j], acc[i][j], 0, 0, 0);
    cur ^= 1;
  }

  // ---- epilogue (C/D layout: col=lane&15, row=(lane>>4)*4+reg) ----
  if (OUT == 3 && n0 < 1024) {
    // Q or K -> fp16 transposed [b][c][s] via LDS transpose tile
    __syncthreads();
#pragma unroll
    for (int j = 0; j < 4; ++j) {
      const int c = wc * 64 + j * 16 + fr;
      const float bv = bias[n0 + c];
#pragma unroll
      for (int i = 0; i < 4; ++i)
#pragma unroll
        for (int r = 0; r < 4; ++r) {
          const int s = wr * 64 + i * 16 + kq * 4 + r;
          _Float16 hh = (_Float16)(acc[i][j][r] + bv);
          Tt[c * 132 + s] = __builtin_bit_cast(ushortT, hh);
        }
    }
    __syncthreads();
    ushortT* dstM = (n0 < 512) ? Qh : Kh;
    const int cg0 = n0 & 511;
    const int bb = m0 >> 9, ss0 = m0 & 511;
    const int g = tid >> 4, ln = tid & 15;
#pragma unroll
    for (int p = 0; p < 8; ++p) {
      const int c = p * 16 + g;
      uint4 v = *(const uint4*)&Tt[c * 132 + ln * 8];
      *(uint4*)&dstM[((size_t)bb * 512 + cg0 + c) * 512 + ss0 + ln * 8] = v;
    }
  } else {
    // generic: optional fp32 C; bf16 (or V-bf16) via LDS transpose tile.
    constexpr bool WB16 = (OUT != 0);
    const int nb  = (OUT == 3) ? 512 : N;          // bf16 dst row width
    const int cb0 = (OUT == 3) ? (n0 - 1024) : n0; // bf16 dst col base
    if (WB16) __syncthreads();
#pragma unroll
    for (int j = 0; j < 4; ++j) {
      const int lc = wc * 64 + j * 16 + fr;
      const int gc = n0 + lc;
      const float bv = bias[gc];
#pragma unroll
      for (int i = 0; i < 4; ++i)
#pragma unroll
        for (int r = 0; r < 4; ++r) {
          const int lr = wr * 64 + i * 16 + kq * 4 + r;
          const int gr = m0 + lr;
          float v = acc[i][j][r] + bv;
          if (RES == 1) v += res[(size_t)gr * N + gc];
          if (RES == 2) v += bf2f(resb[(size_t)gr * N + gc]);
          if (ACT == 1) v = gelu_fast(v);
          if (OUT == 0 || OUT == 1) C[(size_t)gr * N + gc] = v;
          if (WB16) Tt[lr * 132 + lc] = f2bf(v);
        }
    }
    if (WB16) {
      __syncthreads();
      const int g = tid >> 4, ln = tid & 15;
#pragma unroll
      for (int p = 0; p < 8; ++p) {
        const int row = p * 16 + g;
        uint4 v = *(const uint4*)&Tt[row * 132 + ln * 8];
        *(uint4*)&Cb[(size_t)(m0 + row) * nb + cb0 + ln * 8] = v;
      }
    }
  }
}

// ---------------------------------------------------------------------------
// FFT auto-correlation. 8 channels/block, 512 threads; wave = channel.
// Qh,Kh fp16 transposed [b][c][s]; V bf16 [b][s][c]; out bf16 [b][s][c].
// ---------------------------------------------------------------------------
__global__ __launch_bounds__(512) void autocorr_fft(
    const ushortT* __restrict__ Qh, const ushortT* __restrict__ Kh,
    const ushortT* __restrict__ Vb, ushortT* __restrict__ Ob)
{
  __shared__ float2 zs[8 * 578];
  const int tid = threadIdx.x;
  const int b  = blockIdx.x >> 6;
  const int c0 = (blockIdx.x & 63) << 3;
  const int ch = tid >> 6;
  const int t  = tid & 63;
  float2* zc = &zs[ch * 578];

  {
    const ushortT* Qg = Qh + ((size_t)b * 512 + c0 + ch) * 512 + t * 8;
    const ushortT* Kg = Kh + ((size_t)b * 512 + c0 + ch) * 512 + t * 8;
    uint4 qv = *(const uint4*)Qg;
    uint4 kv = *(const uint4*)Kg;
    const ushortT* qp = (const ushortT*)&qv;
    const ushortT* kp = (const ushortT*)&kv;
    const int base = 9 * t;
#pragma unroll
    for (int j = 0; j < 8; ++j) {
      zc[base + j] = float2{(float)__builtin_bit_cast(_Float16, qp[j]),
                            (float)__builtin_bit_cast(_Float16, kp[j])};
    }
  }
  __syncthreads();

  float2 a[8];
  auto stage_fn = [&](int stage, bool do_scatter) {
#pragma unroll
    for (int r = 0; r < 8; ++r) { int ci = t + 64 * r; a[r] = zc[ci + (ci >> 3)]; }
    dft8(a);
    if (stage < 2) {
      float angle = (stage == 0) ? (-6.283185307179586f / 512.f) * (float)t
                                 : (-6.283185307179586f / 64.f) * (float)(t >> 3);
      float sn, cs;
      __sincosf(angle, &sn, &cs);
      float2 w = float2{cs, sn}, wp = w;
      a[1] = cmul(a[1], wp);
#pragma unroll
      for (int r = 2; r < 8; ++r) { wp = cmul(wp, w); a[r] = cmul(a[r], wp); }
    }
    if (!do_scatter) return;
    __syncthreads();
#pragma unroll
    for (int r = 0; r < 8; ++r) {
      int ci = (stage == 0) ? 8 * t + r
             : (stage == 1) ? (t & 7) + 64 * (t >> 3) + 8 * r
                            : t + 64 * r;
      zc[ci + (ci >> 3)] = a[r];
    }
    __syncthreads();
  };

  stage_fn(0, true); stage_fn(1, true); stage_fn(2, true);

  float2 Zk[8], Zm[8];
#pragma unroll
  for (int r = 0; r < 8; ++r) {
    int k = t + 64 * r, mk = (512 - k) & 511;
    Zk[r] = zc[k + (k >> 3)];
    Zm[r] = zc[mk + (mk >> 3)];
  }
  __syncthreads();
  const float S = 0.00048828125f;   // 0.25/512
#pragma unroll
  for (int r = 0; r < 8; ++r) {
    int k = t + 64 * r;
    float x1 = Zk[r].x, y1 = Zk[r].y, x2 = Zm[r].x, y2 = Zm[r].y;
    float sx = x1 + x2, dx = x1 - x2, sy = y1 + y2, dy = y1 - y2;
    float pre = sx * sy - dy * dx;
    float pim = sx * dx + dy * sy;
    zc[k + (k >> 3)] = float2{pre * S, -pim * S};
  }
  __syncthreads();

  stage_fn(0, true); stage_fn(1, true); stage_fn(2, false);

  float corr[8];
#pragma unroll
  for (int r = 0; r < 8; ++r) corr[r] = a[r].x;
  float mx = corr[0];
#pragma unroll
  for (int r = 1; r < 8; ++r) mx = fmaxf(mx, corr[r]);
#pragma unroll
  for (int o = 1; o < 64; o <<= 1) mx = fmaxf(mx, __shfl_xor(mx, o));
  float ex[8], sum = 0.f;
#pragma unroll
  for (int r = 0; r < 8; ++r) { ex[r] = __expf(corr[r] - mx); sum += ex[r]; }
#pragma unroll
  for (int o = 1; o < 64; o <<= 1) sum += __shfl_xor(sum, o);
  const float inv = 1.f / sum;

  __syncthreads();
  float* wl = (float*)zc;
#pragma unroll
  for (int r = 0; r < 8; ++r) wl[t + 64 * r] = ex[r] * inv;
  __syncthreads();

  const float* wall = (const float*)zs;
  const size_t base = (size_t)b * S_LEN * D_DIM + c0;
  for (int i = tid; i < 4096; i += 512) {
    int s = i >> 3, cc = i & 7;
    float wv = wall[cc * 1156 + s];
    size_t ad = base + (size_t)s * D_DIM + cc;
    Ob[ad] = f2bf(wv * bf2f(Vb[ad]));
  }
}

// ---------------------------------------------------------------------------
// out = y - movavg(y,25), sliding-window. WF: also write fp32 output.
// ---------------------------------------------------------------------------
template<int MEAN, int WF>
__global__ __launch_bounds__(256) void movavg_sub2(
    const float* __restrict__ y, float* __restrict__ outf,
    ushortT* __restrict__ outb, float* __restrict__ hm)
{
  __shared__ float ys[512 * 32];
  const int tid = threadIdx.x;
  const int b = blockIdx.y, d0 = blockIdx.x * 32;
  const float* yb = y + (size_t)b * S_LEN * D_DIM + d0;

#pragma unroll 4
  for (int p = 0; p < 16; ++p) {
    int i = p * 256 + tid;
    int s = i >> 3, dq = i & 7;
    float4 v = *(const float4*)(yb + (size_t)s * D_DIM + dq * 4);
    *(float4*)&ys[s * 32 + dq * 4] = v;
  }
  __syncthreads();

  const int d = tid & 31, sg = tid >> 5;
  const int s0 = sg * 64;
  int lo = max(s0 - 12, 0), hi = min(s0 + 13, S_LEN);
  float sum = 0.f;
  for (int t = lo; t < hi; ++t) sum += ys[t * 32 + d];

  float msum = 0.f;
  const size_t gb = (size_t)b * S_LEN * D_DIM + d0 + d;
  for (int i = 0; i < 64; ++i) {
    const int s = s0 + i;
    float val = ys[s * 32 + d] - sum / (float)(hi - lo);
    size_t g = gb + (size_t)s * D_DIM;
    if (WF) outf[g] = val;
    outb[g] = f2bf(val);
    if (MEAN) msum += val;
    int add = s + 13;
    if (add < S_LEN) { sum += ys[add * 32 + d]; hi = add + 1; }
    int rem = s - 12;
    if (rem >= 0) { sum -= ys[rem * 32 + d]; lo = rem + 1; }
  }
  if (MEAN) atomicAdd(&hm[b * D_DIM + d0 + d], msum * (1.f / (float)S_LEN));
}

// ---------------------------------------------------------------------------
__global__ __launch_bounds__(256) void proj_head1(
    const float* __restrict__ hm, const float* __restrict__ W1,
    const float* __restrict__ b1, float* __restrict__ p1)
{
  __shared__ float hs[32 * 512];
  const int tid = threadIdx.x, n0 = blockIdx.x * 32;
  for (int i = tid; i < 16384; i += 256) hs[i] = hm[i];
  __syncthreads();
  const int n = tid & 31, mg = tid >> 5;
  float acc[4] = {};
  for (int k = 0; k < 512; ++k) {
    float w = W1[(size_t)k * 256 + n0 + n];
#pragma unroll
    for (int mi = 0; mi < 4; ++mi)
      acc[mi] = fmaf(hs[(mg * 4 + mi) * 512 + k], w, acc[mi]);
  }
  const float bb = b1[n0 + n];
#pragma unroll
  for (int mi = 0; mi < 4; ++mi)
    p1[(size_t)(mg * 4 + mi) * 256 + n0 + n] = fmaxf(acc[mi] + bb, 0.f);
}

__global__ __launch_bounds__(256) void proj_head2(
    const float* __restrict__ p1, const float* __restrict__ W2,
    const float* __restrict__ b2, float* __restrict__ out)
{
  __shared__ float ps[32 * 256];
  const int tid = threadIdx.x;
  for (int i = tid; i < 8192; i += 256) ps[i] = p1[i];
  __syncthreads();
  const int n = tid & 31, mg = tid >> 5;
  const int ng = blockIdx.x * 32 + n;
  const bool ok = ng < NT_DIM;
  float acc[4] = {};
  for (int k = 0; k < 256; ++k) {
    float w = ok ? W2[(size_t)k * NT_DIM + ng] : 0.f;
#pragma unroll
    for (int mi = 0; mi < 4; ++mi)
      acc[mi] = fmaf(ps[(mg * 4 + mi) * 256 + k], w, acc[mi]);
  }
  if (ok) {
    const float bb = b2[ng];
#pragma unroll
    for (int mi = 0; mi < 4; ++mi)
      out[(size_t)(mg * 4 + mi) * NT_DIM + ng] = acc[mi] + bb;
  }
}

// ---------------------------------------------------------------------------
extern "C" void kernel_launch(void* const* d_in, const int* in_sizes, int n_in,
                              void* d_out, int out_size, void* d_ws, size_t ws_size,
                              hipStream_t stream)
{
  const float* x       = (const float*)d_in[0];
  const float* embed_w = (const float*)d_in[1];
  const float* embed_b = (const float*)d_in[2];
  const float* qkvo_w  = (const float*)d_in[3];
  const float* qkvo_b  = (const float*)d_in[4];
  const float* ffn_w1  = (const float*)d_in[5];
  const float* ffn_b1  = (const float*)d_in[6];
  const float* ffn_w2  = (const float*)d_in[7];
  const float* ffn_b2  = (const float*)d_in[8];
  const float* proj_w1 = (const float*)d_in[9];
  const float* proj_b1 = (const float*)d_in[10];
  const float* proj_w2 = (const float*)d_in[11];
  const float* proj_b2 = (const float*)d_in[12];
  float* out = (float*)d_out;

  float* ws = (float*)d_ws;
  float* Bv = ws;              // V bf16; overlaid by Hb during FFN
  float* Bh = ws + SZ;         // h (residual fp32); overlaid by Hb during FFN
  float* Bq = ws + 2 * SZ;     // Qh fp16T -> y/y2 (fp32); xb during embed
  float* Bk = ws + 3 * SZ;     // Kh fp16T
  ushortT* Sb = (ushortT*)(ws + 4 * SZ);            // bf16 activation mirror
  ushortT* Wb = (ushortT*)(ws + 4 * SZ + SZ / 2);   // bf16 weights
  ushortT* embed_wt = Wb;                            // [512][256]
  ushortT* qkvo_wt  = embed_wt + (size_t)512 * 256;  // 8 x [512][512]
  ushortT* ffn1_wt  = qkvo_wt + (size_t)8 * 512 * 512;   // 2 x [2048][512]
  ushortT* ffn2_wt  = ffn1_wt + (size_t)2 * 2048 * 512;  // 2 x [512][2048]
  float* hm = (float*)(ffn2_wt + (size_t)2 * 512 * 2048); // [32][512]
  float* p1 = hm + 16384;                                  // [32][256]
  ushortT* Hb  = (ushortT*)Bv;   // FFN hidden bf16 [16384][2048] (Bv+Bh)
  ushortT* Vb  = (ushortT*)Bv;   // V bf16 [16384][512]
  ushortT* xb  = (ushortT*)Bq;   // x bf16 during embed
  ushortT* QKh = (ushortT*)Bq;   // Qh [0,SZ) + Kh [SZ,2SZ) fp16T

  dim3 blk(256);

  hipMemsetAsync(hm, 0, 16384 * sizeof(float), stream);

  conv_all<<<dim3(16, 64, 13), blk, 0, stream>>>(
      embed_w, qkvo_w, ffn_w1, ffn_w2, embed_wt, qkvo_wt, ffn1_wt, ffn2_wt);

  cvt_bf16<<<dim3(4096), blk, 0, stream>>>(x, xb, B_DIM * S_LEN * IN_DIM / 4);

  // embed: Bh(fp32) + Sb(bf16) = x @ We + be
  gemm_bf16<0, 0, 1><<<dim3(4, 128), blk, 0, stream>>>(
      xb, embed_wt, embed_b, nullptr, nullptr, Bh, Sb, nullptr, nullptr,
      16384, IN_DIM, D_DIM);

  for (int l = 0; l < 2; ++l) {
    const ushortT* qw = qkvo_wt + (size_t)l * 4 * 512 * 512;
    const float* qb = qkvo_b + (size_t)l * 4 * 512;
    // fused QKV: Q -> QKh (fp16T), K -> QKh+SZ (fp16T), V -> Vb (bf16 plain)
    gemm_bf16<0, 0, 3><<<dim3(12, 128), blk, 0, stream>>>(
        Sb, qw, qb, nullptr, nullptr, nullptr, Vb, QKh, QKh + SZ,
        16384, 512, 1536);
    autocorr_fft<<<dim3(B_DIM * 64), dim3(512), 0, stream>>>(QKh, QKh + SZ, Vb, Sb);
    // y = attn @ Wo + bo + h (fp32 res)  (overwrites QKh space; Q/K dead)
    gemm_bf16<0, 1, 0><<<dim3(4, 128), blk, 0, stream>>>(
        Sb, qw + (size_t)3 * 512 * 512, qb + 1536, Bh, nullptr, Bq, nullptr,
        nullptr, nullptr, 16384, 512, 512);
    // x1 = y - movavg(y): bf16 only (Sb); FFN2 takes res from Sb
    movavg_sub2<0, 0><<<dim3(16, 32), blk, 0, stream>>>(Bq, nullptr, Sb, nullptr);
    // FFN (hidden bf16 overlays Bv+Bh, both dead)
    gemm_bf16<1, 0, 2><<<dim3(16, 128), blk, 0, stream>>>(
        Sb, ffn1_wt + (size_t)l * 2048 * 512, ffn_b1 + (size_t)l * DFF_DIM,
        nullptr, nullptr, nullptr, Hb, nullptr, nullptr, 16384, 512, 2048);
    gemm_bf16<0, 2, 0><<<dim3(4, 128), blk, 0, stream>>>(
        Hb, ffn2_wt + (size_t)l * 512 * 2048, ffn_b2 + (size_t)l * D_DIM,
        nullptr, Sb, Bq, nullptr, nullptr, nullptr, 16384, 2048, 512);
    if (l == 1)
      movavg_sub2<1, 1><<<dim3(16, 32), blk, 0, stream>>>(Bq, Bh, Sb, hm);
    else
      movavg_sub2<0, 1><<<dim3(16, 32), blk, 0, stream>>>(Bq, Bh, Sb, nullptr);
  }

  proj_head1<<<dim3(8), blk, 0, stream>>>(hm, proj_w1, proj_b1, p1);
  proj_head2<<<dim3(14), blk, 0, stream>>>(p1, proj_w2, proj_b2, out);
}

// Round 13
// 553.321 us; speedup vs baseline: 7.6477x; 1.0003x over previous
//
#include <hip/hip_runtime.h>
#include <hip/hip_bf16.h>

// AutoFormer forward. B=32 S=512 IN=256 D=512 H=8 L=2 DFF=2048 NT=424 K=25
#define S_LEN 512
#define D_DIM 512
#define B_DIM 32
#define IN_DIM 256
#define DFF_DIM 2048
#define NT_DIM 424

static constexpr size_t SZ = (size_t)B_DIM * S_LEN * D_DIM; // 8388608

using s8v = __attribute__((ext_vector_type(8))) short;
using f4v = __attribute__((ext_vector_type(4))) float;
typedef unsigned short ushortT;

__device__ __forceinline__ ushortT f2bf(float f) {
  unsigned u = __float_as_uint(f);
  u += 0x7FFFu + ((u >> 16) & 1u);   // RNE
  return (ushortT)(u >> 16);
}
__device__ __forceinline__ float bf2f(ushortT h) {
  return __uint_as_float(((unsigned)h) << 16);
}

// gelu(tanh approx) == x * sigmoid(2*0.7978845608*(x+0.044715x^3)) exactly
__device__ __forceinline__ float gelu_fast(float x) {
  float a = 1.5957691216057308f * (x + 0.044715f * x * x * x);
  return x / (1.f + __expf(-a));
}

__device__ __forceinline__ float2 cadd(float2 a, float2 b) { return float2{a.x + b.x, a.y + b.y}; }
__device__ __forceinline__ float2 csub(float2 a, float2 b) { return float2{a.x - b.x, a.y - b.y}; }
__device__ __forceinline__ float2 cmul(float2 a, float2 b) {
  return float2{a.x * b.x - a.y * b.y, a.x * b.y + a.y * b.x};
}
__device__ __forceinline__ float2 mni(float2 a) { return float2{a.y, -a.x}; } // *(-i)

// 8-point DFT, natural order in/out, e^{-2πi/8} convention.
__device__ __forceinline__ void dft8(float2 a[8]) {
  float2 t0 = cadd(a[0], a[4]), t4 = csub(a[0], a[4]);
  float2 t1 = cadd(a[1], a[5]), t5 = csub(a[1], a[5]);
  float2 t2 = cadd(a[2], a[6]), t6 = csub(a[2], a[6]);
  float2 t3 = cadd(a[3], a[7]), t7 = csub(a[3], a[7]);
  float2 u0 = cadd(t0, t2), u2 = csub(t0, t2);
  float2 u1 = cadd(t1, t3), u3 = csub(t1, t3);
  const float C = 0.70710678118654752f;
  float2 s5 = float2{C * (t5.x + t5.y), C * (t5.y - t5.x)};
  float2 s6 = mni(t6);
  float2 s7 = float2{C * (t7.y - t7.x), -C * (t7.x + t7.y)};
  float2 v0 = cadd(t4, s6), v2 = csub(t4, s6);
  float2 v1 = cadd(s5, s7), v3 = csub(s5, s7);
  a[0] = cadd(u0, u1); a[4] = csub(u0, u1);
  a[2] = cadd(u2, mni(u3)); a[6] = csub(u2, mni(u3));
  a[1] = cadd(v0, v1); a[5] = csub(v0, v1);
  a[3] = cadd(v2, mni(v3)); a[7] = csub(v2, mni(v3));
}

// ---------------------------------------------------------------------------
// All weight conversions in ONE dispatch (z picks the matrix).
// ---------------------------------------------------------------------------
__global__ __launch_bounds__(256) void conv_all(
    const float* __restrict__ embed_w, const float* __restrict__ qkvo_w,
    const float* __restrict__ ffn_w1, const float* __restrict__ ffn_w2,
    ushortT* __restrict__ embed_wt, ushortT* __restrict__ qkvo_wt,
    ushortT* __restrict__ ffn1_wt, ushortT* __restrict__ ffn2_wt)
{
  __shared__ float T[32][33];
  const int z = blockIdx.z;
  const float* W; ushortT* Wt; int Kp, N;
  if (z == 0)       { W = embed_w; Wt = embed_wt; Kp = 256; N = 512; }
  else if (z <= 8)  { int i = z - 1; W = qkvo_w + (size_t)i * 512 * 512;
                      Wt = qkvo_wt + (size_t)i * 512 * 512; Kp = 512; N = 512; }
  else if (z <= 10) { int l = z - 9; W = ffn_w1 + (size_t)l * 512 * 2048;
                      Wt = ffn1_wt + (size_t)l * 2048 * 512; Kp = 512; N = 2048; }
  else              { int l = z - 11; W = ffn_w2 + (size_t)l * 2048 * 512;
                      Wt = ffn2_wt + (size_t)l * 512 * 2048; Kp = 2048; N = 512; }
  int k0, n0;
  if (z >= 11) { k0 = blockIdx.y * 32; n0 = blockIdx.x * 32; }
  else         { k0 = blockIdx.x * 32; n0 = blockIdx.y * 32; }
  if (k0 >= Kp || n0 >= N) return;

  const int tid = threadIdx.x;
  const int col = tid & 31, r8 = tid >> 5;
#pragma unroll
  for (int it = 0; it < 4; ++it) {
    int row = r8 + it * 8;
    T[row][col] = W[(size_t)(k0 + row) * N + n0 + col];
  }
  __syncthreads();
  const int nl = tid >> 3, kq = tid & 7;
#pragma unroll
  for (int j = 0; j < 4; ++j) {
    int kl = kq * 4 + j;
    Wt[(size_t)(n0 + nl) * Kp + k0 + kl] = f2bf(T[kl][nl]);
  }
}

__global__ __launch_bounds__(256) void cvt_bf16(
    const float* __restrict__ in, ushortT* __restrict__ out, int n4)
{
  int i = blockIdx.x * 256 + threadIdx.x;
  if (i >= n4) return;
  float4 v = ((const float4*)in)[i];
  ushortT o[4] = {f2bf(v.x), f2bf(v.y), f2bf(v.z), f2bf(v.w)};
  *(uint2*)&out[(size_t)i * 4] = *(const uint2*)o;
}

// ---------------------------------------------------------------------------
// bf16 MFMA GEMM, 3-buffer circular pipeline with counted vmcnt + raw
// s_barrier (T3/T4): stage k+2 issued in step k; per-step wait is
// vmcnt(4) (stage k done, k+1 in flight), vmcnt(0) on last step only.
// RES: 0 none, 1 fp32 res, 2 bf16 res. OUT: 0 fp32, 1 fp32+bf16, 2 bf16,
// 3 = fused QKV (N=1536): Q/K fp16T [b][c][s], V bf16 plain via Cb.
// Low-precision outputs go through an LDS transpose tile (union w/ staging).
// ---------------------------------------------------------------------------
template<int ACT, int RES, int OUT>
__global__ __launch_bounds__(256) void gemm_bf16(
    const ushortT* __restrict__ A, const ushortT* __restrict__ Wt,
    const float* __restrict__ bias, const float* __restrict__ res,
    const ushortT* __restrict__ resb,
    float* __restrict__ C, ushortT* __restrict__ Cb,
    ushortT* __restrict__ Qh, ushortT* __restrict__ Kh, int M, int Kp, int N)
{
  // union: staging 3 bufs x (A 8KB @0 | W 8KB @24576B) = 24576 ushorts /
  //        epilogue transpose tile [128][132] = 16896 ushorts
  __shared__ __align__(16) ushortT smem[24576];
  ushortT* Tt = smem;

  const int tid = threadIdx.x;
  const int lane = tid & 63, wid = tid >> 6;
  const int fr = lane & 15, kq = lane >> 4;
  const int wr = wid >> 1, wc = wid & 1;

  const int nwg = gridDim.x * gridDim.y;
  const int bid = blockIdx.y * gridDim.x + blockIdx.x;
  const int swz = (bid & 7) * (nwg >> 3) + (bid >> 3);
  const int bx = swz % gridDim.x, by = swz / gridDim.x;
  const int m0 = by * 128, n0 = bx * 128;

  int srow[2], skq[2];
#pragma unroll
  for (int t = 0; t < 2; ++t) {
    int ch = wid * 2 + t;
    int row = ch * 16 + (lane >> 2);
    int kql = lane & 3;
    srow[t] = row;
    skq[t] = kql ^ ((row >> 1) & 3);
  }

  int aoff[4], boff[4];
#pragma unroll
  for (int i = 0; i < 4; ++i) {
    int ra = wr * 64 + i * 16 + fr;
    aoff[i] = ra * 32 + ((kq ^ ((ra >> 1) & 3)) << 3);
    int rb = wc * 64 + i * 16 + fr;
    boff[i] = rb * 32 + ((kq ^ ((rb >> 1) & 3)) << 3);
  }

  auto STAGE = [&](int buf, int k0) {
#pragma unroll
    for (int t = 0; t < 2; ++t) {
      const ushortT* as = A + (size_t)(m0 + srow[t]) * Kp + k0 + skq[t] * 8;
      __builtin_amdgcn_global_load_lds(
          (const __attribute__((address_space(1))) unsigned int*)as,
          (__attribute__((address_space(3))) unsigned int*)&smem[buf * 4096 + (wid * 2 + t) * 512],
          16, 0, 0);
      const ushortT* wsrc = Wt + (size_t)(n0 + srow[t]) * Kp + k0 + skq[t] * 8;
      __builtin_amdgcn_global_load_lds(
          (const __attribute__((address_space(1))) unsigned int*)wsrc,
          (__attribute__((address_space(3))) unsigned int*)&smem[12288 + buf * 4096 + (wid * 2 + t) * 512],
          16, 0, 0);
    }
  };

  f4v acc[4][4] = {};
  STAGE(0, 0);
  if (Kp > 32) STAGE(1, 32);
  int cur = 0, nxt = 2;

  for (int k0 = 0; k0 < Kp; k0 += 32) {
    // wait: own stage-k loads landed (FIFO vmcnt); others via barrier
    if (k0 + 32 < Kp) {
      asm volatile("s_waitcnt vmcnt(4)" ::: "memory");
    } else {
      asm volatile("s_waitcnt vmcnt(0)" ::: "memory");
    }
    __builtin_amdgcn_s_barrier();
    __builtin_amdgcn_sched_barrier(0);
    if (k0 + 64 < Kp) {
      STAGE(nxt, k0 + 64);                  // overwrites buffer of step k-1
      nxt = (nxt == 2) ? 0 : nxt + 1;
    }
    s8v af[4], bfv[4];
    const int ab = cur * 4096, wb = 12288 + cur * 4096;
#pragma unroll
    for (int i = 0; i < 4; ++i) {
      af[i]  = *(const s8v*)&smem[ab + aoff[i]];
      bfv[i] = *(const s8v*)&smem[wb + boff[i]];
    }
#pragma unroll
    for (int i = 0; i < 4; ++i)
#pragma unroll
      for (int j = 0; j < 4; ++j)
        acc[i][j] = __builtin_amdgcn_mfma_f32_16x16x32_bf16(af[i], bfv[j], acc[i][j], 0, 0, 0);
    cur = (cur == 2) ? 0 : cur + 1;
  }

  // ---- epilogue (C/D layout: col=lane&15, row=(lane>>4)*4+reg) ----
  if (OUT == 3 && n0 < 1024) {
    // Q or K -> fp16 transposed [b][c][s] via LDS transpose tile
    __syncthreads();
#pragma unroll
    for (int j = 0; j < 4; ++j) {
      const int c = wc * 64 + j * 16 + fr;
      const float bv = bias[n0 + c];
#pragma unroll
      for (int i = 0; i < 4; ++i)
#pragma unroll
        for (int r = 0; r < 4; ++r) {
          const int s = wr * 64 + i * 16 + kq * 4 + r;
          _Float16 hh = (_Float16)(acc[i][j][r] + bv);
          Tt[c * 132 + s] = __builtin_bit_cast(ushortT, hh);
        }
    }
    __syncthreads();
    ushortT* dstM = (n0 < 512) ? Qh : Kh;
    const int cg0 = n0 & 511;
    const int bb = m0 >> 9, ss0 = m0 & 511;
    const int g = tid >> 4, ln = tid & 15;
#pragma unroll
    for (int p = 0; p < 8; ++p) {
      const int c = p * 16 + g;
      uint4 v = *(const uint4*)&Tt[c * 132 + ln * 8];
      *(uint4*)&dstM[((size_t)bb * 512 + cg0 + c) * 512 + ss0 + ln * 8] = v;
    }
  } else {
    // generic: optional fp32 C; bf16 (or V-bf16) via LDS transpose tile.
    constexpr bool WB16 = (OUT != 0);
    const int nb  = (OUT == 3) ? 512 : N;          // bf16 dst row width
    const int cb0 = (OUT == 3) ? (n0 - 1024) : n0; // bf16 dst col base
    if (WB16) __syncthreads();
#pragma unroll
    for (int j = 0; j < 4; ++j) {
      const int lc = wc * 64 + j * 16 + fr;
      const int gc = n0 + lc;
      const float bv = bias[gc];
#pragma unroll
      for (int i = 0; i < 4; ++i)
#pragma unroll
        for (int r = 0; r < 4; ++r) {
          const int lr = wr * 64 + i * 16 + kq * 4 + r;
          const int gr = m0 + lr;
          float v = acc[i][j][r] + bv;
          if (RES == 1) v += res[(size_t)gr * N + gc];
          if (RES == 2) v += bf2f(resb[(size_t)gr * N + gc]);
          if (ACT == 1) v = gelu_fast(v);
          if (OUT == 0 || OUT == 1) C[(size_t)gr * N + gc] = v;
          if (WB16) Tt[lr * 132 + lc] = f2bf(v);
        }
    }
    if (WB16) {
      __syncthreads();
      const int g = tid >> 4, ln = tid & 15;
#pragma unroll
      for (int p = 0; p < 8; ++p) {
        const int row = p * 16 + g;
        uint4 v = *(const uint4*)&Tt[row * 132 + ln * 8];
        *(uint4*)&Cb[(size_t)(m0 + row) * nb + cb0 + ln * 8] = v;
      }
    }
  }
}

// ---------------------------------------------------------------------------
// FFT auto-correlation. 8 channels/block, 512 threads; wave = channel.
// Qh,Kh fp16 transposed [b][c][s]; V bf16 [b][s][c]; out bf16 [b][s][c].
// ---------------------------------------------------------------------------
__global__ __launch_bounds__(512) void autocorr_fft(
    const ushortT* __restrict__ Qh, const ushortT* __restrict__ Kh,
    const ushortT* __restrict__ Vb, ushortT* __restrict__ Ob)
{
  __shared__ float2 zs[8 * 578];
  const int tid = threadIdx.x;
  const int b  = blockIdx.x >> 6;
  const int c0 = (blockIdx.x & 63) << 3;
  const int ch = tid >> 6;
  const int t  = tid & 63;
  float2* zc = &zs[ch * 578];

  {
    const ushortT* Qg = Qh + ((size_t)b * 512 + c0 + ch) * 512 + t * 8;
    const ushortT* Kg = Kh + ((size_t)b * 512 + c0 + ch) * 512 + t * 8;
    uint4 qv = *(const uint4*)Qg;
    uint4 kv = *(const uint4*)Kg;
    const ushortT* qp = (const ushortT*)&qv;
    const ushortT* kp = (const ushortT*)&kv;
    const int base = 9 * t;
#pragma unroll
    for (int j = 0; j < 8; ++j) {
      zc[base + j] = float2{(float)__builtin_bit_cast(_Float16, qp[j]),
                            (float)__builtin_bit_cast(_Float16, kp[j])};
    }
  }
  __syncthreads();

  float2 a[8];
  auto stage_fn = [&](int stage, bool do_scatter) {
#pragma unroll
    for (int r = 0; r < 8; ++r) { int ci = t + 64 * r; a[r] = zc[ci + (ci >> 3)]; }
    dft8(a);
    if (stage < 2) {
      float angle = (stage == 0) ? (-6.283185307179586f / 512.f) * (float)t
                                 : (-6.283185307179586f / 64.f) * (float)(t >> 3);
      float sn, cs;
      __sincosf(angle, &sn, &cs);
      float2 w = float2{cs, sn}, wp = w;
      a[1] = cmul(a[1], wp);
#pragma unroll
      for (int r = 2; r < 8; ++r) { wp = cmul(wp, w); a[r] = cmul(a[r], wp); }
    }
    if (!do_scatter) return;
    __syncthreads();
#pragma unroll
    for (int r = 0; r < 8; ++r) {
      int ci = (stage == 0) ? 8 * t + r
             : (stage == 1) ? (t & 7) + 64 * (t >> 3) + 8 * r
                            : t + 64 * r;
      zc[ci + (ci >> 3)] = a[r];
    }
    __syncthreads();
  };

  stage_fn(0, true); stage_fn(1, true); stage_fn(2, true);

  float2 Zk[8], Zm[8];
#pragma unroll
  for (int r = 0; r < 8; ++r) {
    int k = t + 64 * r, mk = (512 - k) & 511;
    Zk[r] = zc[k + (k >> 3)];
    Zm[r] = zc[mk + (mk >> 3)];
  }
  __syncthreads();
  const float S = 0.00048828125f;   // 0.25/512
#pragma unroll
  for (int r = 0; r < 8; ++r) {
    int k = t + 64 * r;
    float x1 = Zk[r].x, y1 = Zk[r].y, x2 = Zm[r].x, y2 = Zm[r].y;
    float sx = x1 + x2, dx = x1 - x2, sy = y1 + y2, dy = y1 - y2;
    float pre = sx * sy - dy * dx;
    float pim = sx * dx + dy * sy;
    zc[k + (k >> 3)] = float2{pre * S, -pim * S};
  }
  __syncthreads();

  stage_fn(0, true); stage_fn(1, true); stage_fn(2, false);

  float corr[8];
#pragma unroll
  for (int r = 0; r < 8; ++r) corr[r] = a[r].x;
  float mx = corr[0];
#pragma unroll
  for (int r = 1; r < 8; ++r) mx = fmaxf(mx, corr[r]);
#pragma unroll
  for (int o = 1; o < 64; o <<= 1) mx = fmaxf(mx, __shfl_xor(mx, o));
  float ex[8], sum = 0.f;
#pragma unroll
  for (int r = 0; r < 8; ++r) { ex[r] = __expf(corr[r] - mx); sum += ex[r]; }
#pragma unroll
  for (int o = 1; o < 64; o <<= 1) sum += __shfl_xor(sum, o);
  const float inv = 1.f / sum;

  __syncthreads();
  float* wl = (float*)zc;
#pragma unroll
  for (int r = 0; r < 8; ++r) wl[t + 64 * r] = ex[r] * inv;
  __syncthreads();

  const float* wall = (const float*)zs;
  const size_t base = (size_t)b * S_LEN * D_DIM + c0;
  for (int i = tid; i < 4096; i += 512) {
    int s = i >> 3, cc = i & 7;
    float wv = wall[cc * 1156 + s];
    size_t ad = base + (size_t)s * D_DIM + cc;
    Ob[ad] = f2bf(wv * bf2f(Vb[ad]));
  }
}

// ---------------------------------------------------------------------------
// out = y - movavg(y,25), sliding-window. WF: also write fp32 output.
// ---------------------------------------------------------------------------
template<int MEAN, int WF>
__global__ __launch_bounds__(256) void movavg_sub2(
    const float* __restrict__ y, float* __restrict__ outf,
    ushortT* __restrict__ outb, float* __restrict__ hm)
{
  __shared__ float ys[512 * 32];
  const int tid = threadIdx.x;
  const int b = blockIdx.y, d0 = blockIdx.x * 32;
  const float* yb = y + (size_t)b * S_LEN * D_DIM + d0;

#pragma unroll 4
  for (int p = 0; p < 16; ++p) {
    int i = p * 256 + tid;
    int s = i >> 3, dq = i & 7;
    float4 v = *(const float4*)(yb + (size_t)s * D_DIM + dq * 4);
    *(float4*)&ys[s * 32 + dq * 4] = v;
  }
  __syncthreads();

  const int d = tid & 31, sg = tid >> 5;
  const int s0 = sg * 64;
  int lo = max(s0 - 12, 0), hi = min(s0 + 13, S_LEN);
  float sum = 0.f;
  for (int t = lo; t < hi; ++t) sum += ys[t * 32 + d];

  float msum = 0.f;
  const size_t gb = (size_t)b * S_LEN * D_DIM + d0 + d;
  for (int i = 0; i < 64; ++i) {
    const int s = s0 + i;
    float val = ys[s * 32 + d] - sum / (float)(hi - lo);
    size_t g = gb + (size_t)s * D_DIM;
    if (WF) outf[g] = val;
    outb[g] = f2bf(val);
    if (MEAN) msum += val;
    int add = s + 13;
    if (add < S_LEN) { sum += ys[add * 32 + d]; hi = add + 1; }
    int rem = s - 12;
    if (rem >= 0) { sum -= ys[rem * 32 + d]; lo = rem + 1; }
  }
  if (MEAN) atomicAdd(&hm[b * D_DIM + d0 + d], msum * (1.f / (float)S_LEN));
}

// ---------------------------------------------------------------------------
__global__ __launch_bounds__(256) void proj_head1(
    const float* __restrict__ hm, const float* __restrict__ W1,
    const float* __restrict__ b1, float* __restrict__ p1)
{
  __shared__ float hs[32 * 512];
  const int tid = threadIdx.x, n0 = blockIdx.x * 32;
  for (int i = tid; i < 16384; i += 256) hs[i] = hm[i];
  __syncthreads();
  const int n = tid & 31, mg = tid >> 5;
  float acc[4] = {};
  for (int k = 0; k < 512; ++k) {
    float w = W1[(size_t)k * 256 + n0 + n];
#pragma unroll
    for (int mi = 0; mi < 4; ++mi)
      acc[mi] = fmaf(hs[(mg * 4 + mi) * 512 + k], w, acc[mi]);
  }
  const float bb = b1[n0 + n];
#pragma unroll
  for (int mi = 0; mi < 4; ++mi)
    p1[(size_t)(mg * 4 + mi) * 256 + n0 + n] = fmaxf(acc[mi] + bb, 0.f);
}

__global__ __launch_bounds__(256) void proj_head2(
    const float* __restrict__ p1, const float* __restrict__ W2,
    const float* __restrict__ b2, float* __restrict__ out)
{
  __shared__ float ps[32 * 256];
  const int tid = threadIdx.x;
  for (int i = tid; i < 8192; i += 256) ps[i] = p1[i];
  __syncthreads();
  const int n = tid & 31, mg = tid >> 5;
  const int ng = blockIdx.x * 32 + n;
  const bool ok = ng < NT_DIM;
  float acc[4] = {};
  for (int k = 0; k < 256; ++k) {
    float w = ok ? W2[(size_t)k * NT_DIM + ng] : 0.f;
#pragma unroll
    for (int mi = 0; mi < 4; ++mi)
      acc[mi] = fmaf(ps[(mg * 4 + mi) * 256 + k], w, acc[mi]);
  }
  if (ok) {
    const float bb = b2[ng];
#pragma unroll
    for (int mi = 0; mi < 4; ++mi)
      out[(size_t)(mg * 4 + mi) * NT_DIM + ng] = acc[mi] + bb;
  }
}

// ---------------------------------------------------------------------------
extern "C" void kernel_launch(void* const* d_in, const int* in_sizes, int n_in,
                              void* d_out, int out_size, void* d_ws, size_t ws_size,
                              hipStream_t stream)
{
  const float* x       = (const float*)d_in[0];
  const float* embed_w = (const float*)d_in[1];
  const float* embed_b = (const float*)d_in[2];
  const float* qkvo_w  = (const float*)d_in[3];
  const float* qkvo_b  = (const float*)d_in[4];
  const float* ffn_w1  = (const float*)d_in[5];
  const float* ffn_b1  = (const float*)d_in[6];
  const float* ffn_w2  = (const float*)d_in[7];
  const float* ffn_b2  = (const float*)d_in[8];
  const float* proj_w1 = (const float*)d_in[9];
  const float* proj_b1 = (const float*)d_in[10];
  const float* proj_w2 = (const float*)d_in[11];
  const float* proj_b2 = (const float*)d_in[12];
  float* out = (float*)d_out;

  float* ws = (float*)d_ws;
  float* Bv = ws;              // V bf16; overlaid by Hb during FFN
  float* Bh = ws + SZ;         // h (residual fp32); overlaid by Hb during FFN
  float* Bq = ws + 2 * SZ;     // Qh fp16T -> y/y2 (fp32); xb during embed
  float* Bk = ws + 3 * SZ;     // Kh fp16T
  ushortT* Sb = (ushortT*)(ws + 4 * SZ);            // bf16 activation mirror
  ushortT* Wb = (ushortT*)(ws + 4 * SZ + SZ / 2);   // bf16 weights
  ushortT* embed_wt = Wb;                            // [512][256]
  ushortT* qkvo_wt  = embed_wt + (size_t)512 * 256;  // 8 x [512][512]
  ushortT* ffn1_wt  = qkvo_wt + (size_t)8 * 512 * 512;   // 2 x [2048][512]
  ushortT* ffn2_wt  = ffn1_wt + (size_t)2 * 2048 * 512;  // 2 x [512][2048]
  float* hm = (float*)(ffn2_wt + (size_t)2 * 512 * 2048); // [32][512]
  float* p1 = hm + 16384;                                  // [32][256]
  ushortT* Hb  = (ushortT*)Bv;   // FFN hidden bf16 [16384][2048] (Bv+Bh)
  ushortT* Vb  = (ushortT*)Bv;   // V bf16 [16384][512]
  ushortT* xb  = (ushortT*)Bq;   // x bf16 during embed
  ushortT* QKh = (ushortT*)Bq;   // Qh [0,SZ) + Kh [SZ,2SZ) fp16T

  dim3 blk(256);

  hipMemsetAsync(hm, 0, 16384 * sizeof(float), stream);

  conv_all<<<dim3(16, 64, 13), blk, 0, stream>>>(
      embed_w, qkvo_w, ffn_w1, ffn_w2, embed_wt, qkvo_wt, ffn1_wt, ffn2_wt);

  cvt_bf16<<<dim3(4096), blk, 0, stream>>>(x, xb, B_DIM * S_LEN * IN_DIM / 4);

  // embed: Bh(fp32) + Sb(bf16) = x @ We + be
  gemm_bf16<0, 0, 1><<<dim3(4, 128), blk, 0, stream>>>(
      xb, embed_wt, embed_b, nullptr, nullptr, Bh, Sb, nullptr, nullptr,
      16384, IN_DIM, D_DIM);

  for (int l = 0; l < 2; ++l) {
    const ushortT* qw = qkvo_wt + (size_t)l * 4 * 512 * 512;
    const float* qb = qkvo_b + (size_t)l * 4 * 512;
    // fused QKV: Q -> QKh (fp16T), K -> QKh+SZ (fp16T), V -> Vb (bf16 plain)
    gemm_bf16<0, 0, 3><<<dim3(12, 128), blk, 0, stream>>>(
        Sb, qw, qb, nullptr, nullptr, nullptr, Vb, QKh, QKh + SZ,
        16384, 512, 1536);
    autocorr_fft<<<dim3(B_DIM * 64), dim3(512), 0, stream>>>(QKh, QKh + SZ, Vb, Sb);
    // y = attn @ Wo + bo + h (fp32 res)  (overwrites QKh space; Q/K dead)
    gemm_bf16<0, 1, 0><<<dim3(4, 128), blk, 0, stream>>>(
        Sb, qw + (size_t)3 * 512 * 512, qb + 1536, Bh, nullptr, Bq, nullptr,
        nullptr, nullptr, 16384, 512, 512);
    // x1 = y - movavg(y): bf16 only (Sb); FFN2 takes res from Sb
    movavg_sub2<0, 0><<<dim3(16, 32), blk, 0, stream>>>(Bq, nullptr, Sb, nullptr);
    // FFN (hidden bf16 overlays Bv+Bh, both dead)
    gemm_bf16<1, 0, 2><<<dim3(16, 128), blk, 0, stream>>>(
        Sb, ffn1_wt + (size_t)l * 2048 * 512, ffn_b1 + (size_t)l * DFF_DIM,
        nullptr, nullptr, nullptr, Hb, nullptr, nullptr, 16384, 512, 2048);
    gemm_bf16<0, 2, 0><<<dim3(4, 128), blk, 0, stream>>>(
        Hb, ffn2_wt + (size_t)l * 512 * 2048, ffn_b2 + (size_t)l * D_DIM,
        nullptr, Sb, Bq, nullptr, nullptr, nullptr, 16384, 2048, 512);
    if (l == 1)
      movavg_sub2<1, 1><<<dim3(16, 32), blk, 0, stream>>>(Bq, Bh, Sb, hm);
    else
      movavg_sub2<0, 1><<<dim3(16, 32), blk, 0, stream>>>(Bq, Bh, Sb, nullptr);
  }

  proj_head1<<<dim3(8), blk, 0, stream>>>(hm, proj_w1, proj_b1, p1);
  proj_head2<<<dim3(14), blk, 0, stream>>>(p1, proj_w2, proj_b2, out);
}